// Round 3
// baseline (1690.526 us; speedup 1.0000x reference)
//
#include <hip/hip_runtime.h>
#include <hip/hip_bf16.h>

typedef unsigned long long u64;
typedef __bf16 bf16_t;
typedef __attribute__((ext_vector_type(8))) __bf16 bf16x8;
typedef __attribute__((ext_vector_type(4))) __bf16 bf16x4;
typedef __attribute__((ext_vector_type(4))) float f32x4;

#define NROWS 16384
#define KLAT  768
#define EDIM  256
#define NE    8192
#define ODIM  768

// output element offsets (FLOAT32 elements — d_out is fp32, 16,801,795 elems)
#define OFF_ZQ   0
#define OFF_IND  12582912
#define OFF_LOSS 12599296
#define OFF_EMB  12599297
#define OFF_EAVG 14696449
#define OFF_CSF  16793601
#define OFF_EMIN 16801793
#define OFF_CMT  16801794

// workspace layout (~25.76 MB proven)
#define W_XN    0u           // bf16 xh (8MB) + xl (8MB)
#define W_ESUM  16777216u    // bf16 eh (4MB) + el (4MB); later f32 esum
#define W_RMIN  25165824u    // u64 rowmin [16384]
#define W_RZ    25296896u    // f32 rowZ
#define W_RS1   25362432u    // f32 rowS1
#define W_INVZ  25427968u    // (unused this round)
#define W_INDW  25493504u    // i32 ind
#define W_BINS  25559040u    // f32 bins [8192]
#define W_CN    25591808u    // f32 cluster_new
#define W_CSM   25624576u    // f32 cs smoothed
#define W_IDXS  25657344u    // i32 sampled idx
#define W_AP    25690112u    // f32 ap [8192]
#define W_SCAL  25722880u    // f32 scal[4]
#define W_END   25722896u

#define CANDCAP 16
#define PROWS   2048         // panel rows
#define PM      256          // phase1 block rows
#define PN      128          // phase1 block cols
#define PK      32           // phase1 K chunk
#define LSTR    34           // LDS row stride (bf16): 17 dwords, odd -> bank-balanced

// ---------------------------------------------------------------------------
__global__ __launch_bounds__(256) void zero_out_kernel(float* __restrict__ out, int n)
{
  int i = blockIdx.x * 256 + threadIdx.x;
  if (i < n) out[i] = 0.0f;
}

// ---------------------------------------------------------------------------
// GEMM-in: x_proj[M][256] = x[M][768] @ W_in[256][768]^T + b_in  (fp32)
// ---------------------------------------------------------------------------
__global__ __launch_bounds__(256) void gemm_in_kernel(
    const float* __restrict__ A, const float* __restrict__ B,
    const float* __restrict__ bias, float* __restrict__ C)
{
  __shared__ float As[16][64];
  __shared__ float Bs[16][64];
  const int tid = threadIdx.x;
  const int tx = tid & 15, ty = tid >> 4;
  const int bm = blockIdx.x << 6, bn = blockIdx.y << 6;
  const int lr = tid >> 2, lk = (tid & 3) << 2;
  const size_t aoff = (size_t)(bm + lr) * KLAT;
  const size_t boff = (size_t)(bn + lr) * KLAT;
  float acc[4][4] = {};
  for (int k0 = 0; k0 < KLAT; k0 += 16) {
    __syncthreads();
    float4 av = *(const float4*)(A + aoff + k0 + lk);
    float4 bv = *(const float4*)(B + boff + k0 + lk);
    As[lk + 0][lr] = av.x; As[lk + 1][lr] = av.y; As[lk + 2][lr] = av.z; As[lk + 3][lr] = av.w;
    Bs[lk + 0][lr] = bv.x; Bs[lk + 1][lr] = bv.y; Bs[lk + 2][lr] = bv.z; Bs[lk + 3][lr] = bv.w;
    __syncthreads();
#pragma unroll
    for (int kk = 0; kk < 16; ++kk) {
      float4 a4 = *(const float4*)&As[kk][ty << 2];
      float4 b4 = *(const float4*)&Bs[kk][tx << 2];
      float ar[4] = {a4.x, a4.y, a4.z, a4.w};
      float br[4] = {b4.x, b4.y, b4.z, b4.w};
#pragma unroll
      for (int i = 0; i < 4; ++i)
#pragma unroll
        for (int j = 0; j < 4; ++j)
          acc[i][j] = fmaf(ar[i], br[j], acc[i][j]);
    }
  }
  float4 b4 = *(const float4*)(bias + bn + (tx << 2));
  float bb[4] = {b4.x, b4.y, b4.z, b4.w};
#pragma unroll
  for (int i = 0; i < 4; ++i) {
    const size_t row = (size_t)(bm + (ty << 2) + i);
    float4 o = make_float4(acc[i][0] + bb[0], acc[i][1] + bb[1],
                           acc[i][2] + bb[2], acc[i][3] + bb[3]);
    *(float4*)(C + row * EDIM + bn + (tx << 2)) = o;
  }
}

// ---------------------------------------------------------------------------
// GEMM-out: out[M][768] = embed[ind[M]][256] @ W_out[768][256]^T + b_out
// Runs LAST (overwrites the z_q scratch region).
// ---------------------------------------------------------------------------
__global__ __launch_bounds__(256) void gemm_out_kernel(
    const float* __restrict__ A, const float* __restrict__ B,
    const float* __restrict__ bias, const int* __restrict__ gather,
    float* __restrict__ C)
{
  __shared__ float As[16][64];
  __shared__ float Bs[16][64];
  const int tid = threadIdx.x;
  const int tx = tid & 15, ty = tid >> 4;
  const int bm = blockIdx.x << 6, bn = blockIdx.y << 6;
  const int lr = tid >> 2, lk = (tid & 3) << 2;
  const size_t arow = (size_t)(gather[bm + lr] & (NE - 1));
  const size_t aoff = arow * EDIM;
  const size_t boff = (size_t)(bn + lr) * EDIM;
  float acc[4][4] = {};
  for (int k0 = 0; k0 < EDIM; k0 += 16) {
    __syncthreads();
    float4 av = *(const float4*)(A + aoff + k0 + lk);
    float4 bv = *(const float4*)(B + boff + k0 + lk);
    As[lk + 0][lr] = av.x; As[lk + 1][lr] = av.y; As[lk + 2][lr] = av.z; As[lk + 3][lr] = av.w;
    Bs[lk + 0][lr] = bv.x; Bs[lk + 1][lr] = bv.y; Bs[lk + 2][lr] = bv.z; Bs[lk + 3][lr] = bv.w;
    __syncthreads();
#pragma unroll
    for (int kk = 0; kk < 16; ++kk) {
      float4 a4 = *(const float4*)&As[kk][ty << 2];
      float4 b4 = *(const float4*)&Bs[kk][tx << 2];
      float ar[4] = {a4.x, a4.y, a4.z, a4.w};
      float br[4] = {b4.x, b4.y, b4.z, b4.w};
#pragma unroll
      for (int i = 0; i < 4; ++i)
#pragma unroll
        for (int j = 0; j < 4; ++j)
          acc[i][j] = fmaf(ar[i], br[j], acc[i][j]);
    }
  }
  float4 b4 = *(const float4*)(bias + bn + (tx << 2));
  float bb[4] = {b4.x, b4.y, b4.z, b4.w};
#pragma unroll
  for (int i = 0; i < 4; ++i) {
    const size_t row = (size_t)(bm + (ty << 2) + i);
    float4 o = make_float4(acc[i][0] + bb[0], acc[i][1] + bb[1],
                           acc[i][2] + bb[2], acc[i][3] + bb[3]);
    *(float4*)(C + row * ODIM + bn + (tx << 2)) = o;
  }
}

// ---------------------------------------------------------------------------
// l2norm in place (fp32 in d_out scratch) + bf16 hi/lo planes
// ---------------------------------------------------------------------------
__global__ __launch_bounds__(256) void l2norm_split_kernel(
    float* __restrict__ xnf, bf16_t* __restrict__ xh, bf16_t* __restrict__ xl)
{
  __shared__ float sb[4];
  const int r = blockIdx.x, t = threadIdx.x;
  const size_t o = (size_t)r * EDIM + t;
  float v = xnf[o];
  float s = v * v;
#pragma unroll
  for (int off = 32; off >= 1; off >>= 1) s += __shfl_xor(s, off);
  if ((t & 63) == 0) sb[t >> 6] = s;
  __syncthreads();
  float tot = sb[0] + sb[1] + sb[2] + sb[3];
  float nv = v / sqrtf(tot);
  xnf[o] = nv;
  bf16_t h = (bf16_t)nv;
  xh[o] = h;
  xl[o] = (bf16_t)(nv - (float)h);
}

// ---------------------------------------------------------------------------
__global__ __launch_bounds__(256) void embed_split_kernel(
    const float* __restrict__ embed, bf16_t* __restrict__ eh, bf16_t* __restrict__ el)
{
  const int i = (blockIdx.x * 256 + threadIdx.x) << 2;
  float4 v = *(const float4*)(embed + i);
  bf16_t h0 = (bf16_t)v.x, h1 = (bf16_t)v.y, h2 = (bf16_t)v.z, h3 = (bf16_t)v.w;
  bf16x4 hv = {h0, h1, h2, h3};
  bf16x4 lv = {(bf16_t)(v.x - (float)h0), (bf16_t)(v.y - (float)h1),
               (bf16_t)(v.z - (float)h2), (bf16_t)(v.w - (float)h3)};
  *(bf16x4*)(eh + i) = hv;
  *(bf16x4*)(el + i) = lv;
}

// ---------------------------------------------------------------------------
// Phase 1 (panel): d~ via bf16x3 MFMA. Block 256x128, 4 waves (2x2), wave
// tile 128x64 = 8x4 frags of 16x16x32 -> 96 MFMAs per 24 ds_read_b128 (MFMA-
// bound). Writes P = exp(10 d~) bf16 [PROWS][NE] + rowmin key + Z + S1.
// LDS stride 34 bf16 (17 dwords, odd): b128 windows cover all banks evenly.
// ---------------------------------------------------------------------------
__global__ __launch_bounds__(256) void phase1_mfma_kernel(
    const bf16_t* __restrict__ xh, const bf16_t* __restrict__ xl,
    const bf16_t* __restrict__ eh, const bf16_t* __restrict__ el,
    const int rowbase,
    u64* __restrict__ rowmin, float* __restrict__ rowZ, float* __restrict__ rowS1,
    bf16_t* __restrict__ P)
{
  __shared__ bf16_t Ah[PM * LSTR];
  __shared__ bf16_t Al[PM * LSTR];
  __shared__ bf16_t Bh[PN * LSTR];
  __shared__ bf16_t Bl[PN * LSTR];
  const int tid  = threadIdx.x;
  const int lane = tid & 63;
  const int wave = tid >> 6;
  const int wm = wave >> 1, wn = wave & 1;   // wave tile: rows 128*wm, cols 64*wn
  const int brow = blockIdx.x * PM;          // panel-local row base
  const int bcol = blockIdx.y * PN;          // global col base

  f32x4 acc[8][4] = {};

  for (int k0 = 0; k0 < EDIM; k0 += PK) {
    __syncthreads();
#pragma unroll
    for (int p = 0; p < 4; ++p) {           // A: 256 rows x 32k
      const int idx = tid + (p << 8);
      const int r = idx >> 2, kc = (idx & 3) << 3;
      const size_t g = (size_t)(rowbase + brow + r) * EDIM + k0 + kc;
      *(bf16x8*)&Ah[r * LSTR + kc] = *(const bf16x8*)(xh + g);
      *(bf16x8*)&Al[r * LSTR + kc] = *(const bf16x8*)(xl + g);
    }
#pragma unroll
    for (int p = 0; p < 2; ++p) {           // B: 128 rows x 32k
      const int idx = tid + (p << 8);
      const int r = idx >> 2, kc = (idx & 3) << 3;
      const size_t g = (size_t)(bcol + r) * EDIM + k0 + kc;
      *(bf16x8*)&Bh[r * LSTR + kc] = *(const bf16x8*)(eh + g);
      *(bf16x8*)&Bl[r * LSTR + kc] = *(const bf16x8*)(el + g);
    }
    __syncthreads();
    const int koff = (lane >> 4) << 3;      // 0,8,16,24
    bf16x8 bhf[4], blf[4];
#pragma unroll
    for (int n = 0; n < 4; ++n) {
      const int c = (wn << 6) + (n << 4) + (lane & 15);
      bhf[n] = *(const bf16x8*)&Bh[c * LSTR + koff];
      blf[n] = *(const bf16x8*)&Bl[c * LSTR + koff];
    }
#pragma unroll
    for (int m = 0; m < 8; ++m) {
      const int r = (wm << 7) + (m << 4) + (lane & 15);
      bf16x8 ahf = *(const bf16x8*)&Ah[r * LSTR + koff];
      bf16x8 alf = *(const bf16x8*)&Al[r * LSTR + koff];
#pragma unroll
      for (int n = 0; n < 4; ++n) {
        acc[m][n] = __builtin_amdgcn_mfma_f32_16x16x32_bf16(ahf, bhf[n], acc[m][n], 0, 0, 0);
        acc[m][n] = __builtin_amdgcn_mfma_f32_16x16x32_bf16(ahf, blf[n], acc[m][n], 0, 0, 0);
        acc[m][n] = __builtin_amdgcn_mfma_f32_16x16x32_bf16(alf, bhf[n], acc[m][n], 0, 0, 0);
      }
    }
  }

  // epilogue: C/D layout col = lane&15 (+n*16), row = (lane>>4)*4 + q (+m*16)
  const int colg = bcol + (wn << 6) + (lane & 15);
  const int rl0  = brow + (wm << 7) + ((lane >> 4) << 2);
#pragma unroll
  for (int m = 0; m < 8; ++m) {
#pragma unroll
    for (int q = 0; q < 4; ++q) {
      const int rl = rl0 + (m << 4) + q;      // panel-local row
      float Z = 0.f, S1 = 0.f;
      u64 mk = ~0ull;
#pragma unroll
      for (int n = 0; n < 4; ++n) {
        float d = acc[m][n][q];
        float l = 10.f * d;
        float e = __expf(l);
        Z += e; S1 += l * e;
        P[(size_t)rl * NE + colg + (n << 4)] = (bf16_t)e;
        u64 key = ((u64)__float_as_uint(d + 2.0f) << 32) | (unsigned)(colg + (n << 4));
        if (key < mk) mk = key;
      }
#pragma unroll
      for (int off = 1; off < 16; off <<= 1) {
        u64 ok = __shfl_xor(mk, off);
        if (ok < mk) mk = ok;
        Z  += __shfl_xor(Z, off);
        S1 += __shfl_xor(S1, off);
      }
      if ((lane & 15) == 0) {
        const int rg = rowbase + rl;
        atomicMin(rowmin + rg, mk);
        atomicAdd(rowZ + rg, Z);
        atomicAdd(rowS1 + rg, S1);
      }
    }
  }
}

// ---------------------------------------------------------------------------
// Column reduce over a panel: ap[c] += sum_r P[r][c] / Z_r ; candidate
// collection where P <= exp(10*(dmin + 3e-4)) (covers split + bf16 error).
// ---------------------------------------------------------------------------
__global__ __launch_bounds__(256) void colreduce_kernel(
    const bf16_t* __restrict__ P, const float* __restrict__ rowZ,
    const u64* __restrict__ rowmin, const int rowbase,
    float* __restrict__ ap, int* __restrict__ ccnt, int* __restrict__ clist)
{
  __shared__ float izs[128], ths[128];
  const int t = threadIdx.x;
  const int c = blockIdx.x * 256 + t;
  const int r0 = blockIdx.y * 128;          // panel-local
  if (t < 128) {
    const int rg = rowbase + r0 + t;
    izs[t] = 1.0f / rowZ[rg];
    float dmin = __uint_as_float((unsigned)(rowmin[rg] >> 32)) - 2.0f;
    ths[t] = __expf(10.f * (dmin + 3e-4f));
  }
  __syncthreads();
  float s = 0.f;
  for (int r = 0; r < 128; ++r) {
    float p = (float)P[(size_t)(r0 + r) * NE + c];
    s = fmaf(p, izs[r], s);
    if (p <= ths[r]) {
      const int rg = rowbase + r0 + r;
      int pos = atomicAdd(ccnt + rg, 1);
      if (pos < CANDCAP) clist[(rg << 4) + pos] = c;
    }
  }
  atomicAdd(ap + c, s);
}

// ---------------------------------------------------------------------------
// entropy_to_min partials over all rows (after all panels)
// ---------------------------------------------------------------------------
__global__ __launch_bounds__(256) void rowent_kernel(
    const float* __restrict__ rowZ, const float* __restrict__ rowS1,
    float* __restrict__ scal)
{
  __shared__ float sb[4];
  const int r = blockIdx.x * 256 + threadIdx.x;
  const int t = threadIdx.x;
  float Z = rowZ[r], S1 = rowS1[r];
  float ent = logf(Z) - S1 / Z;
#pragma unroll
  for (int off = 32; off >= 1; off >>= 1) ent += __shfl_xor(ent, off);
  if ((t & 63) == 0) sb[t >> 6] = ent;
  __syncthreads();
  if (t == 0) atomicAdd(scal + 1, sb[0] + sb[1] + sb[2] + sb[3]);
}

// ---------------------------------------------------------------------------
// Repair: exact fp32 argmin over candidate set; lexicographic (d, idx) min.
// ---------------------------------------------------------------------------
__global__ __launch_bounds__(256) void repair_kernel(
    const float* __restrict__ xnf, const float* __restrict__ embed,
    const u64* __restrict__ rowmin, const int* __restrict__ ccnt,
    const int* __restrict__ clist, int* __restrict__ indw,
    float* __restrict__ bins, float* __restrict__ out)
{
  const int t = threadIdx.x;
  const int row = blockIdx.x * 64 + (t >> 2);
  const int sub = t & 3;
  const int base = ((int)(unsigned)(rowmin[row] & 0xFFFFFFFFull)) & (NE - 1);
  int cnt = ccnt[row];
  if (cnt > CANDCAP) cnt = CANDCAP;
  float bestD = 1e30f;
  int bestI = NE;
  const float* xr = xnf + (size_t)row * EDIM + (sub << 6);
  for (int j = -1; j < cnt; ++j) {
    const int c = (j < 0) ? base : (clist[(row << 4) + j] & (NE - 1));
    const float* er = embed + (size_t)c * EDIM + (sub << 6);
    float s = 0.f;
#pragma unroll
    for (int k = 0; k < 64; k += 4) {
      float4 a = *(const float4*)(xr + k);
      float4 b = *(const float4*)(er + k);
      s = fmaf(a.x, b.x, s); s = fmaf(a.y, b.y, s);
      s = fmaf(a.z, b.z, s); s = fmaf(a.w, b.w, s);
    }
    s += __shfl_xor(s, 1);
    s += __shfl_xor(s, 2);
    if (s < bestD || (s == bestD && c < bestI)) { bestD = s; bestI = c; }
  }
  if (sub == 0) {
    indw[row] = bestI;
    out[OFF_IND + row] = (float)bestI;
    atomicAdd(bins + bestI, 1.0f);
  }
}

// ---------------------------------------------------------------------------
__global__ __launch_bounds__(256) void scatter_commit_kernel(
    const float* __restrict__ xn, const float* __restrict__ embed,
    const int* __restrict__ indw, float* __restrict__ esum, float* __restrict__ scal)
{
  __shared__ float sb[4];
  const int r = blockIdx.x, t = threadIdx.x;
  const int ind = indw[r] & (NE - 1);
  float xv = xn[(size_t)r * EDIM + t];
  float ev = embed[(size_t)ind * EDIM + t];
  float df = ev - xv;
  float s = df * df;
#pragma unroll
  for (int off = 32; off >= 1; off >>= 1) s += __shfl_xor(s, off);
  if ((t & 63) == 0) sb[t >> 6] = s;
  __syncthreads();
  if (t == 0) atomicAdd(scal + 2, sb[0] + sb[1] + sb[2] + sb[3]);
  atomicAdd(esum + (size_t)ind * EDIM + t, xv);
}

// ---------------------------------------------------------------------------
__global__ __launch_bounds__(256) void scalars_kernel(
    const float* __restrict__ ap, const float* __restrict__ scal, float* __restrict__ out)
{
  __shared__ float sb[4];
  const int t = threadIdx.x;
  float h = 0.f;
  for (int c = t; c < NE; c += 256) {
    float apv = ap[c] * (1.0f / NROWS);
    h -= apv * logf(apv);
  }
#pragma unroll
  for (int off = 32; off >= 1; off >>= 1) h += __shfl_xor(h, off);
  if ((t & 63) == 0) sb[t >> 6] = h;
  __syncthreads();
  if (t == 0) {
    float Hmax = sb[0] + sb[1] + sb[2] + sb[3];
    float commit = scal[2] * (1.0f / ((float)NROWS * (float)EDIM));
    float emin = scal[1] * (1.0f / (float)NROWS);
    out[OFF_LOSS] = commit - Hmax;
    out[OFF_EMIN] = emin;
    out[OFF_CMT]  = commit;
  }
}

// ---------------------------------------------------------------------------
__global__ __launch_bounds__(256) void cluster_kernel(
    const float* __restrict__ cs_in, const float* __restrict__ bins,
    float* __restrict__ cn, float* __restrict__ scal)
{
  __shared__ float sb[4];
  const int c = blockIdx.x * 256 + threadIdx.x;
  const int t = threadIdx.x;
  float v = cs_in[c] * 0.99f + bins[c] * 0.01f;
  cn[c] = v;
  float s = v;
#pragma unroll
  for (int off = 32; off >= 1; off >>= 1) s += __shfl_xor(s, off);
  if ((t & 63) == 0) sb[t >> 6] = s;
  __syncthreads();
  if (t == 0) atomicAdd(scal + 0, sb[0] + sb[1] + sb[2] + sb[3]);
}

// ---------------------------------------------------------------------------
__global__ __launch_bounds__(256) void scan_kernel(
    const float* __restrict__ cn, const float* __restrict__ scal,
    int* __restrict__ idxs, float* __restrict__ csm, float* __restrict__ out)
{
  __shared__ int ssum[256];
  const int t = threadIdx.x;
  const int base = t * 32;
  int cnt = 0;
  for (int j = 0; j < 32; ++j) cnt += (cn[base + j] < 0.1f) ? 1 : 0;
  ssum[t] = cnt;
  __syncthreads();
  for (int off = 1; off < 256; off <<= 1) {
    int v = (t >= off) ? ssum[t - off] : 0;
    __syncthreads();
    ssum[t] += v;
    __syncthreads();
  }
  int run = (t > 0) ? ssum[t - 1] : 0;
  const float total = scal[0];
  const float dscale = total / (total + (float)NE * 1e-5f);
  for (int j = 0; j < 32; ++j) {
    float v = cn[base + j];
    bool ex = v < 0.1f;                 // DEAD_THRESH * RATIO
    run += ex ? 1 : 0;
    int idx = run - 1; if (idx < 0) idx = 0;
    idx &= (NROWS - 1);
    idxs[base + j] = idx;
    csm[base + j] = (v + 1e-5f) * dscale;
    out[OFF_CSF + base + j] = ex ? 0.12f : v;   // RESET_CS*RATIO
  }
}

// ---------------------------------------------------------------------------
__global__ __launch_bounds__(256) void embed_out_kernel(
    const float* __restrict__ cn, const float* __restrict__ csm,
    const int* __restrict__ idxs, const float* __restrict__ xn,
    const float* __restrict__ embed_avg, const float* __restrict__ esum,
    float* __restrict__ out)
{
  const int c = blockIdx.x, t = threadIdx.x;
  float oe, oa;
  if (cn[c] < 0.1f) {
    float s = xn[(size_t)(idxs[c] & (NROWS - 1)) * EDIM + t];
    oe = s; oa = s * 0.12f;
  } else {
    float an = embed_avg[(size_t)c * EDIM + t] * 0.99f
             + esum[(size_t)c * EDIM + t] * 0.01f;
    oa = an; oe = an / csm[c];
  }
  out[OFF_EMB  + (size_t)c * EDIM + t] = oe;
  out[OFF_EAVG + (size_t)c * EDIM + t] = oa;
}

// ---------------------------------------------------------------------------
extern "C" void kernel_launch(void* const* d_in, const int* in_sizes, int n_in,
                              void* d_out, int out_size, void* d_ws, size_t ws_size,
                              hipStream_t stream)
{
  const float* x         = (const float*)d_in[0];
  const float* W_in      = (const float*)d_in[1];
  const float* b_in      = (const float*)d_in[2];
  const float* W_out     = (const float*)d_in[3];
  const float* b_out     = (const float*)d_in[4];
  const float* embed     = (const float*)d_in[5];
  const float* embed_avg = (const float*)d_in[6];
  const float* cs_in     = (const float*)d_in[7];
  float* out = (float*)d_out;
  char* ws = (char*)d_ws;

  if (ws_size < (size_t)W_END) {   // guard (proven not to fire)
    zero_out_kernel<<<(out_size + 255) / 256, 256, 0, stream>>>(out, out_size);
    return;
  }

  bf16_t* xh = (bf16_t*)(ws + W_XN);
  bf16_t* xl = (bf16_t*)(ws + W_XN + 8388608u);
  bf16_t* eh = (bf16_t*)(ws + W_ESUM);
  bf16_t* el = (bf16_t*)(ws + W_ESUM + 4194304u);
  float* esum  = (float*)(ws + W_ESUM);
  u64*   rowmin= (u64*)  (ws + W_RMIN);
  float* rowZ  = (float*)(ws + W_RZ);
  float* rowS1 = (float*)(ws + W_RS1);
  int*   indw  = (int*)  (ws + W_INDW);
  float* bins  = (float*)(ws + W_BINS);
  float* cn    = (float*)(ws + W_CN);
  float* csm   = (float*)(ws + W_CSM);
  int*   idxs  = (int*)  (ws + W_IDXS);
  float* ap    = (float*)(ws + W_AP);
  float* scal  = (float*)(ws + W_SCAL);

  // d_out scratch (until the late kernels overwrite):
  //   z_q region: [0, 16MB) fp32 xn ; [16MB, 48MB) bf16 P panel (ends at OFF_IND)
  //   emb region: ccnt[16384] + clist[16384*16]  (overwritten by embed_out later)
  float*  xnf   = out + OFF_ZQ;
  bf16_t* Pbuf  = (bf16_t*)(out + OFF_ZQ + 4194304);
  int*    ccnt  = (int*)(out + OFF_EMB);
  int*    clist = ccnt + NROWS;

  hipMemsetAsync(ws + W_RMIN, 0xFF, W_RZ - W_RMIN, stream); // rowmin = ~0
  hipMemsetAsync(ws + W_RZ,   0,    W_END - W_RZ,  stream); // rowZ..scal = 0
  hipMemsetAsync(ccnt, 0, NROWS * sizeof(int), stream);     // candidate counts

  // 1. x_proj (fp32 into d_out scratch)
  gemm_in_kernel<<<dim3(NROWS / 64, EDIM / 64), 256, 0, stream>>>(
      x, W_in, b_in, xnf);
  // 2. l2norm + bf16 hi/lo planes
  l2norm_split_kernel<<<NROWS, 256, 0, stream>>>(xnf, xh, xl);
  // 3. embed bf16 hi/lo planes (esum region until panels done)
  embed_split_kernel<<<(NE * EDIM / 4) / 256, 256, 0, stream>>>(embed, eh, el);
  // 4. panel loop: MFMA similarity + P store, then column reduce
  for (int p = 0; p < NROWS / PROWS; ++p) {
    const int rowbase = p * PROWS;
    phase1_mfma_kernel<<<dim3(PROWS / PM, NE / PN), 256, 0, stream>>>(
        xh, xl, eh, el, rowbase, rowmin, rowZ, rowS1, Pbuf);
    colreduce_kernel<<<dim3(NE / 256, PROWS / 128), 256, 0, stream>>>(
        Pbuf, rowZ, rowmin, rowbase, ap, ccnt, clist);
  }
  // 5. entropy_to_min partials
  rowent_kernel<<<NROWS / 256, 256, 0, stream>>>(rowZ, rowS1, scal);
  // 6. free eh/el -> esum = 0
  hipMemsetAsync(ws + W_ESUM, 0, W_RMIN - W_ESUM, stream);
  // 7. exact argmin repair
  repair_kernel<<<NROWS / 64, 256, 0, stream>>>(
      xnf, embed, rowmin, ccnt, clist, indw, bins, out);
  // 8. commit loss + embed_sum scatter
  scatter_commit_kernel<<<NROWS, 256, 0, stream>>>(xnf, embed, indw, esum, scal);
  // 9. cluster_new + total
  cluster_kernel<<<NE / 256, 256, 0, stream>>>(cs_in, bins, cn, scal);
  // 10. expiry scan + cluster_final
  scan_kernel<<<1, 256, 0, stream>>>(cn, scal, idxs, csm, out);
  // 11. scalar outputs
  scalars_kernel<<<1, 256, 0, stream>>>(ap, scal, out);
  // 12. embed_final / embed_avg_final (reads fp32 xn scratch)
  embed_out_kernel<<<NE, 256, 0, stream>>>(cn, csm, idxs, xnf, embed_avg, esum, out);
  // 13. z_q GEMM LAST (overwrites z_q scratch incl. P)
  gemm_out_kernel<<<dim3(NROWS / 64, ODIM / 64), 256, 0, stream>>>(
      embed, W_out, b_out, indw, out + OFF_ZQ);
}

// Round 4
// 1445.634 us; speedup vs baseline: 1.1694x; 1.1694x over previous
//
#include <hip/hip_runtime.h>
#include <hip/hip_bf16.h>

typedef unsigned long long u64;
typedef __bf16 bf16_t;
typedef __attribute__((ext_vector_type(8))) __bf16 bf16x8;
typedef __attribute__((ext_vector_type(4))) __bf16 bf16x4;
typedef __attribute__((ext_vector_type(4))) float f32x4;

#define NROWS 16384
#define KLAT  768
#define EDIM  256
#define NE    8192
#define ODIM  768

// output element offsets (FLOAT32 elements — d_out is fp32, 16,801,795 elems)
#define OFF_ZQ   0
#define OFF_IND  12582912
#define OFF_LOSS 12599296
#define OFF_EMB  12599297
#define OFF_EAVG 14696449
#define OFF_CSF  16793601
#define OFF_EMIN 16801793
#define OFF_CMT  16801794

// workspace layout (~25.76 MB proven)
#define W_XN    0u           // bf16 xh (8MB) + xl (8MB)
#define W_ESUM  16777216u    // bf16 eh (4MB) + el (4MB); later f32 esum (written in full)
#define W_RMIN  25165824u    // u64 rowmin [16384]; after repair: i32 offs[8192]+cursor[8192]
#define W_RZ    25296896u    // f32 rowZ
#define W_RS1   25362432u    // f32 rowS1
#define W_INVZ  25427968u    // i32 binsI [8192]
#define W_INDW  25493504u    // i32 ind
#define W_BINS  25559040u    // f32 bins [8192]
#define W_CN    25591808u    // f32 cluster_new
#define W_CSM   25624576u    // f32 cs smoothed
#define W_IDXS  25657344u    // i32 sampled idx
#define W_AP    25690112u    // f32 ap [8192] (PERMUTED col space — entropy invariant)
#define W_SCAL  25722880u    // f32 scal[4]
#define W_END   25722896u

#define CANDCAP 16
#define PROWS   2048         // panel rows
#define PM      256          // phase1 block rows
#define PN      128          // phase1 block cols
#define PK      32           // phase1 K chunk
#define LSTR    34           // LDS row stride (bf16): 17 dwords, odd -> bank-balanced

// ---------------------------------------------------------------------------
__global__ __launch_bounds__(256) void zero_out_kernel(float* __restrict__ out, int n)
{
  int i = blockIdx.x * 256 + threadIdx.x;
  if (i < n) out[i] = 0.0f;
}

// ---------------------------------------------------------------------------
// GEMM-in: x_proj[M][256] = x[M][768] @ W_in[256][768]^T + b_in  (fp32)
// ---------------------------------------------------------------------------
__global__ __launch_bounds__(256) void gemm_in_kernel(
    const float* __restrict__ A, const float* __restrict__ B,
    const float* __restrict__ bias, float* __restrict__ C)
{
  __shared__ float As[16][64];
  __shared__ float Bs[16][64];
  const int tid = threadIdx.x;
  const int tx = tid & 15, ty = tid >> 4;
  const int bm = blockIdx.x << 6, bn = blockIdx.y << 6;
  const int lr = tid >> 2, lk = (tid & 3) << 2;
  const size_t aoff = (size_t)(bm + lr) * KLAT;
  const size_t boff = (size_t)(bn + lr) * KLAT;
  float acc[4][4] = {};
  for (int k0 = 0; k0 < KLAT; k0 += 16) {
    __syncthreads();
    float4 av = *(const float4*)(A + aoff + k0 + lk);
    float4 bv = *(const float4*)(B + boff + k0 + lk);
    As[lk + 0][lr] = av.x; As[lk + 1][lr] = av.y; As[lk + 2][lr] = av.z; As[lk + 3][lr] = av.w;
    Bs[lk + 0][lr] = bv.x; Bs[lk + 1][lr] = bv.y; Bs[lk + 2][lr] = bv.z; Bs[lk + 3][lr] = bv.w;
    __syncthreads();
#pragma unroll
    for (int kk = 0; kk < 16; ++kk) {
      float4 a4 = *(const float4*)&As[kk][ty << 2];
      float4 b4 = *(const float4*)&Bs[kk][tx << 2];
      float ar[4] = {a4.x, a4.y, a4.z, a4.w};
      float br[4] = {b4.x, b4.y, b4.z, b4.w};
#pragma unroll
      for (int i = 0; i < 4; ++i)
#pragma unroll
        for (int j = 0; j < 4; ++j)
          acc[i][j] = fmaf(ar[i], br[j], acc[i][j]);
    }
  }
  float4 b4 = *(const float4*)(bias + bn + (tx << 2));
  float bb[4] = {b4.x, b4.y, b4.z, b4.w};
#pragma unroll
  for (int i = 0; i < 4; ++i) {
    const size_t row = (size_t)(bm + (ty << 2) + i);
    float4 o = make_float4(acc[i][0] + bb[0], acc[i][1] + bb[1],
                           acc[i][2] + bb[2], acc[i][3] + bb[3]);
    *(float4*)(C + row * EDIM + bn + (tx << 2)) = o;
  }
}

// ---------------------------------------------------------------------------
// GEMM-out: out[M][768] = embed[ind[M]][256] @ W_out[768][256]^T + b_out
// Runs LAST (overwrites the z_q scratch region).
// ---------------------------------------------------------------------------
__global__ __launch_bounds__(256) void gemm_out_kernel(
    const float* __restrict__ A, const float* __restrict__ B,
    const float* __restrict__ bias, const int* __restrict__ gather,
    float* __restrict__ C)
{
  __shared__ float As[16][64];
  __shared__ float Bs[16][64];
  const int tid = threadIdx.x;
  const int tx = tid & 15, ty = tid >> 4;
  const int bm = blockIdx.x << 6, bn = blockIdx.y << 6;
  const int lr = tid >> 2, lk = (tid & 3) << 2;
  const size_t arow = (size_t)(gather[bm + lr] & (NE - 1));
  const size_t aoff = arow * EDIM;
  const size_t boff = (size_t)(bn + lr) * EDIM;
  float acc[4][4] = {};
  for (int k0 = 0; k0 < EDIM; k0 += 16) {
    __syncthreads();
    float4 av = *(const float4*)(A + aoff + k0 + lk);
    float4 bv = *(const float4*)(B + boff + k0 + lk);
    As[lk + 0][lr] = av.x; As[lk + 1][lr] = av.y; As[lk + 2][lr] = av.z; As[lk + 3][lr] = av.w;
    Bs[lk + 0][lr] = bv.x; Bs[lk + 1][lr] = bv.y; Bs[lk + 2][lr] = bv.z; Bs[lk + 3][lr] = bv.w;
    __syncthreads();
#pragma unroll
    for (int kk = 0; kk < 16; ++kk) {
      float4 a4 = *(const float4*)&As[kk][ty << 2];
      float4 b4 = *(const float4*)&Bs[kk][tx << 2];
      float ar[4] = {a4.x, a4.y, a4.z, a4.w};
      float br[4] = {b4.x, b4.y, b4.z, b4.w};
#pragma unroll
      for (int i = 0; i < 4; ++i)
#pragma unroll
        for (int j = 0; j < 4; ++j)
          acc[i][j] = fmaf(ar[i], br[j], acc[i][j]);
    }
  }
  float4 b4 = *(const float4*)(bias + bn + (tx << 2));
  float bb[4] = {b4.x, b4.y, b4.z, b4.w};
#pragma unroll
  for (int i = 0; i < 4; ++i) {
    const size_t row = (size_t)(bm + (ty << 2) + i);
    float4 o = make_float4(acc[i][0] + bb[0], acc[i][1] + bb[1],
                           acc[i][2] + bb[2], acc[i][3] + bb[3]);
    *(float4*)(C + row * ODIM + bn + (tx << 2)) = o;
  }
}

// ---------------------------------------------------------------------------
// l2norm in place (fp32 in d_out scratch) + bf16 hi/lo planes
// ---------------------------------------------------------------------------
__global__ __launch_bounds__(256) void l2norm_split_kernel(
    float* __restrict__ xnf, bf16_t* __restrict__ xh, bf16_t* __restrict__ xl)
{
  __shared__ float sb[4];
  const int r = blockIdx.x, t = threadIdx.x;
  const size_t o = (size_t)r * EDIM + t;
  float v = xnf[o];
  float s = v * v;
#pragma unroll
  for (int off = 32; off >= 1; off >>= 1) s += __shfl_xor(s, off);
  if ((t & 63) == 0) sb[t >> 6] = s;
  __syncthreads();
  float tot = sb[0] + sb[1] + sb[2] + sb[3];
  float nv = v / sqrtf(tot);
  xnf[o] = nv;
  bf16_t h = (bf16_t)nv;
  xh[o] = h;
  xl[o] = (bf16_t)(nv - (float)h);
}

// ---------------------------------------------------------------------------
__global__ __launch_bounds__(256) void embed_split_kernel(
    const float* __restrict__ embed, bf16_t* __restrict__ eh, bf16_t* __restrict__ el)
{
  const int i = (blockIdx.x * 256 + threadIdx.x) << 2;
  float4 v = *(const float4*)(embed + i);
  bf16_t h0 = (bf16_t)v.x, h1 = (bf16_t)v.y, h2 = (bf16_t)v.z, h3 = (bf16_t)v.w;
  bf16x4 hv = {h0, h1, h2, h3};
  bf16x4 lv = {(bf16_t)(v.x - (float)h0), (bf16_t)(v.y - (float)h1),
               (bf16_t)(v.z - (float)h2), (bf16_t)(v.w - (float)h3)};
  *(bf16x4*)(eh + i) = hv;
  *(bf16x4*)(el + i) = lv;
}

// ---------------------------------------------------------------------------
// Phase 1 (panel): d~ via bf16x3 MFMA. Block 256x128, 4 waves (2x2), wave
// tile 128x64. Writes P = exp(10 d~) bf16 [PROWS][NE] in PERMUTED col layout:
// pcol = colgroup*64 + (lane&15)*4 + n  (true col = colgroup*64 + n*16 + (lane&15))
// so each thread stores one bf16x4 (coalesced) instead of 4 scalar bf16.
// Also rowmin key + Z + S1 (final per panel since all cols covered).
// ---------------------------------------------------------------------------
__global__ __launch_bounds__(256) void phase1_mfma_kernel(
    const bf16_t* __restrict__ xh, const bf16_t* __restrict__ xl,
    const bf16_t* __restrict__ eh, const bf16_t* __restrict__ el,
    const int rowbase,
    u64* __restrict__ rowmin, float* __restrict__ rowZ, float* __restrict__ rowS1,
    bf16_t* __restrict__ P)
{
  __shared__ bf16_t Ah[PM * LSTR];
  __shared__ bf16_t Al[PM * LSTR];
  __shared__ bf16_t Bh[PN * LSTR];
  __shared__ bf16_t Bl[PN * LSTR];
  const int tid  = threadIdx.x;
  const int lane = tid & 63;
  const int wave = tid >> 6;
  const int wm = wave >> 1, wn = wave & 1;   // wave tile: rows 128*wm, cols 64*wn
  const int brow = blockIdx.x * PM;          // panel-local row base
  const int bcol = blockIdx.y * PN;          // global col base

  f32x4 acc[8][4] = {};

  for (int k0 = 0; k0 < EDIM; k0 += PK) {
    __syncthreads();
#pragma unroll
    for (int p = 0; p < 4; ++p) {           // A: 256 rows x 32k
      const int idx = tid + (p << 8);
      const int r = idx >> 2, kc = (idx & 3) << 3;
      const size_t g = (size_t)(rowbase + brow + r) * EDIM + k0 + kc;
      *(bf16x8*)&Ah[r * LSTR + kc] = *(const bf16x8*)(xh + g);
      *(bf16x8*)&Al[r * LSTR + kc] = *(const bf16x8*)(xl + g);
    }
#pragma unroll
    for (int p = 0; p < 2; ++p) {           // B: 128 rows x 32k
      const int idx = tid + (p << 8);
      const int r = idx >> 2, kc = (idx & 3) << 3;
      const size_t g = (size_t)(bcol + r) * EDIM + k0 + kc;
      *(bf16x8*)&Bh[r * LSTR + kc] = *(const bf16x8*)(eh + g);
      *(bf16x8*)&Bl[r * LSTR + kc] = *(const bf16x8*)(el + g);
    }
    __syncthreads();
    const int koff = (lane >> 4) << 3;      // 0,8,16,24
    bf16x8 bhf[4], blf[4];
#pragma unroll
    for (int n = 0; n < 4; ++n) {
      const int c = (wn << 6) + (n << 4) + (lane & 15);
      bhf[n] = *(const bf16x8*)&Bh[c * LSTR + koff];
      blf[n] = *(const bf16x8*)&Bl[c * LSTR + koff];
    }
#pragma unroll
    for (int m = 0; m < 8; ++m) {
      const int r = (wm << 7) + (m << 4) + (lane & 15);
      bf16x8 ahf = *(const bf16x8*)&Ah[r * LSTR + koff];
      bf16x8 alf = *(const bf16x8*)&Al[r * LSTR + koff];
#pragma unroll
      for (int n = 0; n < 4; ++n) {
        acc[m][n] = __builtin_amdgcn_mfma_f32_16x16x32_bf16(ahf, bhf[n], acc[m][n], 0, 0, 0);
        acc[m][n] = __builtin_amdgcn_mfma_f32_16x16x32_bf16(ahf, blf[n], acc[m][n], 0, 0, 0);
        acc[m][n] = __builtin_amdgcn_mfma_f32_16x16x32_bf16(alf, bhf[n], acc[m][n], 0, 0, 0);
      }
    }
  }

  // epilogue: C/D layout col = lane&15 (+n*16), row = (lane>>4)*4 + q (+m*16)
  const int colg  = bcol + (wn << 6) + (lane & 15);    // true col base
  const int pbase = bcol + (wn << 6) + ((lane & 15) << 2); // permuted store base
  const int rl0   = brow + (wm << 7) + ((lane >> 4) << 2);
#pragma unroll
  for (int m = 0; m < 8; ++m) {
#pragma unroll
    for (int q = 0; q < 4; ++q) {
      const int rl = rl0 + (m << 4) + q;      // panel-local row
      float Z = 0.f, S1 = 0.f;
      u64 mk = ~0ull;
      bf16_t evv[4];
#pragma unroll
      for (int n = 0; n < 4; ++n) {
        float d = acc[m][n][q];
        float l = 10.f * d;
        float e = __expf(l);
        Z += e; S1 += l * e;
        evv[n] = (bf16_t)e;
        u64 key = ((u64)__float_as_uint(d + 2.0f) << 32) | (unsigned)(colg + (n << 4));
        if (key < mk) mk = key;
      }
      bf16x4 pv = {evv[0], evv[1], evv[2], evv[3]};
      *(bf16x4*)(P + (size_t)rl * NE + pbase) = pv;
#pragma unroll
      for (int off = 1; off < 16; off <<= 1) {
        u64 ok = __shfl_xor(mk, off);
        if (ok < mk) mk = ok;
        Z  += __shfl_xor(Z, off);
        S1 += __shfl_xor(S1, off);
      }
      if ((lane & 15) == 0) {
        const int rg = rowbase + rl;
        atomicMin(rowmin + rg, mk);
        atomicAdd(rowZ + rg, Z);
        atomicAdd(rowS1 + rg, S1);
      }
    }
  }
}

// ---------------------------------------------------------------------------
// Column reduce v2: vectorized bf16x4, 4 cols/thread over 64 rows.
// ap accumulated in PERMUTED col space (entropy is permutation-invariant).
// Candidates mapped back to TRUE col in the rare hit path.
// ---------------------------------------------------------------------------
__global__ __launch_bounds__(256) void colreduce_kernel(
    const bf16_t* __restrict__ P, const float* __restrict__ rowZ,
    const u64* __restrict__ rowmin, const int rowbase,
    float* __restrict__ ap, int* __restrict__ ccnt, int* __restrict__ clist)
{
  __shared__ float izs[64], ths[64];
  const int t = threadIdx.x;
  const int pc0 = blockIdx.x * 1024 + (t << 2);
  const int r0 = blockIdx.y * 64;           // panel-local
  if (t < 64) {
    const int rg = rowbase + r0 + t;
    izs[t] = 1.0f / rowZ[rg];
    float dmin = __uint_as_float((unsigned)(rowmin[rg] >> 32)) - 2.0f;
    ths[t] = __expf(10.f * (dmin + 3e-4f));
  }
  __syncthreads();
  const int Bbase = pc0 & ~63;              // 64-col group base (same in both spaces)
  const int sub   = (pc0 & 63) >> 2;        // original lane&15
  float s0 = 0.f, s1 = 0.f, s2 = 0.f, s3 = 0.f;
  for (int r = 0; r < 64; ++r) {
    bf16x4 p4 = *(const bf16x4*)(P + (size_t)(r0 + r) * NE + pc0);
    float p0 = (float)p4[0], p1 = (float)p4[1], p2 = (float)p4[2], p3 = (float)p4[3];
    float iz = izs[r], th = ths[r];
    s0 = fmaf(p0, iz, s0); s1 = fmaf(p1, iz, s1);
    s2 = fmaf(p2, iz, s2); s3 = fmaf(p3, iz, s3);
    float pm = fminf(fminf(p0, p1), fminf(p2, p3));
    if (pm <= th) {                         // rare
      const int rg = rowbase + r0 + r;
      float pvv[4] = {p0, p1, p2, p3};
      for (int n = 0; n < 4; ++n)
        if (pvv[n] <= th) {
          int pos = atomicAdd(ccnt + rg, 1);
          if (pos < CANDCAP) clist[(rg << 4) + pos] = Bbase + (n << 4) + sub;
        }
    }
  }
  atomicAdd(ap + pc0 + 0, s0); atomicAdd(ap + pc0 + 1, s1);
  atomicAdd(ap + pc0 + 2, s2); atomicAdd(ap + pc0 + 3, s3);
}

// ---------------------------------------------------------------------------
// entropy_to_min partials over all rows (after all panels)
// ---------------------------------------------------------------------------
__global__ __launch_bounds__(256) void rowent_kernel(
    const float* __restrict__ rowZ, const float* __restrict__ rowS1,
    float* __restrict__ scal)
{
  __shared__ float sb[4];
  const int r = blockIdx.x * 256 + threadIdx.x;
  const int t = threadIdx.x;
  float Z = rowZ[r], S1 = rowS1[r];
  float ent = logf(Z) - S1 / Z;
#pragma unroll
  for (int off = 32; off >= 1; off >>= 1) ent += __shfl_xor(ent, off);
  if ((t & 63) == 0) sb[t >> 6] = ent;
  __syncthreads();
  if (t == 0) atomicAdd(scal + 1, sb[0] + sb[1] + sb[2] + sb[3]);
}

// ---------------------------------------------------------------------------
// Repair: exact fp32 argmin over candidate set; lexicographic (d, idx) min.
// Also builds float bins + int bins (for the counting sort).
// ---------------------------------------------------------------------------
__global__ __launch_bounds__(256) void repair_kernel(
    const float* __restrict__ xnf, const float* __restrict__ embed,
    const u64* __restrict__ rowmin, const int* __restrict__ ccnt,
    const int* __restrict__ clist, int* __restrict__ indw,
    float* __restrict__ bins, int* __restrict__ binsI, float* __restrict__ out)
{
  const int t = threadIdx.x;
  const int row = blockIdx.x * 64 + (t >> 2);
  const int sub = t & 3;
  const int base = ((int)(unsigned)(rowmin[row] & 0xFFFFFFFFull)) & (NE - 1);
  int cnt = ccnt[row];
  if (cnt > CANDCAP) cnt = CANDCAP;
  float bestD = 1e30f;
  int bestI = NE;
  const float* xr = xnf + (size_t)row * EDIM + (sub << 6);
  for (int j = -1; j < cnt; ++j) {
    const int c = (j < 0) ? base : (clist[(row << 4) + j] & (NE - 1));
    const float* er = embed + (size_t)c * EDIM + (sub << 6);
    float s = 0.f;
#pragma unroll
    for (int k = 0; k < 64; k += 4) {
      float4 a = *(const float4*)(xr + k);
      float4 b = *(const float4*)(er + k);
      s = fmaf(a.x, b.x, s); s = fmaf(a.y, b.y, s);
      s = fmaf(a.z, b.z, s); s = fmaf(a.w, b.w, s);
    }
    s += __shfl_xor(s, 1);
    s += __shfl_xor(s, 2);
    if (s < bestD || (s == bestD && c < bestI)) { bestD = s; bestI = c; }
  }
  if (sub == 0) {
    indw[row] = bestI;
    out[OFF_IND + row] = (float)bestI;
    atomicAdd(bins + bestI, 1.0f);
    atomicAdd(binsI + bestI, 1);
  }
}

// ---------------------------------------------------------------------------
// Counting-sort prep: exclusive prefix over int bins -> offs + cursor.
// ---------------------------------------------------------------------------
__global__ __launch_bounds__(256) void sortprep_kernel(
    const int* __restrict__ binsI, int* __restrict__ offs, int* __restrict__ cursor)
{
  __shared__ int ssum[256];
  const int t = threadIdx.x;
  const int base = t * 32;
  int loc[32];
  int cnt = 0;
#pragma unroll
  for (int j = 0; j < 32; ++j) { loc[j] = cnt; cnt += binsI[base + j]; }
  ssum[t] = cnt;
  __syncthreads();
  for (int off = 1; off < 256; off <<= 1) {
    int v = (t >= off) ? ssum[t - off] : 0;
    __syncthreads();
    ssum[t] += v;
    __syncthreads();
  }
  int run = (t > 0) ? ssum[t - 1] : 0;
#pragma unroll
  for (int j = 0; j < 32; ++j) {
    offs[base + j]   = run + loc[j];
    cursor[base + j] = run + loc[j];
  }
}

// ---------------------------------------------------------------------------
__global__ __launch_bounds__(256) void rowsort_kernel(
    const int* __restrict__ indw, int* __restrict__ cursor, int* __restrict__ sorted)
{
  const int r = blockIdx.x * 256 + threadIdx.x;
  const int ind = indw[r] & (NE - 1);
  int pos = atomicAdd(cursor + ind, 1);
  sorted[pos & (NROWS - 1)] = r;
}

// ---------------------------------------------------------------------------
// esum + commit via sorted rows: one block per code, NO fp32 atomics on esum.
// Writes esum in full (no memset needed).
// ---------------------------------------------------------------------------
__global__ __launch_bounds__(256) void esum_commit_kernel(
    const int* __restrict__ offs, const int* __restrict__ binsI,
    const int* __restrict__ sorted, const float* __restrict__ xnf,
    const float* __restrict__ embed, float* __restrict__ esum,
    float* __restrict__ scal)
{
  __shared__ float sb[4];
  const int c = blockIdx.x, t = threadIdx.x;
  const float ev = embed[(size_t)c * EDIM + t];
  const int start = offs[c];
  const int cnt = binsI[c];
  float s = 0.f, cm = 0.f;
  for (int j = 0; j < cnt; ++j) {
    const int r = sorted[(start + j) & (NROWS - 1)];
    float xv = xnf[(size_t)r * EDIM + t];
    s += xv;
    float df = ev - xv;
    cm = fmaf(df, df, cm);
  }
  esum[(size_t)c * EDIM + t] = s;
#pragma unroll
  for (int off = 32; off >= 1; off >>= 1) cm += __shfl_xor(cm, off);
  if ((t & 63) == 0) sb[t >> 6] = cm;
  __syncthreads();
  if (t == 0) atomicAdd(scal + 2, sb[0] + sb[1] + sb[2] + sb[3]);
}

// ---------------------------------------------------------------------------
__global__ __launch_bounds__(256) void scalars_kernel(
    const float* __restrict__ ap, const float* __restrict__ scal, float* __restrict__ out)
{
  __shared__ float sb[4];
  const int t = threadIdx.x;
  float h = 0.f;
  for (int c = t; c < NE; c += 256) {
    float apv = ap[c] * (1.0f / NROWS);
    h -= apv * logf(apv);
  }
#pragma unroll
  for (int off = 32; off >= 1; off >>= 1) h += __shfl_xor(h, off);
  if ((t & 63) == 0) sb[t >> 6] = h;
  __syncthreads();
  if (t == 0) {
    float Hmax = sb[0] + sb[1] + sb[2] + sb[3];
    float commit = scal[2] * (1.0f / ((float)NROWS * (float)EDIM));
    float emin = scal[1] * (1.0f / (float)NROWS);
    out[OFF_LOSS] = commit - Hmax;
    out[OFF_EMIN] = emin;
    out[OFF_CMT]  = commit;
  }
}

// ---------------------------------------------------------------------------
__global__ __launch_bounds__(256) void cluster_kernel(
    const float* __restrict__ cs_in, const float* __restrict__ bins,
    float* __restrict__ cn, float* __restrict__ scal)
{
  __shared__ float sb[4];
  const int c = blockIdx.x * 256 + threadIdx.x;
  const int t = threadIdx.x;
  float v = cs_in[c] * 0.99f + bins[c] * 0.01f;
  cn[c] = v;
  float s = v;
#pragma unroll
  for (int off = 32; off >= 1; off >>= 1) s += __shfl_xor(s, off);
  if ((t & 63) == 0) sb[t >> 6] = s;
  __syncthreads();
  if (t == 0) atomicAdd(scal + 0, sb[0] + sb[1] + sb[2] + sb[3]);
}

// ---------------------------------------------------------------------------
__global__ __launch_bounds__(256) void scan_kernel(
    const float* __restrict__ cn, const float* __restrict__ scal,
    int* __restrict__ idxs, float* __restrict__ csm, float* __restrict__ out)
{
  __shared__ int ssum[256];
  const int t = threadIdx.x;
  const int base = t * 32;
  int cnt = 0;
  for (int j = 0; j < 32; ++j) cnt += (cn[base + j] < 0.1f) ? 1 : 0;
  ssum[t] = cnt;
  __syncthreads();
  for (int off = 1; off < 256; off <<= 1) {
    int v = (t >= off) ? ssum[t - off] : 0;
    __syncthreads();
    ssum[t] += v;
    __syncthreads();
  }
  int run = (t > 0) ? ssum[t - 1] : 0;
  const float total = scal[0];
  const float dscale = total / (total + (float)NE * 1e-5f);
  for (int j = 0; j < 32; ++j) {
    float v = cn[base + j];
    bool ex = v < 0.1f;                 // DEAD_THRESH * RATIO
    run += ex ? 1 : 0;
    int idx = run - 1; if (idx < 0) idx = 0;
    idx &= (NROWS - 1);
    idxs[base + j] = idx;
    csm[base + j] = (v + 1e-5f) * dscale;
    out[OFF_CSF + base + j] = ex ? 0.12f : v;   // RESET_CS*RATIO
  }
}

// ---------------------------------------------------------------------------
__global__ __launch_bounds__(256) void embed_out_kernel(
    const float* __restrict__ cn, const float* __restrict__ csm,
    const int* __restrict__ idxs, const float* __restrict__ xn,
    const float* __restrict__ embed_avg, const float* __restrict__ esum,
    float* __restrict__ out)
{
  const int c = blockIdx.x, t = threadIdx.x;
  float oe, oa;
  if (cn[c] < 0.1f) {
    float s = xn[(size_t)(idxs[c] & (NROWS - 1)) * EDIM + t];
    oe = s; oa = s * 0.12f;
  } else {
    float an = embed_avg[(size_t)c * EDIM + t] * 0.99f
             + esum[(size_t)c * EDIM + t] * 0.01f;
    oa = an; oe = an / csm[c];
  }
  out[OFF_EMB  + (size_t)c * EDIM + t] = oe;
  out[OFF_EAVG + (size_t)c * EDIM + t] = oa;
}

// ---------------------------------------------------------------------------
extern "C" void kernel_launch(void* const* d_in, const int* in_sizes, int n_in,
                              void* d_out, int out_size, void* d_ws, size_t ws_size,
                              hipStream_t stream)
{
  const float* x         = (const float*)d_in[0];
  const float* W_in      = (const float*)d_in[1];
  const float* b_in      = (const float*)d_in[2];
  const float* W_out     = (const float*)d_in[3];
  const float* b_out     = (const float*)d_in[4];
  const float* embed     = (const float*)d_in[5];
  const float* embed_avg = (const float*)d_in[6];
  const float* cs_in     = (const float*)d_in[7];
  float* out = (float*)d_out;
  char* ws = (char*)d_ws;

  if (ws_size < (size_t)W_END) {   // guard (proven not to fire)
    zero_out_kernel<<<(out_size + 255) / 256, 256, 0, stream>>>(out, out_size);
    return;
  }

  bf16_t* xh = (bf16_t*)(ws + W_XN);
  bf16_t* xl = (bf16_t*)(ws + W_XN + 8388608u);
  bf16_t* eh = (bf16_t*)(ws + W_ESUM);
  bf16_t* el = (bf16_t*)(ws + W_ESUM + 4194304u);
  float* esum  = (float*)(ws + W_ESUM);
  u64*   rowmin= (u64*)  (ws + W_RMIN);
  int*   offs  = (int*)  (ws + W_RMIN);            // reuses rowmin AFTER repair
  int*   cursor= offs + NE;
  float* rowZ  = (float*)(ws + W_RZ);
  float* rowS1 = (float*)(ws + W_RS1);
  int*   binsI = (int*)  (ws + W_INVZ);
  int*   indw  = (int*)  (ws + W_INDW);
  float* bins  = (float*)(ws + W_BINS);
  float* cn    = (float*)(ws + W_CN);
  float* csm   = (float*)(ws + W_CSM);
  int*   idxs  = (int*)  (ws + W_IDXS);
  float* ap    = (float*)(ws + W_AP);
  float* scal  = (float*)(ws + W_SCAL);

  // d_out scratch:
  //   z_q region: [0,16MB) fp32 xn ; [16MB,48MB) bf16 P panel (ends at OFF_IND)
  //   emb region: ccnt[16384] + clist[16384*16] + sorted[16384] (pre-embed_out)
  float*  xnf    = out + OFF_ZQ;
  bf16_t* Pbuf   = (bf16_t*)(out + OFF_ZQ + 4194304);
  int*    ccnt   = (int*)(out + OFF_EMB);
  int*    clist  = ccnt + NROWS;
  int*    sorted = clist + NROWS * CANDCAP;

  hipMemsetAsync(ws + W_RMIN, 0xFF, W_RZ - W_RMIN, stream); // rowmin = ~0
  hipMemsetAsync(ws + W_RZ,   0,    W_END - W_RZ,  stream); // rowZ..scal = 0 (incl binsI)
  hipMemsetAsync(ccnt, 0, NROWS * sizeof(int), stream);     // candidate counts

  // 1. x_proj (fp32 into d_out scratch)
  gemm_in_kernel<<<dim3(NROWS / 64, EDIM / 64), 256, 0, stream>>>(
      x, W_in, b_in, xnf);
  // 2. l2norm + bf16 hi/lo planes
  l2norm_split_kernel<<<NROWS, 256, 0, stream>>>(xnf, xh, xl);
  // 3. embed bf16 hi/lo planes (esum region until panels done)
  embed_split_kernel<<<(NE * EDIM / 4) / 256, 256, 0, stream>>>(embed, eh, el);
  // 4. panel loop: MFMA similarity + permuted P store, then vector column-reduce
  for (int p = 0; p < NROWS / PROWS; ++p) {
    const int rowbase = p * PROWS;
    phase1_mfma_kernel<<<dim3(PROWS / PM, NE / PN), 256, 0, stream>>>(
        xh, xl, eh, el, rowbase, rowmin, rowZ, rowS1, Pbuf);
    colreduce_kernel<<<dim3(NE / 1024, PROWS / 64), 256, 0, stream>>>(
        Pbuf, rowZ, rowmin, rowbase, ap, ccnt, clist);
  }
  // 5. entropy_to_min partials
  rowent_kernel<<<NROWS / 256, 256, 0, stream>>>(rowZ, rowS1, scal);
  // 6. exact argmin repair (+ bins / binsI)
  repair_kernel<<<NROWS / 64, 256, 0, stream>>>(
      xnf, embed, rowmin, ccnt, clist, indw, bins, binsI, out);
  // 7. counting sort of rows by code (rowmin region reused for offs/cursor)
  sortprep_kernel<<<1, 256, 0, stream>>>(binsI, offs, cursor);
  rowsort_kernel<<<NROWS / 256, 256, 0, stream>>>(indw, cursor, sorted);
  // 8. esum + commit loss (writes esum fully; eh/el dead now)
  esum_commit_kernel<<<NE, 256, 0, stream>>>(
      offs, binsI, sorted, xnf, embed, esum, scal);
  // 9. cluster_new + total
  cluster_kernel<<<NE / 256, 256, 0, stream>>>(cs_in, bins, cn, scal);
  // 10. expiry scan + cluster_final
  scan_kernel<<<1, 256, 0, stream>>>(cn, scal, idxs, csm, out);
  // 11. scalar outputs
  scalars_kernel<<<1, 256, 0, stream>>>(ap, scal, out);
  // 12. embed_final / embed_avg_final (reads fp32 xn scratch)
  embed_out_kernel<<<NE, 256, 0, stream>>>(cn, csm, idxs, xnf, embed_avg, esum, out);
  // 13. z_q GEMM LAST (overwrites z_q scratch incl. P)
  gemm_out_kernel<<<dim3(NROWS / 64, ODIM / 64), 256, 0, stream>>>(
      embed, W_out, b_out, indw, out + OFF_ZQ);
}

// Round 5
// 1167.898 us; speedup vs baseline: 1.4475x; 1.2378x over previous
//
#include <hip/hip_runtime.h>
#include <hip/hip_bf16.h>

typedef unsigned long long u64;
typedef __bf16 bf16_t;
typedef __attribute__((ext_vector_type(8))) __bf16 bf16x8;
typedef __attribute__((ext_vector_type(4))) __bf16 bf16x4;
typedef __attribute__((ext_vector_type(4))) float f32x4;

#define NROWS 16384
#define KLAT  768
#define EDIM  256
#define NE    8192
#define ODIM  768

// output element offsets (FLOAT32 elements — d_out is fp32, 16,801,795 elems)
#define OFF_ZQ   0
#define OFF_IND  12582912
#define OFF_LOSS 12599296
#define OFF_EMB  12599297
#define OFF_EAVG 14696449
#define OFF_CSF  16793601
#define OFF_EMIN 16801793
#define OFF_CMT  16801794

// workspace layout (~25.76 MB proven)
#define W_XN    0u           // bf16 xh (8MB) + xl (8MB)
#define W_ESUM  16777216u    // bf16 eh (4MB) + el (4MB); later f32 esum (written in full)
#define W_RMIN  25165824u    // u64 rowmin [16384]; after repair: i32 offs[8192]+cursor[8192]
#define W_RZ    25296896u    // f32 rowZ
#define W_RS1   25362432u    // f32 rowS1
#define W_INVZ  25427968u    // i32 binsI [8192]
#define W_INDW  25493504u    // i32 ind
#define W_BINS  25559040u    // f32 bins [8192]
#define W_CN    25591808u    // f32 cluster_new
#define W_CSM   25624576u    // f32 cs smoothed
#define W_IDXS  25657344u    // i32 sampled idx
#define W_AP    25690112u    // f32 ap [8192] (PERMUTED col space — entropy invariant)
#define W_SCAL  25722880u    // f32 scal[4]
#define W_END   25722896u

#define CANDCAP 16
#define PROWS   2048         // panel rows
#define PM      128          // phase1 block rows
#define PN      128          // phase1 block cols
#define PK      32           // phase1 K chunk

typedef __attribute__((address_space(3))) unsigned char lds_u8;
typedef __attribute__((address_space(1))) const unsigned char glb_u8;
static __device__ __forceinline__ void gload16(const void* g, void* l)
{
  __builtin_amdgcn_global_load_lds((glb_u8*)g, (lds_u8*)l, 16, 0, 0);
}

// ---------------------------------------------------------------------------
__global__ __launch_bounds__(256) void zero_out_kernel(float* __restrict__ out, int n)
{
  int i = blockIdx.x * 256 + threadIdx.x;
  if (i < n) out[i] = 0.0f;
}

// ---------------------------------------------------------------------------
// GEMM-in: x_proj[M][256] = x[M][768] @ W_in[256][768]^T + b_in  (fp32)
// ---------------------------------------------------------------------------
__global__ __launch_bounds__(256) void gemm_in_kernel(
    const float* __restrict__ A, const float* __restrict__ B,
    const float* __restrict__ bias, float* __restrict__ C)
{
  __shared__ float As[16][64];
  __shared__ float Bs[16][64];
  const int tid = threadIdx.x;
  const int tx = tid & 15, ty = tid >> 4;
  const int bm = blockIdx.x << 6, bn = blockIdx.y << 6;
  const int lr = tid >> 2, lk = (tid & 3) << 2;
  const size_t aoff = (size_t)(bm + lr) * KLAT;
  const size_t boff = (size_t)(bn + lr) * KLAT;
  float acc[4][4] = {};
  for (int k0 = 0; k0 < KLAT; k0 += 16) {
    __syncthreads();
    float4 av = *(const float4*)(A + aoff + k0 + lk);
    float4 bv = *(const float4*)(B + boff + k0 + lk);
    As[lk + 0][lr] = av.x; As[lk + 1][lr] = av.y; As[lk + 2][lr] = av.z; As[lk + 3][lr] = av.w;
    Bs[lk + 0][lr] = bv.x; Bs[lk + 1][lr] = bv.y; Bs[lk + 2][lr] = bv.z; Bs[lk + 3][lr] = bv.w;
    __syncthreads();
#pragma unroll
    for (int kk = 0; kk < 16; ++kk) {
      float4 a4 = *(const float4*)&As[kk][ty << 2];
      float4 b4 = *(const float4*)&Bs[kk][tx << 2];
      float ar[4] = {a4.x, a4.y, a4.z, a4.w};
      float br[4] = {b4.x, b4.y, b4.z, b4.w};
#pragma unroll
      for (int i = 0; i < 4; ++i)
#pragma unroll
        for (int j = 0; j < 4; ++j)
          acc[i][j] = fmaf(ar[i], br[j], acc[i][j]);
    }
  }
  float4 b4 = *(const float4*)(bias + bn + (tx << 2));
  float bb[4] = {b4.x, b4.y, b4.z, b4.w};
#pragma unroll
  for (int i = 0; i < 4; ++i) {
    const size_t row = (size_t)(bm + (ty << 2) + i);
    float4 o = make_float4(acc[i][0] + bb[0], acc[i][1] + bb[1],
                           acc[i][2] + bb[2], acc[i][3] + bb[3]);
    *(float4*)(C + row * EDIM + bn + (tx << 2)) = o;
  }
}

// ---------------------------------------------------------------------------
// GEMM-out: out[M][768] = embed[ind[M]][256] @ W_out[768][256]^T + b_out
// Runs LAST (overwrites the z_q scratch region).
// ---------------------------------------------------------------------------
__global__ __launch_bounds__(256) void gemm_out_kernel(
    const float* __restrict__ A, const float* __restrict__ B,
    const float* __restrict__ bias, const int* __restrict__ gather,
    float* __restrict__ C)
{
  __shared__ float As[16][64];
  __shared__ float Bs[16][64];
  const int tid = threadIdx.x;
  const int tx = tid & 15, ty = tid >> 4;
  const int bm = blockIdx.x << 6, bn = blockIdx.y << 6;
  const int lr = tid >> 2, lk = (tid & 3) << 2;
  const size_t arow = (size_t)(gather[bm + lr] & (NE - 1));
  const size_t aoff = arow * EDIM;
  const size_t boff = (size_t)(bn + lr) * EDIM;
  float acc[4][4] = {};
  for (int k0 = 0; k0 < EDIM; k0 += 16) {
    __syncthreads();
    float4 av = *(const float4*)(A + aoff + k0 + lk);
    float4 bv = *(const float4*)(B + boff + k0 + lk);
    As[lk + 0][lr] = av.x; As[lk + 1][lr] = av.y; As[lk + 2][lr] = av.z; As[lk + 3][lr] = av.w;
    Bs[lk + 0][lr] = bv.x; Bs[lk + 1][lr] = bv.y; Bs[lk + 2][lr] = bv.z; Bs[lk + 3][lr] = bv.w;
    __syncthreads();
#pragma unroll
    for (int kk = 0; kk < 16; ++kk) {
      float4 a4 = *(const float4*)&As[kk][ty << 2];
      float4 b4 = *(const float4*)&Bs[kk][tx << 2];
      float ar[4] = {a4.x, a4.y, a4.z, a4.w};
      float br[4] = {b4.x, b4.y, b4.z, b4.w};
#pragma unroll
      for (int i = 0; i < 4; ++i)
#pragma unroll
        for (int j = 0; j < 4; ++j)
          acc[i][j] = fmaf(ar[i], br[j], acc[i][j]);
    }
  }
  float4 b4 = *(const float4*)(bias + bn + (tx << 2));
  float bb[4] = {b4.x, b4.y, b4.z, b4.w};
#pragma unroll
  for (int i = 0; i < 4; ++i) {
    const size_t row = (size_t)(bm + (ty << 2) + i);
    float4 o = make_float4(acc[i][0] + bb[0], acc[i][1] + bb[1],
                           acc[i][2] + bb[2], acc[i][3] + bb[3]);
    *(float4*)(C + row * ODIM + bn + (tx << 2)) = o;
  }
}

// ---------------------------------------------------------------------------
// l2norm in place (fp32 in d_out scratch) + bf16 hi/lo planes
// ---------------------------------------------------------------------------
__global__ __launch_bounds__(256) void l2norm_split_kernel(
    float* __restrict__ xnf, bf16_t* __restrict__ xh, bf16_t* __restrict__ xl)
{
  __shared__ float sb[4];
  const int r = blockIdx.x, t = threadIdx.x;
  const size_t o = (size_t)r * EDIM + t;
  float v = xnf[o];
  float s = v * v;
#pragma unroll
  for (int off = 32; off >= 1; off >>= 1) s += __shfl_xor(s, off);
  if ((t & 63) == 0) sb[t >> 6] = s;
  __syncthreads();
  float tot = sb[0] + sb[1] + sb[2] + sb[3];
  float nv = v / sqrtf(tot);
  xnf[o] = nv;
  bf16_t h = (bf16_t)nv;
  xh[o] = h;
  xl[o] = (bf16_t)(nv - (float)h);
}

// ---------------------------------------------------------------------------
__global__ __launch_bounds__(256) void embed_split_kernel(
    const float* __restrict__ embed, bf16_t* __restrict__ eh, bf16_t* __restrict__ el)
{
  const int i = (blockIdx.x * 256 + threadIdx.x) << 2;
  float4 v = *(const float4*)(embed + i);
  bf16_t h0 = (bf16_t)v.x, h1 = (bf16_t)v.y, h2 = (bf16_t)v.z, h3 = (bf16_t)v.w;
  bf16x4 hv = {h0, h1, h2, h3};
  bf16x4 lv = {(bf16_t)(v.x - (float)h0), (bf16_t)(v.y - (float)h1),
               (bf16_t)(v.z - (float)h2), (bf16_t)(v.w - (float)h3)};
  *(bf16x4*)(eh + i) = hv;
  *(bf16x4*)(el + i) = lv;
}

// ---------------------------------------------------------------------------
// Phase 1 v3 (panel): d~ via bf16x3 MFMA.
// Block 128x128, 4 waves (2x2), wave tile 64x64 (4x4 frags of 16x16x32).
// LDS: interleaved rows of 128B = [hi 64B | lo 64B], XOR-swizzled slot^=(row&7).
// Staged via global_load_lds width=16 with pre-swizzled per-lane global source
// (LDS dest linear per call) -> zero LDS-write instructions, conflict-free
// ds_read_b128 (consecutive-8-lane windows hit 8 distinct 16B slots).
// Writes P = exp(10 d~) bf16 [PROWS][NE] in PERMUTED col layout (bf16x4
// coalesced; colreduce maps back). Also rowmin key + Z + S1.
// ---------------------------------------------------------------------------
__global__ __launch_bounds__(256) void phase1_mfma_kernel(
    const bf16_t* __restrict__ xh, const bf16_t* __restrict__ xl,
    const bf16_t* __restrict__ eh, const bf16_t* __restrict__ el,
    const int rowbase,
    u64* __restrict__ rowmin, float* __restrict__ rowZ, float* __restrict__ rowS1,
    bf16_t* __restrict__ P)
{
  __shared__ bf16_t Ab[PM * 64];   // 128 rows x 128B (hi|lo), swizzled
  __shared__ bf16_t Bb[PN * 64];
  const int tid  = threadIdx.x;
  const int lane = tid & 63;
  const int wave = tid >> 6;
  const int wm = wave >> 1, wn = wave & 1;
  const int brow = blockIdx.x * PM;          // panel-local row base
  const int bcol = blockIdx.y * PN;          // global col base

  // staging-lane invariants: lane l -> LDS (row = call + l>>3, slot = l&7);
  // global chunk = slot ^ (row&7); row&7 == l>>3 (call is a multiple of 8).
  const int srow8 = lane >> 3;               // 0..7
  const int chunk = (lane & 7) ^ srow8;      // 0..7; <4 => hi plane
  const bf16_t* gpa = (chunk & 4) ? xl : xh;
  const bf16_t* gpb = (chunk & 4) ? el : eh;
  const int within = (chunk & 3) << 3;       // bf16 offset in 64B window
  const int acall0 = wave << 5;              // this wave stages rows [acall0, acall0+32)

  // per-lane global row offsets (advance by PK each K-step)
  const bf16_t* ga0 = gpa + (size_t)(rowbase + brow + acall0 + srow8) * EDIM + within;
  const bf16_t* gb0 = gpb + (size_t)(bcol + acall0 + srow8) * EDIM + within;

  f32x4 acc[4][4] = {};

  for (int k0 = 0; k0 < EDIM; k0 += PK) {
    __syncthreads();                         // prior reads done before DMA lands
#pragma unroll
    for (int c = 0; c < 4; ++c) {
      const int rr = acall0 + (c << 3);      // LDS call-row (multiple of 8)
      gload16(ga0 + (size_t)(c << 3) * EDIM + k0, &Ab[rr * 64]);
      gload16(gb0 + (size_t)(c << 3) * EDIM + k0, &Bb[rr * 64]);
    }
    __syncthreads();                         // drains vmcnt (DMA) for all waves

    const int swz = lane & 7;
    const int sh  = (lane >> 4) ^ swz;       // hi slot (16B units)
    const int sl  = sh ^ 4;                  // lo slot
    const int ar0 = (wm << 6) + (lane & 15);
    const int br0 = (wn << 6) + (lane & 15);
    bf16x8 bhf[4], blf[4];
#pragma unroll
    for (int n = 0; n < 4; ++n) {
      const int r = br0 + (n << 4);
      bhf[n] = *(const bf16x8*)&Bb[r * 64 + (sh << 3)];
      blf[n] = *(const bf16x8*)&Bb[r * 64 + (sl << 3)];
    }
#pragma unroll
    for (int m = 0; m < 4; ++m) {
      const int r = ar0 + (m << 4);
      bf16x8 ahf = *(const bf16x8*)&Ab[r * 64 + (sh << 3)];
      bf16x8 alf = *(const bf16x8*)&Ab[r * 64 + (sl << 3)];
#pragma unroll
      for (int n = 0; n < 4; ++n) {
        acc[m][n] = __builtin_amdgcn_mfma_f32_16x16x32_bf16(ahf, bhf[n], acc[m][n], 0, 0, 0);
        acc[m][n] = __builtin_amdgcn_mfma_f32_16x16x32_bf16(ahf, blf[n], acc[m][n], 0, 0, 0);
        acc[m][n] = __builtin_amdgcn_mfma_f32_16x16x32_bf16(alf, bhf[n], acc[m][n], 0, 0, 0);
      }
    }
  }

  // epilogue: C/D layout col = lane&15 (+n*16), row = (lane>>4)*4 + q (+m*16)
  const int colg  = bcol + (wn << 6) + (lane & 15);        // true col base
  const int pbase = bcol + (wn << 6) + ((lane & 15) << 2); // permuted store base
  const int rl0   = brow + (wm << 6) + ((lane >> 4) << 2);
#pragma unroll
  for (int m = 0; m < 4; ++m) {
#pragma unroll
    for (int q = 0; q < 4; ++q) {
      const int rl = rl0 + (m << 4) + q;      // panel-local row
      float Z = 0.f, S1 = 0.f;
      u64 mk = ~0ull;
      bf16_t evv[4];
#pragma unroll
      for (int n = 0; n < 4; ++n) {
        float d = acc[m][n][q];
        float l = 10.f * d;
        float e = __expf(l);
        Z += e; S1 += l * e;
        evv[n] = (bf16_t)e;
        u64 key = ((u64)__float_as_uint(d + 2.0f) << 32) | (unsigned)(colg + (n << 4));
        if (key < mk) mk = key;
      }
      bf16x4 pv = {evv[0], evv[1], evv[2], evv[3]};
      *(bf16x4*)(P + (size_t)rl * NE + pbase) = pv;
#pragma unroll
      for (int off = 1; off < 16; off <<= 1) {
        u64 ok = __shfl_xor(mk, off);
        if (ok < mk) mk = ok;
        Z  += __shfl_xor(Z, off);
        S1 += __shfl_xor(S1, off);
      }
      if ((lane & 15) == 0) {
        const int rg = rowbase + rl;
        atomicMin(rowmin + rg, mk);
        atomicAdd(rowZ + rg, Z);
        atomicAdd(rowS1 + rg, S1);
      }
    }
  }
}

// ---------------------------------------------------------------------------
// Column reduce: vectorized bf16x4, 4 cols/thread over 64 rows.
// ap accumulated in PERMUTED col space (entropy is permutation-invariant).
// Candidates mapped back to TRUE col in the rare hit path.
// ---------------------------------------------------------------------------
__global__ __launch_bounds__(256) void colreduce_kernel(
    const bf16_t* __restrict__ P, const float* __restrict__ rowZ,
    const u64* __restrict__ rowmin, const int rowbase,
    float* __restrict__ ap, int* __restrict__ ccnt, int* __restrict__ clist)
{
  __shared__ float izs[64], ths[64];
  const int t = threadIdx.x;
  const int pc0 = blockIdx.x * 1024 + (t << 2);
  const int r0 = blockIdx.y * 64;           // panel-local
  if (t < 64) {
    const int rg = rowbase + r0 + t;
    izs[t] = 1.0f / rowZ[rg];
    float dmin = __uint_as_float((unsigned)(rowmin[rg] >> 32)) - 2.0f;
    ths[t] = __expf(10.f * (dmin + 3e-4f));
  }
  __syncthreads();
  const int Bbase = pc0 & ~63;              // 64-col group base (same in both spaces)
  const int sub   = (pc0 & 63) >> 2;        // original lane&15
  float s0 = 0.f, s1 = 0.f, s2 = 0.f, s3 = 0.f;
  for (int r = 0; r < 64; ++r) {
    bf16x4 p4 = *(const bf16x4*)(P + (size_t)(r0 + r) * NE + pc0);
    float p0 = (float)p4[0], p1 = (float)p4[1], p2 = (float)p4[2], p3 = (float)p4[3];
    float iz = izs[r], th = ths[r];
    s0 = fmaf(p0, iz, s0); s1 = fmaf(p1, iz, s1);
    s2 = fmaf(p2, iz, s2); s3 = fmaf(p3, iz, s3);
    float pm = fminf(fminf(p0, p1), fminf(p2, p3));
    if (pm <= th) {                         // rare
      const int rg = rowbase + r0 + r;
      float pvv[4] = {p0, p1, p2, p3};
      for (int n = 0; n < 4; ++n)
        if (pvv[n] <= th) {
          int pos = atomicAdd(ccnt + rg, 1);
          if (pos < CANDCAP) clist[(rg << 4) + pos] = Bbase + (n << 4) + sub;
        }
    }
  }
  atomicAdd(ap + pc0 + 0, s0); atomicAdd(ap + pc0 + 1, s1);
  atomicAdd(ap + pc0 + 2, s2); atomicAdd(ap + pc0 + 3, s3);
}

// ---------------------------------------------------------------------------
__global__ __launch_bounds__(256) void rowent_kernel(
    const float* __restrict__ rowZ, const float* __restrict__ rowS1,
    float* __restrict__ scal)
{
  __shared__ float sb[4];
  const int r = blockIdx.x * 256 + threadIdx.x;
  const int t = threadIdx.x;
  float Z = rowZ[r], S1 = rowS1[r];
  float ent = logf(Z) - S1 / Z;
#pragma unroll
  for (int off = 32; off >= 1; off >>= 1) ent += __shfl_xor(ent, off);
  if ((t & 63) == 0) sb[t >> 6] = ent;
  __syncthreads();
  if (t == 0) atomicAdd(scal + 1, sb[0] + sb[1] + sb[2] + sb[3]);
}

// ---------------------------------------------------------------------------
// Repair: exact fp32 argmin over candidate set; lexicographic (d, idx) min.
// Also builds float bins + int bins (for the counting sort).
// ---------------------------------------------------------------------------
__global__ __launch_bounds__(256) void repair_kernel(
    const float* __restrict__ xnf, const float* __restrict__ embed,
    const u64* __restrict__ rowmin, const int* __restrict__ ccnt,
    const int* __restrict__ clist, int* __restrict__ indw,
    float* __restrict__ bins, int* __restrict__ binsI, float* __restrict__ out)
{
  const int t = threadIdx.x;
  const int row = blockIdx.x * 64 + (t >> 2);
  const int sub = t & 3;
  const int base = ((int)(unsigned)(rowmin[row] & 0xFFFFFFFFull)) & (NE - 1);
  int cnt = ccnt[row];
  if (cnt > CANDCAP) cnt = CANDCAP;
  float bestD = 1e30f;
  int bestI = NE;
  const float* xr = xnf + (size_t)row * EDIM + (sub << 6);
  for (int j = -1; j < cnt; ++j) {
    const int c = (j < 0) ? base : (clist[(row << 4) + j] & (NE - 1));
    const float* er = embed + (size_t)c * EDIM + (sub << 6);
    float s = 0.f;
#pragma unroll
    for (int k = 0; k < 64; k += 4) {
      float4 a = *(const float4*)(xr + k);
      float4 b = *(const float4*)(er + k);
      s = fmaf(a.x, b.x, s); s = fmaf(a.y, b.y, s);
      s = fmaf(a.z, b.z, s); s = fmaf(a.w, b.w, s);
    }
    s += __shfl_xor(s, 1);
    s += __shfl_xor(s, 2);
    if (s < bestD || (s == bestD && c < bestI)) { bestD = s; bestI = c; }
  }
  if (sub == 0) {
    indw[row] = bestI;
    out[OFF_IND + row] = (float)bestI;
    atomicAdd(bins + bestI, 1.0f);
    atomicAdd(binsI + bestI, 1);
  }
}

// ---------------------------------------------------------------------------
__global__ __launch_bounds__(256) void sortprep_kernel(
    const int* __restrict__ binsI, int* __restrict__ offs, int* __restrict__ cursor)
{
  __shared__ int ssum[256];
  const int t = threadIdx.x;
  const int base = t * 32;
  int loc[32];
  int cnt = 0;
#pragma unroll
  for (int j = 0; j < 32; ++j) { loc[j] = cnt; cnt += binsI[base + j]; }
  ssum[t] = cnt;
  __syncthreads();
  for (int off = 1; off < 256; off <<= 1) {
    int v = (t >= off) ? ssum[t - off] : 0;
    __syncthreads();
    ssum[t] += v;
    __syncthreads();
  }
  int run = (t > 0) ? ssum[t - 1] : 0;
#pragma unroll
  for (int j = 0; j < 32; ++j) {
    offs[base + j]   = run + loc[j];
    cursor[base + j] = run + loc[j];
  }
}

// ---------------------------------------------------------------------------
__global__ __launch_bounds__(256) void rowsort_kernel(
    const int* __restrict__ indw, int* __restrict__ cursor, int* __restrict__ sorted)
{
  const int r = blockIdx.x * 256 + threadIdx.x;
  const int ind = indw[r] & (NE - 1);
  int pos = atomicAdd(cursor + ind, 1);
  sorted[pos & (NROWS - 1)] = r;
}

// ---------------------------------------------------------------------------
// esum + commit via sorted rows: one block per code, NO fp32 atomics on esum.
// ---------------------------------------------------------------------------
__global__ __launch_bounds__(256) void esum_commit_kernel(
    const int* __restrict__ offs, const int* __restrict__ binsI,
    const int* __restrict__ sorted, const float* __restrict__ xnf,
    const float* __restrict__ embed, float* __restrict__ esum,
    float* __restrict__ scal)
{
  __shared__ float sb[4];
  const int c = blockIdx.x, t = threadIdx.x;
  const float ev = embed[(size_t)c * EDIM + t];
  const int start = offs[c];
  const int cnt = binsI[c];
  float s = 0.f, cm = 0.f;
  for (int j = 0; j < cnt; ++j) {
    const int r = sorted[(start + j) & (NROWS - 1)];
    float xv = xnf[(size_t)r * EDIM + t];
    s += xv;
    float df = ev - xv;
    cm = fmaf(df, df, cm);
  }
  esum[(size_t)c * EDIM + t] = s;
#pragma unroll
  for (int off = 32; off >= 1; off >>= 1) cm += __shfl_xor(cm, off);
  if ((t & 63) == 0) sb[t >> 6] = cm;
  __syncthreads();
  if (t == 0) atomicAdd(scal + 2, sb[0] + sb[1] + sb[2] + sb[3]);
}

// ---------------------------------------------------------------------------
__global__ __launch_bounds__(256) void scalars_kernel(
    const float* __restrict__ ap, const float* __restrict__ scal, float* __restrict__ out)
{
  __shared__ float sb[4];
  const int t = threadIdx.x;
  float h = 0.f;
  for (int c = t; c < NE; c += 256) {
    float apv = ap[c] * (1.0f / NROWS);
    h -= apv * logf(apv);
  }
#pragma unroll
  for (int off = 32; off >= 1; off >>= 1) h += __shfl_xor(h, off);
  if ((t & 63) == 0) sb[t >> 6] = h;
  __syncthreads();
  if (t == 0) {
    float Hmax = sb[0] + sb[1] + sb[2] + sb[3];
    float commit = scal[2] * (1.0f / ((float)NROWS * (float)EDIM));
    float emin = scal[1] * (1.0f / (float)NROWS);
    out[OFF_LOSS] = commit - Hmax;
    out[OFF_EMIN] = emin;
    out[OFF_CMT]  = commit;
  }
}

// ---------------------------------------------------------------------------
__global__ __launch_bounds__(256) void cluster_kernel(
    const float* __restrict__ cs_in, const float* __restrict__ bins,
    float* __restrict__ cn, float* __restrict__ scal)
{
  __shared__ float sb[4];
  const int c = blockIdx.x * 256 + threadIdx.x;
  const int t = threadIdx.x;
  float v = cs_in[c] * 0.99f + bins[c] * 0.01f;
  cn[c] = v;
  float s = v;
#pragma unroll
  for (int off = 32; off >= 1; off >>= 1) s += __shfl_xor(s, off);
  if ((t & 63) == 0) sb[t >> 6] = s;
  __syncthreads();
  if (t == 0) atomicAdd(scal + 0, sb[0] + sb[1] + sb[2] + sb[3]);
}

// ---------------------------------------------------------------------------
__global__ __launch_bounds__(256) void scan_kernel(
    const float* __restrict__ cn, const float* __restrict__ scal,
    int* __restrict__ idxs, float* __restrict__ csm, float* __restrict__ out)
{
  __shared__ int ssum[256];
  const int t = threadIdx.x;
  const int base = t * 32;
  int cnt = 0;
  for (int j = 0; j < 32; ++j) cnt += (cn[base + j] < 0.1f) ? 1 : 0;
  ssum[t] = cnt;
  __syncthreads();
  for (int off = 1; off < 256; off <<= 1) {
    int v = (t >= off) ? ssum[t - off] : 0;
    __syncthreads();
    ssum[t] += v;
    __syncthreads();
  }
  int run = (t > 0) ? ssum[t - 1] : 0;
  const float total = scal[0];
  const float dscale = total / (total + (float)NE * 1e-5f);
  for (int j = 0; j < 32; ++j) {
    float v = cn[base + j];
    bool ex = v < 0.1f;                 // DEAD_THRESH * RATIO
    run += ex ? 1 : 0;
    int idx = run - 1; if (idx < 0) idx = 0;
    idx &= (NROWS - 1);
    idxs[base + j] = idx;
    csm[base + j] = (v + 1e-5f) * dscale;
    out[OFF_CSF + base + j] = ex ? 0.12f : v;   // RESET_CS*RATIO
  }
}

// ---------------------------------------------------------------------------
__global__ __launch_bounds__(256) void embed_out_kernel(
    const float* __restrict__ cn, const float* __restrict__ csm,
    const int* __restrict__ idxs, const float* __restrict__ xn,
    const float* __restrict__ embed_avg, const float* __restrict__ esum,
    float* __restrict__ out)
{
  const int c = blockIdx.x, t = threadIdx.x;
  float oe, oa;
  if (cn[c] < 0.1f) {
    float s = xn[(size_t)(idxs[c] & (NROWS - 1)) * EDIM + t];
    oe = s; oa = s * 0.12f;
  } else {
    float an = embed_avg[(size_t)c * EDIM + t] * 0.99f
             + esum[(size_t)c * EDIM + t] * 0.01f;
    oa = an; oe = an / csm[c];
  }
  out[OFF_EMB  + (size_t)c * EDIM + t] = oe;
  out[OFF_EAVG + (size_t)c * EDIM + t] = oa;
}

// ---------------------------------------------------------------------------
extern "C" void kernel_launch(void* const* d_in, const int* in_sizes, int n_in,
                              void* d_out, int out_size, void* d_ws, size_t ws_size,
                              hipStream_t stream)
{
  const float* x         = (const float*)d_in[0];
  const float* W_in      = (const float*)d_in[1];
  const float* b_in      = (const float*)d_in[2];
  const float* W_out     = (const float*)d_in[3];
  const float* b_out     = (const float*)d_in[4];
  const float* embed     = (const float*)d_in[5];
  const float* embed_avg = (const float*)d_in[6];
  const float* cs_in     = (const float*)d_in[7];
  float* out = (float*)d_out;
  char* ws = (char*)d_ws;

  if (ws_size < (size_t)W_END) {   // guard (proven not to fire)
    zero_out_kernel<<<(out_size + 255) / 256, 256, 0, stream>>>(out, out_size);
    return;
  }

  bf16_t* xh = (bf16_t*)(ws + W_XN);
  bf16_t* xl = (bf16_t*)(ws + W_XN + 8388608u);
  bf16_t* eh = (bf16_t*)(ws + W_ESUM);
  bf16_t* el = (bf16_t*)(ws + W_ESUM + 4194304u);
  float* esum  = (float*)(ws + W_ESUM);
  u64*   rowmin= (u64*)  (ws + W_RMIN);
  int*   offs  = (int*)  (ws + W_RMIN);            // reuses rowmin AFTER repair
  int*   cursor= offs + NE;
  float* rowZ  = (float*)(ws + W_RZ);
  float* rowS1 = (float*)(ws + W_RS1);
  int*   binsI = (int*)  (ws + W_INVZ);
  int*   indw  = (int*)  (ws + W_INDW);
  float* bins  = (float*)(ws + W_BINS);
  float* cn    = (float*)(ws + W_CN);
  float* csm   = (float*)(ws + W_CSM);
  int*   idxs  = (int*)  (ws + W_IDXS);
  float* ap    = (float*)(ws + W_AP);
  float* scal  = (float*)(ws + W_SCAL);

  // d_out scratch:
  //   z_q region: [0,16MB) fp32 xn ; [16MB,48MB) bf16 P panel (ends at OFF_IND)
  //   emb region: ccnt[16384] + clist[16384*16] + sorted[16384] (pre-embed_out)
  float*  xnf    = out + OFF_ZQ;
  bf16_t* Pbuf   = (bf16_t*)(out + OFF_ZQ + 4194304);
  int*    ccnt   = (int*)(out + OFF_EMB);
  int*    clist  = ccnt + NROWS;
  int*    sorted = clist + NROWS * CANDCAP;

  hipMemsetAsync(ws + W_RMIN, 0xFF, W_RZ - W_RMIN, stream); // rowmin = ~0
  hipMemsetAsync(ws + W_RZ,   0,    W_END - W_RZ,  stream); // rowZ..scal = 0 (incl binsI)
  hipMemsetAsync(ccnt, 0, NROWS * sizeof(int), stream);     // candidate counts

  // 1. x_proj (fp32 into d_out scratch)
  gemm_in_kernel<<<dim3(NROWS / 64, EDIM / 64), 256, 0, stream>>>(
      x, W_in, b_in, xnf);
  // 2. l2norm + bf16 hi/lo planes
  l2norm_split_kernel<<<NROWS, 256, 0, stream>>>(xnf, xh, xl);
  // 3. embed bf16 hi/lo planes (esum region until panels done)
  embed_split_kernel<<<(NE * EDIM / 4) / 256, 256, 0, stream>>>(embed, eh, el);
  // 4. panel loop: MFMA similarity + permuted P store, then vector column-reduce
  for (int p = 0; p < NROWS / PROWS; ++p) {
    const int rowbase = p * PROWS;
    phase1_mfma_kernel<<<dim3(PROWS / PM, NE / PN), 256, 0, stream>>>(
        xh, xl, eh, el, rowbase, rowmin, rowZ, rowS1, Pbuf);
    colreduce_kernel<<<dim3(NE / 1024, PROWS / 64), 256, 0, stream>>>(
        Pbuf, rowZ, rowmin, rowbase, ap, ccnt, clist);
  }
  // 5. entropy_to_min partials
  rowent_kernel<<<NROWS / 256, 256, 0, stream>>>(rowZ, rowS1, scal);
  // 6. exact argmin repair (+ bins / binsI)
  repair_kernel<<<NROWS / 64, 256, 0, stream>>>(
      xnf, embed, rowmin, ccnt, clist, indw, bins, binsI, out);
  // 7. counting sort of rows by code (rowmin region reused for offs/cursor)
  sortprep_kernel<<<1, 256, 0, stream>>>(binsI, offs, cursor);
  rowsort_kernel<<<NROWS / 256, 256, 0, stream>>>(indw, cursor, sorted);
  // 8. esum + commit loss (writes esum fully; eh/el dead now)
  esum_commit_kernel<<<NE, 256, 0, stream>>>(
      offs, binsI, sorted, xnf, embed, esum, scal);
  // 9. cluster_new + total
  cluster_kernel<<<NE / 256, 256, 0, stream>>>(cs_in, bins, cn, scal);
  // 10. expiry scan + cluster_final
  scan_kernel<<<1, 256, 0, stream>>>(cn, scal, idxs, csm, out);
  // 11. scalar outputs
  scalars_kernel<<<1, 256, 0, stream>>>(ap, scal, out);
  // 12. embed_final / embed_avg_final (reads fp32 xn scratch)
  embed_out_kernel<<<NE, 256, 0, stream>>>(cn, csm, idxs, xnf, embed_avg, esum, out);
  // 13. z_q GEMM LAST (overwrites z_q scratch incl. P)
  gemm_out_kernel<<<dim3(NROWS / 64, ODIM / 64), 256, 0, stream>>>(
      embed, W_out, b_out, indw, out + OFF_ZQ);
}

// Round 6
// 1102.453 us; speedup vs baseline: 1.5334x; 1.0594x over previous
//
#include <hip/hip_runtime.h>
#include <hip/hip_bf16.h>

typedef unsigned long long u64;
typedef __bf16 bf16_t;
typedef __attribute__((ext_vector_type(8))) __bf16 bf16x8;
typedef __attribute__((ext_vector_type(4))) __bf16 bf16x4;
typedef __attribute__((ext_vector_type(4))) float f32x4;

#define NROWS 16384
#define KLAT  768
#define EDIM  256
#define NE    8192
#define ODIM  768

// output element offsets (FLOAT32 elements — d_out is fp32, 16,801,795 elems)
#define OFF_ZQ   0
#define OFF_IND  12582912
#define OFF_LOSS 12599296
#define OFF_EMB  12599297
#define OFF_EAVG 14696449
#define OFF_CSF  16793601
#define OFF_EMIN 16801793
#define OFF_CMT  16801794

// workspace layout (~25.76 MB proven)
// W_XN: bf16 xh (8MB) + xl (8MB) during panels; AFTER panels:
//       [0,8MB) f32 esum ; [8MB, 8MB+768KB) bf16 W_out hi/lo planes
#define W_XN    0u
#define W_ESUM  16777216u    // bf16 eh (4MB) + el (4MB) — live until gemm_out (last)
#define W_RMIN  25165824u    // u64 rowmin [16384]; after repair: i32 offs+cursor
#define W_RZ    25296896u    // f32 rowZ
#define W_RS1   25362432u    // f32 rowS1
#define W_INVZ  25427968u    // i32 binsI [8192]
#define W_INDW  25493504u    // i32 ind
#define W_BINS  25559040u    // f32 bins [8192]
#define W_CN    25591808u    // f32 cluster_new
#define W_CSM   25624576u    // f32 cs smoothed
#define W_IDXS  25657344u    // i32 sampled idx
#define W_AP    25690112u    // f32 ap [8192] (PERMUTED col space — entropy invariant)
#define W_SCAL  25722880u    // f32 scal[4]
#define W_END   25722896u

#define CANDCAP 16
#define PROWS   2048         // panel rows
#define PM      128          // MFMA block rows
#define PN      128          // MFMA block cols
#define PK      32           // MFMA K chunk

typedef __attribute__((address_space(3))) unsigned char lds_u8;
typedef __attribute__((address_space(1))) const unsigned char glb_u8;
static __device__ __forceinline__ void gload16(const void* g, void* l)
{
  __builtin_amdgcn_global_load_lds((glb_u8*)g, (lds_u8*)l, 16, 0, 0);
}

// ---------------------------------------------------------------------------
__global__ __launch_bounds__(256) void zero_out_kernel(float* __restrict__ out, int n)
{
  int i = blockIdx.x * 256 + threadIdx.x;
  if (i < n) out[i] = 0.0f;
}

// ---------------------------------------------------------------------------
// GEMM-in: x_proj[M][256] = x[M][768] @ W_in[256][768]^T + b_in  (fp32)
// LDS rows padded to 68 floats: staging writes 4-way -> 2-way (free);
// FMA accumulation order IDENTICAL to prior rounds (bit-exact xn).
// ---------------------------------------------------------------------------
__global__ __launch_bounds__(256) void gemm_in_kernel(
    const float* __restrict__ A, const float* __restrict__ B,
    const float* __restrict__ bias, float* __restrict__ C)
{
  __shared__ float As[16][68];
  __shared__ float Bs[16][68];
  const int tid = threadIdx.x;
  const int tx = tid & 15, ty = tid >> 4;
  const int bm = blockIdx.x << 6, bn = blockIdx.y << 6;
  const int lr = tid >> 2, lk = (tid & 3) << 2;
  const size_t aoff = (size_t)(bm + lr) * KLAT;
  const size_t boff = (size_t)(bn + lr) * KLAT;
  float acc[4][4] = {};
  for (int k0 = 0; k0 < KLAT; k0 += 16) {
    __syncthreads();
    float4 av = *(const float4*)(A + aoff + k0 + lk);
    float4 bv = *(const float4*)(B + boff + k0 + lk);
    As[lk + 0][lr] = av.x; As[lk + 1][lr] = av.y; As[lk + 2][lr] = av.z; As[lk + 3][lr] = av.w;
    Bs[lk + 0][lr] = bv.x; Bs[lk + 1][lr] = bv.y; Bs[lk + 2][lr] = bv.z; Bs[lk + 3][lr] = bv.w;
    __syncthreads();
#pragma unroll
    for (int kk = 0; kk < 16; ++kk) {
      float4 a4 = *(const float4*)&As[kk][ty << 2];
      float4 b4 = *(const float4*)&Bs[kk][tx << 2];
      float ar[4] = {a4.x, a4.y, a4.z, a4.w};
      float br[4] = {b4.x, b4.y, b4.z, b4.w};
#pragma unroll
      for (int i = 0; i < 4; ++i)
#pragma unroll
        for (int j = 0; j < 4; ++j)
          acc[i][j] = fmaf(ar[i], br[j], acc[i][j]);
    }
  }
  float4 b4 = *(const float4*)(bias + bn + (tx << 2));
  float bb[4] = {b4.x, b4.y, b4.z, b4.w};
#pragma unroll
  for (int i = 0; i < 4; ++i) {
    const size_t row = (size_t)(bm + (ty << 2) + i);
    float4 o = make_float4(acc[i][0] + bb[0], acc[i][1] + bb[1],
                           acc[i][2] + bb[2], acc[i][3] + bb[3]);
    *(float4*)(C + row * EDIM + bn + (tx << 2)) = o;
  }
}

// ---------------------------------------------------------------------------
// l2norm in place (fp32 in d_out scratch) + bf16 hi/lo planes
// ---------------------------------------------------------------------------
__global__ __launch_bounds__(256) void l2norm_split_kernel(
    float* __restrict__ xnf, bf16_t* __restrict__ xh, bf16_t* __restrict__ xl)
{
  __shared__ float sb[4];
  const int r = blockIdx.x, t = threadIdx.x;
  const size_t o = (size_t)r * EDIM + t;
  float v = xnf[o];
  float s = v * v;
#pragma unroll
  for (int off = 32; off >= 1; off >>= 1) s += __shfl_xor(s, off);
  if ((t & 63) == 0) sb[t >> 6] = s;
  __syncthreads();
  float tot = sb[0] + sb[1] + sb[2] + sb[3];
  float nv = v / sqrtf(tot);
  xnf[o] = nv;
  bf16_t h = (bf16_t)nv;
  xh[o] = h;
  xl[o] = (bf16_t)(nv - (float)h);
}

// ---------------------------------------------------------------------------
__global__ __launch_bounds__(256) void split_kernel(
    const float* __restrict__ src, bf16_t* __restrict__ hi, bf16_t* __restrict__ lo)
{
  const int i = (blockIdx.x * 256 + threadIdx.x) << 2;
  float4 v = *(const float4*)(src + i);
  bf16_t h0 = (bf16_t)v.x, h1 = (bf16_t)v.y, h2 = (bf16_t)v.z, h3 = (bf16_t)v.w;
  bf16x4 hv = {h0, h1, h2, h3};
  bf16x4 lv = {(bf16_t)(v.x - (float)h0), (bf16_t)(v.y - (float)h1),
               (bf16_t)(v.z - (float)h2), (bf16_t)(v.w - (float)h3)};
  *(bf16x4*)(hi + i) = hv;
  *(bf16x4*)(lo + i) = lv;
}

// ---------------------------------------------------------------------------
// Phase 1 (panel): d~ via bf16x3 MFMA. Block 128x128, 4 waves (2x2), wave
// tile 64x64. LDS rows 128B = [hi|lo], XOR-swizzled; staged via
// global_load_lds w=16 with pre-swizzled per-lane global source.
// Epilogue: f32 min-reduce + rare matching-lane u64 atomicMin (lowest col
// wins via packed key); Z/S1 shuffles; permuted bf16x4 P store.
// ---------------------------------------------------------------------------
__global__ __launch_bounds__(256) void phase1_mfma_kernel(
    const bf16_t* __restrict__ xh, const bf16_t* __restrict__ xl,
    const bf16_t* __restrict__ eh, const bf16_t* __restrict__ el,
    const int rowbase,
    u64* __restrict__ rowmin, float* __restrict__ rowZ, float* __restrict__ rowS1,
    bf16_t* __restrict__ P)
{
  __shared__ bf16_t Ab[PM * 64];
  __shared__ bf16_t Bb[PN * 64];
  const int tid  = threadIdx.x;
  const int lane = tid & 63;
  const int wave = tid >> 6;
  const int wm = wave >> 1, wn = wave & 1;
  const int brow = blockIdx.x * PM;
  const int bcol = blockIdx.y * PN;

  const int srow8 = lane >> 3;
  const int chunk = (lane & 7) ^ srow8;
  const bf16_t* gpa = (chunk & 4) ? xl : xh;
  const bf16_t* gpb = (chunk & 4) ? el : eh;
  const int within = (chunk & 3) << 3;
  const int acall0 = wave << 5;

  const bf16_t* ga0 = gpa + (size_t)(rowbase + brow + acall0 + srow8) * EDIM + within;
  const bf16_t* gb0 = gpb + (size_t)(bcol + acall0 + srow8) * EDIM + within;

  f32x4 acc[4][4] = {};

  for (int k0 = 0; k0 < EDIM; k0 += PK) {
    __syncthreads();
#pragma unroll
    for (int c = 0; c < 4; ++c) {
      const int rr = acall0 + (c << 3);
      gload16(ga0 + (size_t)(c << 3) * EDIM + k0, &Ab[rr * 64]);
      gload16(gb0 + (size_t)(c << 3) * EDIM + k0, &Bb[rr * 64]);
    }
    __syncthreads();

    const int swz = lane & 7;
    const int sh  = (lane >> 4) ^ swz;
    const int sl  = sh ^ 4;
    const int ar0 = (wm << 6) + (lane & 15);
    const int br0 = (wn << 6) + (lane & 15);
    bf16x8 bhf[4], blf[4];
#pragma unroll
    for (int n = 0; n < 4; ++n) {
      const int r = br0 + (n << 4);
      bhf[n] = *(const bf16x8*)&Bb[r * 64 + (sh << 3)];
      blf[n] = *(const bf16x8*)&Bb[r * 64 + (sl << 3)];
    }
#pragma unroll
    for (int m = 0; m < 4; ++m) {
      const int r = ar0 + (m << 4);
      bf16x8 ahf = *(const bf16x8*)&Ab[r * 64 + (sh << 3)];
      bf16x8 alf = *(const bf16x8*)&Ab[r * 64 + (sl << 3)];
#pragma unroll
      for (int n = 0; n < 4; ++n) {
        acc[m][n] = __builtin_amdgcn_mfma_f32_16x16x32_bf16(ahf, bhf[n], acc[m][n], 0, 0, 0);
        acc[m][n] = __builtin_amdgcn_mfma_f32_16x16x32_bf16(ahf, blf[n], acc[m][n], 0, 0, 0);
        acc[m][n] = __builtin_amdgcn_mfma_f32_16x16x32_bf16(alf, bhf[n], acc[m][n], 0, 0, 0);
      }
    }
  }

  const int colg  = bcol + (wn << 6) + (lane & 15);
  const int pbase = bcol + (wn << 6) + ((lane & 15) << 2);
  const int rl0   = brow + (wm << 6) + ((lane >> 4) << 2);
#pragma unroll
  for (int m = 0; m < 4; ++m) {
#pragma unroll
    for (int q = 0; q < 4; ++q) {
      const int rl = rl0 + (m << 4) + q;
      float Z = 0.f, S1 = 0.f;
      float dloc = 1e30f;
      int nbest = 0;
      bf16_t evv[4];
#pragma unroll
      for (int n = 0; n < 4; ++n) {
        float d = acc[m][n][q];
        float l = 10.f * d;
        float e = __expf(l);
        Z += e; S1 += l * e;
        evv[n] = (bf16_t)e;
        if (d < dloc) { dloc = d; nbest = n; }
      }
      bf16x4 pv = {evv[0], evv[1], evv[2], evv[3]};
      *(bf16x4*)(P + (size_t)rl * NE + pbase) = pv;
      float dmin = dloc;
#pragma unroll
      for (int off = 1; off < 16; off <<= 1) {
        dmin = fminf(dmin, __shfl_xor(dmin, off));
        Z  += __shfl_xor(Z, off);
        S1 += __shfl_xor(S1, off);
      }
      const int rg = rowbase + rl;
      if (dloc == dmin) {
        u64 key = ((u64)__float_as_uint(dloc + 2.0f) << 32)
                | (unsigned)(colg + (nbest << 4));
        atomicMin(rowmin + rg, key);
      }
      if ((lane & 15) == 0) {
        atomicAdd(rowZ + rg, Z);
        atomicAdd(rowS1 + rg, S1);
      }
    }
  }
}

// ---------------------------------------------------------------------------
// Column reduce: vectorized bf16x4, 4 cols/thread over 64 rows.
// ---------------------------------------------------------------------------
__global__ __launch_bounds__(256) void colreduce_kernel(
    const bf16_t* __restrict__ P, const float* __restrict__ rowZ,
    const u64* __restrict__ rowmin, const int rowbase,
    float* __restrict__ ap, int* __restrict__ ccnt, int* __restrict__ clist)
{
  __shared__ float izs[64], ths[64];
  const int t = threadIdx.x;
  const int pc0 = blockIdx.x * 1024 + (t << 2);
  const int r0 = blockIdx.y * 64;
  if (t < 64) {
    const int rg = rowbase + r0 + t;
    izs[t] = 1.0f / rowZ[rg];
    float dmin = __uint_as_float((unsigned)(rowmin[rg] >> 32)) - 2.0f;
    ths[t] = __expf(10.f * (dmin + 3e-4f));
  }
  __syncthreads();
  const int Bbase = pc0 & ~63;
  const int sub   = (pc0 & 63) >> 2;
  float s0 = 0.f, s1 = 0.f, s2 = 0.f, s3 = 0.f;
  for (int r = 0; r < 64; ++r) {
    bf16x4 p4 = *(const bf16x4*)(P + (size_t)(r0 + r) * NE + pc0);
    float p0 = (float)p4[0], p1 = (float)p4[1], p2 = (float)p4[2], p3 = (float)p4[3];
    float iz = izs[r], th = ths[r];
    s0 = fmaf(p0, iz, s0); s1 = fmaf(p1, iz, s1);
    s2 = fmaf(p2, iz, s2); s3 = fmaf(p3, iz, s3);
    float pm = fminf(fminf(p0, p1), fminf(p2, p3));
    if (pm <= th) {
      const int rg = rowbase + r0 + r;
      float pvv[4] = {p0, p1, p2, p3};
      for (int n = 0; n < 4; ++n)
        if (pvv[n] <= th) {
          int pos = atomicAdd(ccnt + rg, 1);
          if (pos < CANDCAP) clist[(rg << 4) + pos] = Bbase + (n << 4) + sub;
        }
    }
  }
  atomicAdd(ap + pc0 + 0, s0); atomicAdd(ap + pc0 + 1, s1);
  atomicAdd(ap + pc0 + 2, s2); atomicAdd(ap + pc0 + 3, s3);
}

// ---------------------------------------------------------------------------
__global__ __launch_bounds__(256) void rowent_kernel(
    const float* __restrict__ rowZ, const float* __restrict__ rowS1,
    float* __restrict__ scal)
{
  __shared__ float sb[4];
  const int r = blockIdx.x * 256 + threadIdx.x;
  const int t = threadIdx.x;
  float Z = rowZ[r], S1 = rowS1[r];
  float ent = logf(Z) - S1 / Z;
#pragma unroll
  for (int off = 32; off >= 1; off >>= 1) ent += __shfl_xor(ent, off);
  if ((t & 63) == 0) sb[t >> 6] = ent;
  __syncthreads();
  if (t == 0) atomicAdd(scal + 1, sb[0] + sb[1] + sb[2] + sb[3]);
}

// ---------------------------------------------------------------------------
// Repair: exact fp32 argmin over candidate set; lexicographic (d, idx) min.
// ---------------------------------------------------------------------------
__global__ __launch_bounds__(256) void repair_kernel(
    const float* __restrict__ xnf, const float* __restrict__ embed,
    const u64* __restrict__ rowmin, const int* __restrict__ ccnt,
    const int* __restrict__ clist, int* __restrict__ indw,
    float* __restrict__ bins, int* __restrict__ binsI, float* __restrict__ out)
{
  const int t = threadIdx.x;
  const int row = blockIdx.x * 64 + (t >> 2);
  const int sub = t & 3;
  const int base = ((int)(unsigned)(rowmin[row] & 0xFFFFFFFFull)) & (NE - 1);
  int cnt = ccnt[row];
  if (cnt > CANDCAP) cnt = CANDCAP;
  float bestD = 1e30f;
  int bestI = NE;
  const float* xr = xnf + (size_t)row * EDIM + (sub << 6);
  for (int j = -1; j < cnt; ++j) {
    const int c = (j < 0) ? base : (clist[(row << 4) + j] & (NE - 1));
    const float* er = embed + (size_t)c * EDIM + (sub << 6);
    float s = 0.f;
#pragma unroll
    for (int k = 0; k < 64; k += 4) {
      float4 a = *(const float4*)(xr + k);
      float4 b = *(const float4*)(er + k);
      s = fmaf(a.x, b.x, s); s = fmaf(a.y, b.y, s);
      s = fmaf(a.z, b.z, s); s = fmaf(a.w, b.w, s);
    }
    s += __shfl_xor(s, 1);
    s += __shfl_xor(s, 2);
    if (s < bestD || (s == bestD && c < bestI)) { bestD = s; bestI = c; }
  }
  if (sub == 0) {
    indw[row] = bestI;
    out[OFF_IND + row] = (float)bestI;
    atomicAdd(bins + bestI, 1.0f);
    atomicAdd(binsI + bestI, 1);
  }
}

// ---------------------------------------------------------------------------
__global__ __launch_bounds__(256) void sortprep_kernel(
    const int* __restrict__ binsI, int* __restrict__ offs, int* __restrict__ cursor)
{
  __shared__ int ssum[256];
  const int t = threadIdx.x;
  const int base = t * 32;
  int loc[32];
  int cnt = 0;
#pragma unroll
  for (int j = 0; j < 32; ++j) { loc[j] = cnt; cnt += binsI[base + j]; }
  ssum[t] = cnt;
  __syncthreads();
  for (int off = 1; off < 256; off <<= 1) {
    int v = (t >= off) ? ssum[t - off] : 0;
    __syncthreads();
    ssum[t] += v;
    __syncthreads();
  }
  int run = (t > 0) ? ssum[t - 1] : 0;
#pragma unroll
  for (int j = 0; j < 32; ++j) {
    offs[base + j]   = run + loc[j];
    cursor[base + j] = run + loc[j];
  }
}

// ---------------------------------------------------------------------------
__global__ __launch_bounds__(256) void rowsort_kernel(
    const int* __restrict__ indw, int* __restrict__ cursor, int* __restrict__ sorted)
{
  const int r = blockIdx.x * 256 + threadIdx.x;
  const int ind = indw[r] & (NE - 1);
  int pos = atomicAdd(cursor + ind, 1);
  sorted[pos & (NROWS - 1)] = r;
}

// ---------------------------------------------------------------------------
// esum + commit via sorted rows: one block per code, NO fp32 atomics on esum.
// ---------------------------------------------------------------------------
__global__ __launch_bounds__(256) void esum_commit_kernel(
    const int* __restrict__ offs, const int* __restrict__ binsI,
    const int* __restrict__ sorted, const float* __restrict__ xnf,
    const float* __restrict__ embed, float* __restrict__ esum,
    float* __restrict__ scal)
{
  __shared__ float sb[4];
  const int c = blockIdx.x, t = threadIdx.x;
  const float ev = embed[(size_t)c * EDIM + t];
  const int start = offs[c];
  const int cnt = binsI[c];
  float s = 0.f, cm = 0.f;
  for (int j = 0; j < cnt; ++j) {
    const int r = sorted[(start + j) & (NROWS - 1)];
    float xv = xnf[(size_t)r * EDIM + t];
    s += xv;
    float df = ev - xv;
    cm = fmaf(df, df, cm);
  }
  esum[(size_t)c * EDIM + t] = s;
#pragma unroll
  for (int off = 32; off >= 1; off >>= 1) cm += __shfl_xor(cm, off);
  if ((t & 63) == 0) sb[t >> 6] = cm;
  __syncthreads();
  if (t == 0) atomicAdd(scal + 2, sb[0] + sb[1] + sb[2] + sb[3]);
}

// ---------------------------------------------------------------------------
__global__ __launch_bounds__(256) void scalars_kernel(
    const float* __restrict__ ap, const float* __restrict__ scal, float* __restrict__ out)
{
  __shared__ float sb[4];
  const int t = threadIdx.x;
  float h = 0.f;
  for (int c = t; c < NE; c += 256) {
    float apv = ap[c] * (1.0f / NROWS);
    h -= apv * logf(apv);
  }
#pragma unroll
  for (int off = 32; off >= 1; off >>= 1) h += __shfl_xor(h, off);
  if ((t & 63) == 0) sb[t >> 6] = h;
  __syncthreads();
  if (t == 0) {
    float Hmax = sb[0] + sb[1] + sb[2] + sb[3];
    float commit = scal[2] * (1.0f / ((float)NROWS * (float)EDIM));
    float emin = scal[1] * (1.0f / (float)NROWS);
    out[OFF_LOSS] = commit - Hmax;
    out[OFF_EMIN] = emin;
    out[OFF_CMT]  = commit;
  }
}

// ---------------------------------------------------------------------------
__global__ __launch_bounds__(256) void cluster_kernel(
    const float* __restrict__ cs_in, const float* __restrict__ bins,
    float* __restrict__ cn, float* __restrict__ scal)
{
  __shared__ float sb[4];
  const int c = blockIdx.x * 256 + threadIdx.x;
  const int t = threadIdx.x;
  float v = cs_in[c] * 0.99f + bins[c] * 0.01f;
  cn[c] = v;
  float s = v;
#pragma unroll
  for (int off = 32; off >= 1; off >>= 1) s += __shfl_xor(s, off);
  if ((t & 63) == 0) sb[t >> 6] = s;
  __syncthreads();
  if (t == 0) atomicAdd(scal + 0, sb[0] + sb[1] + sb[2] + sb[3]);
}

// ---------------------------------------------------------------------------
__global__ __launch_bounds__(256) void scan_kernel(
    const float* __restrict__ cn, const float* __restrict__ scal,
    int* __restrict__ idxs, float* __restrict__ csm, float* __restrict__ out)
{
  __shared__ int ssum[256];
  const int t = threadIdx.x;
  const int base = t * 32;
  int cnt = 0;
  for (int j = 0; j < 32; ++j) cnt += (cn[base + j] < 0.1f) ? 1 : 0;
  ssum[t] = cnt;
  __syncthreads();
  for (int off = 1; off < 256; off <<= 1) {
    int v = (t >= off) ? ssum[t - off] : 0;
    __syncthreads();
    ssum[t] += v;
    __syncthreads();
  }
  int run = (t > 0) ? ssum[t - 1] : 0;
  const float total = scal[0];
  const float dscale = total / (total + (float)NE * 1e-5f);
  for (int j = 0; j < 32; ++j) {
    float v = cn[base + j];
    bool ex = v < 0.1f;                 // DEAD_THRESH * RATIO
    run += ex ? 1 : 0;
    int idx = run - 1; if (idx < 0) idx = 0;
    idx &= (NROWS - 1);
    idxs[base + j] = idx;
    csm[base + j] = (v + 1e-5f) * dscale;
    out[OFF_CSF + base + j] = ex ? 0.12f : v;   // RESET_CS*RATIO
  }
}

// ---------------------------------------------------------------------------
__global__ __launch_bounds__(256) void embed_out_kernel(
    const float* __restrict__ cn, const float* __restrict__ csm,
    const int* __restrict__ idxs, const float* __restrict__ xn,
    const float* __restrict__ embed_avg, const float* __restrict__ esum,
    float* __restrict__ out)
{
  const int c = blockIdx.x, t = threadIdx.x;
  float oe, oa;
  if (cn[c] < 0.1f) {
    float s = xn[(size_t)(idxs[c] & (NROWS - 1)) * EDIM + t];
    oe = s; oa = s * 0.12f;
  } else {
    float an = embed_avg[(size_t)c * EDIM + t] * 0.99f
             + esum[(size_t)c * EDIM + t] * 0.01f;
    oa = an; oe = an / csm[c];
  }
  out[OFF_EMB  + (size_t)c * EDIM + t] = oe;
  out[OFF_EAVG + (size_t)c * EDIM + t] = oa;
}

// ---------------------------------------------------------------------------
// GEMM-out via bf16x3 MFMA: out[M][768] = embed[ind[M]] @ W_out^T + b_out.
// A = gathered embed planes (eh/el), B = W_out planes (wh/wl).
// Same staging/swizzle structure as phase1. Runs LAST. z_q abs err ~1e-5.
// ---------------------------------------------------------------------------
__global__ __launch_bounds__(256) void gemm_out_mfma_kernel(
    const bf16_t* __restrict__ eh, const bf16_t* __restrict__ el,
    const bf16_t* __restrict__ wh, const bf16_t* __restrict__ wl,
    const float* __restrict__ bias, const int* __restrict__ gather,
    float* __restrict__ C)
{
  __shared__ bf16_t Ab[PM * 64];
  __shared__ bf16_t Bb[PN * 64];
  const int tid  = threadIdx.x;
  const int lane = tid & 63;
  const int wave = tid >> 6;
  const int wm = wave >> 1, wn = wave & 1;
  const int bm   = blockIdx.x * PM;          // output row base
  const int bcol = blockIdx.y * PN;          // output col base (W_out row)

  const int srow8 = lane >> 3;
  const int chunk = (lane & 7) ^ srow8;
  const bf16_t* gpa = (chunk & 4) ? el : eh;
  const bf16_t* gpb = (chunk & 4) ? wl : wh;
  const int within = (chunk & 3) << 3;
  const int acall0 = wave << 5;

  // gathered embed rows for the 4 A-staging calls (constant across K)
  const bf16_t* ga[4];
#pragma unroll
  for (int c = 0; c < 4; ++c) {
    const int gr = gather[bm + acall0 + (c << 3) + srow8] & (NE - 1);
    ga[c] = gpa + (size_t)gr * EDIM + within;
  }
  const bf16_t* gb0 = gpb + (size_t)(bcol + acall0 + srow8) * EDIM + within;

  f32x4 acc[4][4] = {};

  for (int k0 = 0; k0 < EDIM; k0 += PK) {
    __syncthreads();
#pragma unroll
    for (int c = 0; c < 4; ++c) {
      const int rr = acall0 + (c << 3);
      gload16(ga[c] + k0, &Ab[rr * 64]);
      gload16(gb0 + (size_t)(c << 3) * EDIM + k0, &Bb[rr * 64]);
    }
    __syncthreads();

    const int swz = lane & 7;
    const int sh  = (lane >> 4) ^ swz;
    const int sl  = sh ^ 4;
    const int ar0 = (wm << 6) + (lane & 15);
    const int br0 = (wn << 6) + (lane & 15);
    bf16x8 bhf[4], blf[4];
#pragma unroll
    for (int n = 0; n < 4; ++n) {
      const int r = br0 + (n << 4);
      bhf[n] = *(const bf16x8*)&Bb[r * 64 + (sh << 3)];
      blf[n] = *(const bf16x8*)&Bb[r * 64 + (sl << 3)];
    }
#pragma unroll
    for (int m = 0; m < 4; ++m) {
      const int r = ar0 + (m << 4);
      bf16x8 ahf = *(const bf16x8*)&Ab[r * 64 + (sh << 3)];
      bf16x8 alf = *(const bf16x8*)&Ab[r * 64 + (sl << 3)];
#pragma unroll
      for (int n = 0; n < 4; ++n) {
        acc[m][n] = __builtin_amdgcn_mfma_f32_16x16x32_bf16(ahf, bhf[n], acc[m][n], 0, 0, 0);
        acc[m][n] = __builtin_amdgcn_mfma_f32_16x16x32_bf16(ahf, blf[n], acc[m][n], 0, 0, 0);
        acc[m][n] = __builtin_amdgcn_mfma_f32_16x16x32_bf16(alf, bhf[n], acc[m][n], 0, 0, 0);
      }
    }
  }

  // epilogue: col = bcol + wn*64 + n*16 + (lane&15); row = bm + wm*64 + m*16 + (lane>>4)*4 + q
  const int colb = bcol + (wn << 6) + (lane & 15);
  float bs[4];
#pragma unroll
  for (int n = 0; n < 4; ++n) bs[n] = bias[colb + (n << 4)];
  const int row0 = bm + (wm << 6) + ((lane >> 4) << 2);
#pragma unroll
  for (int m = 0; m < 4; ++m) {
#pragma unroll
    for (int q = 0; q < 4; ++q) {
      float* op = C + (size_t)(row0 + (m << 4) + q) * ODIM;
#pragma unroll
      for (int n = 0; n < 4; ++n)
        op[colb + (n << 4)] = acc[m][n][q] + bs[n];
    }
  }
}

// ---------------------------------------------------------------------------
extern "C" void kernel_launch(void* const* d_in, const int* in_sizes, int n_in,
                              void* d_out, int out_size, void* d_ws, size_t ws_size,
                              hipStream_t stream)
{
  const float* x         = (const float*)d_in[0];
  const float* W_in      = (const float*)d_in[1];
  const float* b_in      = (const float*)d_in[2];
  const float* W_out     = (const float*)d_in[3];
  const float* b_out     = (const float*)d_in[4];
  const float* embed     = (const float*)d_in[5];
  const float* embed_avg = (const float*)d_in[6];
  const float* cs_in     = (const float*)d_in[7];
  float* out = (float*)d_out;
  char* ws = (char*)d_ws;

  if (ws_size < (size_t)W_END) {   // guard (proven not to fire)
    zero_out_kernel<<<(out_size + 255) / 256, 256, 0, stream>>>(out, out_size);
    return;
  }

  bf16_t* xh = (bf16_t*)(ws + W_XN);
  bf16_t* xl = (bf16_t*)(ws + W_XN + 8388608u);
  bf16_t* eh = (bf16_t*)(ws + W_ESUM);
  bf16_t* el = (bf16_t*)(ws + W_ESUM + 4194304u);
  // after panels: esum in dead xh region; W_out planes in dead xl region
  float*  esum = (float*)(ws + W_XN);
  bf16_t* wh   = (bf16_t*)(ws + W_XN + 8388608u);
  bf16_t* wl   = (bf16_t*)(ws + W_XN + 8388608u + 393216u);
  u64*   rowmin= (u64*)  (ws + W_RMIN);
  int*   offs  = (int*)  (ws + W_RMIN);            // reuses rowmin AFTER repair
  int*   cursor= offs + NE;
  float* rowZ  = (float*)(ws + W_RZ);
  float* rowS1 = (float*)(ws + W_RS1);
  int*   binsI = (int*)  (ws + W_INVZ);
  int*   indw  = (int*)  (ws + W_INDW);
  float* bins  = (float*)(ws + W_BINS);
  float* cn    = (float*)(ws + W_CN);
  float* csm   = (float*)(ws + W_CSM);
  int*   idxs  = (int*)  (ws + W_IDXS);
  float* ap    = (float*)(ws + W_AP);
  float* scal  = (float*)(ws + W_SCAL);

  // d_out scratch:
  //   z_q region: [0,16MB) fp32 xn ; [16MB,48MB) bf16 P panel (ends at OFF_IND)
  //   emb region: ccnt[16384] + clist[16384*16] + sorted[16384] (pre-embed_out)
  float*  xnf    = out + OFF_ZQ;
  bf16_t* Pbuf   = (bf16_t*)(out + OFF_ZQ + 4194304);
  int*    ccnt   = (int*)(out + OFF_EMB);
  int*    clist  = ccnt + NROWS;
  int*    sorted = clist + NROWS * CANDCAP;

  hipMemsetAsync(ws + W_RMIN, 0xFF, W_RZ - W_RMIN, stream); // rowmin = ~0
  hipMemsetAsync(ws + W_RZ,   0,    W_END - W_RZ,  stream); // rowZ..scal = 0 (incl binsI)
  hipMemsetAsync(ccnt, 0, NROWS * sizeof(int), stream);     // candidate counts

  // 1. x_proj (fp32 into d_out scratch)
  gemm_in_kernel<<<dim3(NROWS / 64, EDIM / 64), 256, 0, stream>>>(
      x, W_in, b_in, xnf);
  // 2. l2norm + bf16 hi/lo planes
  l2norm_split_kernel<<<NROWS, 256, 0, stream>>>(xnf, xh, xl);
  // 3. embed bf16 hi/lo planes
  split_kernel<<<(NE * EDIM / 4) / 256, 256, 0, stream>>>(embed, eh, el);
  // 4. panel loop: MFMA similarity + permuted P store, then vector column-reduce
  for (int p = 0; p < NROWS / PROWS; ++p) {
    const int rowbase = p * PROWS;
    phase1_mfma_kernel<<<dim3(PROWS / PM, NE / PN), 256, 0, stream>>>(
        xh, xl, eh, el, rowbase, rowmin, rowZ, rowS1, Pbuf);
    colreduce_kernel<<<dim3(NE / 1024, PROWS / 64), 256, 0, stream>>>(
        Pbuf, rowZ, rowmin, rowbase, ap, ccnt, clist);
  }
  // 5. entropy_to_min partials
  rowent_kernel<<<NROWS / 256, 256, 0, stream>>>(rowZ, rowS1, scal);
  // 6. exact argmin repair (+ bins / binsI)
  repair_kernel<<<NROWS / 64, 256, 0, stream>>>(
      xnf, embed, rowmin, ccnt, clist, indw, bins, binsI, out);
  // 7. counting sort of rows by code (rowmin region reused for offs/cursor)
  sortprep_kernel<<<1, 256, 0, stream>>>(binsI, offs, cursor);
  rowsort_kernel<<<NROWS / 256, 256, 0, stream>>>(indw, cursor, sorted);
  // 8. W_out bf16 planes (xl region dead after panels)
  split_kernel<<<(ODIM * EDIM / 4) / 256, 256, 0, stream>>>(W_out, wh, wl);
  // 9. esum + commit loss (esum in dead xh region; eh/el preserved)
  esum_commit_kernel<<<NE, 256, 0, stream>>>(
      offs, binsI, sorted, xnf, embed, esum, scal);
  // 10. cluster_new + total
  cluster_kernel<<<NE / 256, 256, 0, stream>>>(cs_in, bins, cn, scal);
  // 11. expiry scan + cluster_final
  scan_kernel<<<1, 256, 0, stream>>>(cn, scal, idxs, csm, out);
  // 12. scalar outputs
  scalars_kernel<<<1, 256, 0, stream>>>(ap, scal, out);
  // 13. embed_final / embed_avg_final (reads fp32 xn scratch + relocated esum)
  embed_out_kernel<<<NE, 256, 0, stream>>>(cn, csm, idxs, xnf, embed_avg, esum, out);
  // 14. z_q GEMM LAST via MFMA (overwrites z_q scratch incl. P)
  gemm_out_mfma_kernel<<<dim3(NROWS / PM, ODIM / PN), 256, 0, stream>>>(
      eh, el, wh, wl, b_out, indw, out + OFF_ZQ);
}

// Round 7
// 1015.774 us; speedup vs baseline: 1.6643x; 1.0853x over previous
//
#include <hip/hip_runtime.h>
#include <hip/hip_bf16.h>

typedef unsigned long long u64;
typedef __bf16 bf16_t;
typedef __attribute__((ext_vector_type(8))) __bf16 bf16x8;
typedef __attribute__((ext_vector_type(4))) __bf16 bf16x4;
typedef __attribute__((ext_vector_type(4))) float f32x4;

#define NROWS 16384
#define KLAT  768
#define EDIM  256
#define NE    8192
#define ODIM  768

// output element offsets (FLOAT32 elements — d_out is fp32, 16,801,795 elems)
#define OFF_ZQ   0
#define OFF_IND  12582912
#define OFF_LOSS 12599296
#define OFF_EMB  12599297
#define OFF_EAVG 14696449
#define OFF_CSF  16793601
#define OFF_EMIN 16801793
#define OFF_CMT  16801794

// workspace layout (~25.76 MB proven)
// W_XN: bf16 xh (8MB) + xl (8MB) during panels; AFTER panels:
//       [0,8MB) f32 esum ; [8MB, 8MB+768KB) bf16 W_out hi/lo planes
#define W_XN    0u
#define W_ESUM  16777216u    // bf16 eh (4MB) + el (4MB) — live until gemm_out (last)
#define W_RMIN  25165824u    // u64 rowmin [16384]; after repair: i32 offs+cursor
#define W_RZ    25296896u    // f32 rowZ
#define W_RS1   25362432u    // f32 rowS1
#define W_INVZ  25427968u    // i32 binsI [8192]
#define W_INDW  25493504u    // i32 ind
#define W_BINS  25559040u    // f32 bins [8192]
#define W_CN    25591808u    // f32 cluster_new
#define W_CSM   25624576u    // f32 cs smoothed
#define W_IDXS  25657344u    // i32 sampled idx
#define W_AP    25690112u    // f32 ap [8192] (PERMUTED col space — entropy invariant)
#define W_SCAL  25722880u    // f32 scal[4]
#define W_END   25722896u

#define CANDCAP 16
#define PROWS   2048         // panel rows
#define PM      128          // MFMA block rows
#define PN      128          // MFMA block cols
#define PK      32           // MFMA K chunk

typedef __attribute__((address_space(3))) unsigned char lds_u8;
typedef __attribute__((address_space(1))) const unsigned char glb_u8;
static __device__ __forceinline__ void gload16(const void* g, void* l)
{
  __builtin_amdgcn_global_load_lds((glb_u8*)g, (lds_u8*)l, 16, 0, 0);
}

// ---------------------------------------------------------------------------
__global__ __launch_bounds__(256) void zero_out_kernel(float* __restrict__ out, int n)
{
  int i = blockIdx.x * 256 + threadIdx.x;
  if (i < n) out[i] = 0.0f;
}

// ---------------------------------------------------------------------------
// GEMM-in: x_proj[M][256] = x[M][768] @ W_in[256][768]^T + b_in  (fp32)
// LDS rows padded to 68 floats; FMA order bit-exact vs prior rounds.
// ---------------------------------------------------------------------------
__global__ __launch_bounds__(256) void gemm_in_kernel(
    const float* __restrict__ A, const float* __restrict__ B,
    const float* __restrict__ bias, float* __restrict__ C)
{
  __shared__ float As[16][68];
  __shared__ float Bs[16][68];
  const int tid = threadIdx.x;
  const int tx = tid & 15, ty = tid >> 4;
  const int bm = blockIdx.x << 6, bn = blockIdx.y << 6;
  const int lr = tid >> 2, lk = (tid & 3) << 2;
  const size_t aoff = (size_t)(bm + lr) * KLAT;
  const size_t boff = (size_t)(bn + lr) * KLAT;
  float acc[4][4] = {};
  for (int k0 = 0; k0 < KLAT; k0 += 16) {
    __syncthreads();
    float4 av = *(const float4*)(A + aoff + k0 + lk);
    float4 bv = *(const float4*)(B + boff + k0 + lk);
    As[lk + 0][lr] = av.x; As[lk + 1][lr] = av.y; As[lk + 2][lr] = av.z; As[lk + 3][lr] = av.w;
    Bs[lk + 0][lr] = bv.x; Bs[lk + 1][lr] = bv.y; Bs[lk + 2][lr] = bv.z; Bs[lk + 3][lr] = bv.w;
    __syncthreads();
#pragma unroll
    for (int kk = 0; kk < 16; ++kk) {
      float4 a4 = *(const float4*)&As[kk][ty << 2];
      float4 b4 = *(const float4*)&Bs[kk][tx << 2];
      float ar[4] = {a4.x, a4.y, a4.z, a4.w};
      float br[4] = {b4.x, b4.y, b4.z, b4.w};
#pragma unroll
      for (int i = 0; i < 4; ++i)
#pragma unroll
        for (int j = 0; j < 4; ++j)
          acc[i][j] = fmaf(ar[i], br[j], acc[i][j]);
    }
  }
  float4 b4 = *(const float4*)(bias + bn + (tx << 2));
  float bb[4] = {b4.x, b4.y, b4.z, b4.w};
#pragma unroll
  for (int i = 0; i < 4; ++i) {
    const size_t row = (size_t)(bm + (ty << 2) + i);
    float4 o = make_float4(acc[i][0] + bb[0], acc[i][1] + bb[1],
                           acc[i][2] + bb[2], acc[i][3] + bb[3]);
    *(float4*)(C + row * EDIM + bn + (tx << 2)) = o;
  }
}

// ---------------------------------------------------------------------------
__global__ __launch_bounds__(256) void l2norm_split_kernel(
    float* __restrict__ xnf, bf16_t* __restrict__ xh, bf16_t* __restrict__ xl)
{
  __shared__ float sb[4];
  const int r = blockIdx.x, t = threadIdx.x;
  const size_t o = (size_t)r * EDIM + t;
  float v = xnf[o];
  float s = v * v;
#pragma unroll
  for (int off = 32; off >= 1; off >>= 1) s += __shfl_xor(s, off);
  if ((t & 63) == 0) sb[t >> 6] = s;
  __syncthreads();
  float tot = sb[0] + sb[1] + sb[2] + sb[3];
  float nv = v / sqrtf(tot);
  xnf[o] = nv;
  bf16_t h = (bf16_t)nv;
  xh[o] = h;
  xl[o] = (bf16_t)(nv - (float)h);
}

// ---------------------------------------------------------------------------
__global__ __launch_bounds__(256) void split_kernel(
    const float* __restrict__ src, bf16_t* __restrict__ hi, bf16_t* __restrict__ lo)
{
  const int i = (blockIdx.x * 256 + threadIdx.x) << 2;
  float4 v = *(const float4*)(src + i);
  bf16_t h0 = (bf16_t)v.x, h1 = (bf16_t)v.y, h2 = (bf16_t)v.z, h3 = (bf16_t)v.w;
  bf16x4 hv = {h0, h1, h2, h3};
  bf16x4 lv = {(bf16_t)(v.x - (float)h0), (bf16_t)(v.y - (float)h1),
               (bf16_t)(v.z - (float)h2), (bf16_t)(v.w - (float)h3)};
  *(bf16x4*)(hi + i) = hv;
  *(bf16x4*)(lo + i) = lv;
}

// ---------------------------------------------------------------------------
// Phase 1 (panel): d~ via bf16x3 MFMA. Block 128x128, 4 waves (2x2), wave
// tile 64x64. LDS rows 128B = [hi|lo], XOR-swizzled; staged via
// global_load_lds w=16 with pre-swizzled per-lane global source.
// ---------------------------------------------------------------------------
__global__ __launch_bounds__(256) void phase1_mfma_kernel(
    const bf16_t* __restrict__ xh, const bf16_t* __restrict__ xl,
    const bf16_t* __restrict__ eh, const bf16_t* __restrict__ el,
    const int rowbase,
    u64* __restrict__ rowmin, float* __restrict__ rowZ, float* __restrict__ rowS1,
    bf16_t* __restrict__ P)
{
  __shared__ bf16_t Ab[PM * 64];
  __shared__ bf16_t Bb[PN * 64];
  const int tid  = threadIdx.x;
  const int lane = tid & 63;
  const int wave = tid >> 6;
  const int wm = wave >> 1, wn = wave & 1;
  const int brow = blockIdx.x * PM;
  const int bcol = blockIdx.y * PN;

  const int srow8 = lane >> 3;
  const int chunk = (lane & 7) ^ srow8;
  const bf16_t* gpa = (chunk & 4) ? xl : xh;
  const bf16_t* gpb = (chunk & 4) ? el : eh;
  const int within = (chunk & 3) << 3;
  const int acall0 = wave << 5;

  const bf16_t* ga0 = gpa + (size_t)(rowbase + brow + acall0 + srow8) * EDIM + within;
  const bf16_t* gb0 = gpb + (size_t)(bcol + acall0 + srow8) * EDIM + within;

  f32x4 acc[4][4] = {};

  for (int k0 = 0; k0 < EDIM; k0 += PK) {
    __syncthreads();
#pragma unroll
    for (int c = 0; c < 4; ++c) {
      const int rr = acall0 + (c << 3);
      gload16(ga0 + (size_t)(c << 3) * EDIM + k0, &Ab[rr * 64]);
      gload16(gb0 + (size_t)(c << 3) * EDIM + k0, &Bb[rr * 64]);
    }
    __syncthreads();

    const int swz = lane & 7;
    const int sh  = (lane >> 4) ^ swz;
    const int sl  = sh ^ 4;
    const int ar0 = (wm << 6) + (lane & 15);
    const int br0 = (wn << 6) + (lane & 15);
    bf16x8 bhf[4], blf[4];
#pragma unroll
    for (int n = 0; n < 4; ++n) {
      const int r = br0 + (n << 4);
      bhf[n] = *(const bf16x8*)&Bb[r * 64 + (sh << 3)];
      blf[n] = *(const bf16x8*)&Bb[r * 64 + (sl << 3)];
    }
#pragma unroll
    for (int m = 0; m < 4; ++m) {
      const int r = ar0 + (m << 4);
      bf16x8 ahf = *(const bf16x8*)&Ab[r * 64 + (sh << 3)];
      bf16x8 alf = *(const bf16x8*)&Ab[r * 64 + (sl << 3)];
#pragma unroll
      for (int n = 0; n < 4; ++n) {
        acc[m][n] = __builtin_amdgcn_mfma_f32_16x16x32_bf16(ahf, bhf[n], acc[m][n], 0, 0, 0);
        acc[m][n] = __builtin_amdgcn_mfma_f32_16x16x32_bf16(ahf, blf[n], acc[m][n], 0, 0, 0);
        acc[m][n] = __builtin_amdgcn_mfma_f32_16x16x32_bf16(alf, bhf[n], acc[m][n], 0, 0, 0);
      }
    }
  }

  const int colg  = bcol + (wn << 6) + (lane & 15);
  const int pbase = bcol + (wn << 6) + ((lane & 15) << 2);
  const int rl0   = brow + (wm << 6) + ((lane >> 4) << 2);
#pragma unroll
  for (int m = 0; m < 4; ++m) {
#pragma unroll
    for (int q = 0; q < 4; ++q) {
      const int rl = rl0 + (m << 4) + q;
      float Z = 0.f, S1 = 0.f;
      float dloc = 1e30f;
      int nbest = 0;
      bf16_t evv[4];
#pragma unroll
      for (int n = 0; n < 4; ++n) {
        float d = acc[m][n][q];
        float l = 10.f * d;
        float e = __expf(l);
        Z += e; S1 += l * e;
        evv[n] = (bf16_t)e;
        if (d < dloc) { dloc = d; nbest = n; }
      }
      bf16x4 pv = {evv[0], evv[1], evv[2], evv[3]};
      *(bf16x4*)(P + (size_t)rl * NE + pbase) = pv;
      float dmin = dloc;
#pragma unroll
      for (int off = 1; off < 16; off <<= 1) {
        dmin = fminf(dmin, __shfl_xor(dmin, off));
        Z  += __shfl_xor(Z, off);
        S1 += __shfl_xor(S1, off);
      }
      const int rg = rowbase + rl;
      if (dloc == dmin) {
        u64 key = ((u64)__float_as_uint(dloc + 2.0f) << 32)
                | (unsigned)(colg + (nbest << 4));
        atomicMin(rowmin + rg, key);
      }
      if ((lane & 15) == 0) {
        atomicAdd(rowZ + rg, Z);
        atomicAdd(rowS1 + rg, S1);
      }
    }
  }
}

// ---------------------------------------------------------------------------
// Column reduce: vectorized bf16x4, 4 cols/thread over 64 rows.
// ---------------------------------------------------------------------------
__global__ __launch_bounds__(256) void colreduce_kernel(
    const bf16_t* __restrict__ P, const float* __restrict__ rowZ,
    const u64* __restrict__ rowmin, const int rowbase,
    float* __restrict__ ap, int* __restrict__ ccnt, int* __restrict__ clist)
{
  __shared__ float izs[64], ths[64];
  const int t = threadIdx.x;
  const int pc0 = blockIdx.x * 1024 + (t << 2);
  const int r0 = blockIdx.y * 64;
  if (t < 64) {
    const int rg = rowbase + r0 + t;
    izs[t] = 1.0f / rowZ[rg];
    float dmin = __uint_as_float((unsigned)(rowmin[rg] >> 32)) - 2.0f;
    ths[t] = __expf(10.f * (dmin + 3e-4f));
  }
  __syncthreads();
  const int Bbase = pc0 & ~63;
  const int sub   = (pc0 & 63) >> 2;
  float s0 = 0.f, s1 = 0.f, s2 = 0.f, s3 = 0.f;
  for (int r = 0; r < 64; ++r) {
    bf16x4 p4 = *(const bf16x4*)(P + (size_t)(r0 + r) * NE + pc0);
    float p0 = (float)p4[0], p1 = (float)p4[1], p2 = (float)p4[2], p3 = (float)p4[3];
    float iz = izs[r], th = ths[r];
    s0 = fmaf(p0, iz, s0); s1 = fmaf(p1, iz, s1);
    s2 = fmaf(p2, iz, s2); s3 = fmaf(p3, iz, s3);
    float pm = fminf(fminf(p0, p1), fminf(p2, p3));
    if (pm <= th) {
      const int rg = rowbase + r0 + r;
      float pvv[4] = {p0, p1, p2, p3};
      for (int n = 0; n < 4; ++n)
        if (pvv[n] <= th) {
          int pos = atomicAdd(ccnt + rg, 1);
          if (pos < CANDCAP) clist[(rg << 4) + pos] = Bbase + (n << 4) + sub;
        }
    }
  }
  atomicAdd(ap + pc0 + 0, s0); atomicAdd(ap + pc0 + 1, s1);
  atomicAdd(ap + pc0 + 2, s2); atomicAdd(ap + pc0 + 3, s3);
}

// ---------------------------------------------------------------------------
__global__ __launch_bounds__(256) void rowent_kernel(
    const float* __restrict__ rowZ, const float* __restrict__ rowS1,
    float* __restrict__ scal)
{
  __shared__ float sb[4];
  const int r = blockIdx.x * 256 + threadIdx.x;
  const int t = threadIdx.x;
  float Z = rowZ[r], S1 = rowS1[r];
  float ent = logf(Z) - S1 / Z;
#pragma unroll
  for (int off = 32; off >= 1; off >>= 1) ent += __shfl_xor(ent, off);
  if ((t & 63) == 0) sb[t >> 6] = ent;
  __syncthreads();
  if (t == 0) atomicAdd(scal + 1, sb[0] + sb[1] + sb[2] + sb[3]);
}

// ---------------------------------------------------------------------------
// Repair: exact fp32 argmin over candidate set; lexicographic (d, idx) min.
// ---------------------------------------------------------------------------
__global__ __launch_bounds__(256) void repair_kernel(
    const float* __restrict__ xnf, const float* __restrict__ embed,
    const u64* __restrict__ rowmin, const int* __restrict__ ccnt,
    const int* __restrict__ clist, int* __restrict__ indw,
    float* __restrict__ bins, int* __restrict__ binsI, float* __restrict__ out)
{
  const int t = threadIdx.x;
  const int row = blockIdx.x * 64 + (t >> 2);
  const int sub = t & 3;
  const int base = ((int)(unsigned)(rowmin[row] & 0xFFFFFFFFull)) & (NE - 1);
  int cnt = ccnt[row];
  if (cnt > CANDCAP) cnt = CANDCAP;
  float bestD = 1e30f;
  int bestI = NE;
  const float* xr = xnf + (size_t)row * EDIM + (sub << 6);
  for (int j = -1; j < cnt; ++j) {
    const int c = (j < 0) ? base : (clist[(row << 4) + j] & (NE - 1));
    const float* er = embed + (size_t)c * EDIM + (sub << 6);
    float s = 0.f;
#pragma unroll
    for (int k = 0; k < 64; k += 4) {
      float4 a = *(const float4*)(xr + k);
      float4 b = *(const float4*)(er + k);
      s = fmaf(a.x, b.x, s); s = fmaf(a.y, b.y, s);
      s = fmaf(a.z, b.z, s); s = fmaf(a.w, b.w, s);
    }
    s += __shfl_xor(s, 1);
    s += __shfl_xor(s, 2);
    if (s < bestD || (s == bestD && c < bestI)) { bestD = s; bestI = c; }
  }
  if (sub == 0) {
    indw[row] = bestI;
    out[OFF_IND + row] = (float)bestI;
    atomicAdd(bins + bestI, 1.0f);
    atomicAdd(binsI + bestI, 1);
  }
}

// ---------------------------------------------------------------------------
__global__ __launch_bounds__(256) void sortprep_kernel(
    const int* __restrict__ binsI, int* __restrict__ offs, int* __restrict__ cursor)
{
  __shared__ int ssum[256];
  const int t = threadIdx.x;
  const int base = t * 32;
  int loc[32];
  int cnt = 0;
#pragma unroll
  for (int j = 0; j < 32; ++j) { loc[j] = cnt; cnt += binsI[base + j]; }
  ssum[t] = cnt;
  __syncthreads();
  for (int off = 1; off < 256; off <<= 1) {
    int v = (t >= off) ? ssum[t - off] : 0;
    __syncthreads();
    ssum[t] += v;
    __syncthreads();
  }
  int run = (t > 0) ? ssum[t - 1] : 0;
#pragma unroll
  for (int j = 0; j < 32; ++j) {
    offs[base + j]   = run + loc[j];
    cursor[base + j] = run + loc[j];
  }
}

// ---------------------------------------------------------------------------
// rowsort: payload packs code in high bits -> (ind << 14) | row
// ---------------------------------------------------------------------------
__global__ __launch_bounds__(256) void rowsort_kernel(
    const int* __restrict__ indw, int* __restrict__ cursor, int* __restrict__ sorted)
{
  const int r = blockIdx.x * 256 + threadIdx.x;
  const int ind = indw[r] & (NE - 1);
  int pos = atomicAdd(cursor + ind, 1);
  sorted[pos & (NROWS - 1)] = (ind << 14) | r;
}

// ---------------------------------------------------------------------------
// esum + commit v2: entry-parallel segmented reduction over the sorted list.
// 256 blocks x 64 entries; all row loads independent (latency-pipelined).
// Interior segments -> plain store; block-spanning segments -> atomicAdd
// (esum pre-zeroed by memset). One commit-loss atomic per block.
// ---------------------------------------------------------------------------
__global__ __launch_bounds__(256) void esum_commit_kernel(
    const int* __restrict__ sorted, const int* __restrict__ offs,
    const int* __restrict__ binsI, const float* __restrict__ xnf,
    const float* __restrict__ embed, float* __restrict__ esum,
    float* __restrict__ scal)
{
  __shared__ int ent[64];
  __shared__ float sb[4];
  const int t = threadIdx.x;
  const int base = blockIdx.x * 64;
  if (t < 64) ent[t] = sorted[base + t];
  __syncthreads();
  float cm = 0.f;
  float acc = 0.f;
  int ccur = ent[0] >> 14;
#pragma unroll
  for (int j = 0; j < 64; ++j) {
    const int e = ent[j];
    const int c = e >> 14;
    const int r = e & (NROWS - 1);
    if (c != ccur) {
      const int s0 = offs[ccur], cn = binsI[ccur];
      float* ep = esum + (size_t)ccur * EDIM + t;
      if (s0 >= base && s0 + cn <= base + 64) *ep = acc;
      else atomicAdd(ep, acc);
      acc = 0.f;
      ccur = c;
    }
    float xv = xnf[(size_t)r * EDIM + t];
    acc += xv;
    float df = embed[(size_t)c * EDIM + t] - xv;
    cm = fmaf(df, df, cm);
  }
  {
    const int s0 = offs[ccur], cn = binsI[ccur];
    float* ep = esum + (size_t)ccur * EDIM + t;
    if (s0 >= base && s0 + cn <= base + 64) *ep = acc;
    else atomicAdd(ep, acc);
  }
#pragma unroll
  for (int off = 32; off >= 1; off >>= 1) cm += __shfl_xor(cm, off);
  if ((t & 63) == 0) sb[t >> 6] = cm;
  __syncthreads();
  if (t == 0) atomicAdd(scal + 2, sb[0] + sb[1] + sb[2] + sb[3]);
}

// ---------------------------------------------------------------------------
__global__ __launch_bounds__(256) void scalars_kernel(
    const float* __restrict__ ap, const float* __restrict__ scal, float* __restrict__ out)
{
  __shared__ float sb[4];
  const int t = threadIdx.x;
  float h = 0.f;
  for (int c = t; c < NE; c += 256) {
    float apv = ap[c] * (1.0f / NROWS);
    h -= apv * logf(apv);
  }
#pragma unroll
  for (int off = 32; off >= 1; off >>= 1) h += __shfl_xor(h, off);
  if ((t & 63) == 0) sb[t >> 6] = h;
  __syncthreads();
  if (t == 0) {
    float Hmax = sb[0] + sb[1] + sb[2] + sb[3];
    float commit = scal[2] * (1.0f / ((float)NROWS * (float)EDIM));
    float emin = scal[1] * (1.0f / (float)NROWS);
    out[OFF_LOSS] = commit - Hmax;
    out[OFF_EMIN] = emin;
    out[OFF_CMT]  = commit;
  }
}

// ---------------------------------------------------------------------------
__global__ __launch_bounds__(256) void cluster_kernel(
    const float* __restrict__ cs_in, const float* __restrict__ bins,
    float* __restrict__ cn, float* __restrict__ scal)
{
  __shared__ float sb[4];
  const int c = blockIdx.x * 256 + threadIdx.x;
  const int t = threadIdx.x;
  float v = cs_in[c] * 0.99f + bins[c] * 0.01f;
  cn[c] = v;
  float s = v;
#pragma unroll
  for (int off = 32; off >= 1; off >>= 1) s += __shfl_xor(s, off);
  if ((t & 63) == 0) sb[t >> 6] = s;
  __syncthreads();
  if (t == 0) atomicAdd(scal + 0, sb[0] + sb[1] + sb[2] + sb[3]);
}

// ---------------------------------------------------------------------------
__global__ __launch_bounds__(256) void scan_kernel(
    const float* __restrict__ cn, const float* __restrict__ scal,
    int* __restrict__ idxs, float* __restrict__ csm, float* __restrict__ out)
{
  __shared__ int ssum[256];
  const int t = threadIdx.x;
  const int base = t * 32;
  int cnt = 0;
  for (int j = 0; j < 32; ++j) cnt += (cn[base + j] < 0.1f) ? 1 : 0;
  ssum[t] = cnt;
  __syncthreads();
  for (int off = 1; off < 256; off <<= 1) {
    int v = (t >= off) ? ssum[t - off] : 0;
    __syncthreads();
    ssum[t] += v;
    __syncthreads();
  }
  int run = (t > 0) ? ssum[t - 1] : 0;
  const float total = scal[0];
  const float dscale = total / (total + (float)NE * 1e-5f);
  for (int j = 0; j < 32; ++j) {
    float v = cn[base + j];
    bool ex = v < 0.1f;                 // DEAD_THRESH * RATIO
    run += ex ? 1 : 0;
    int idx = run - 1; if (idx < 0) idx = 0;
    idx &= (NROWS - 1);
    idxs[base + j] = idx;
    csm[base + j] = (v + 1e-5f) * dscale;
    out[OFF_CSF + base + j] = ex ? 0.12f : v;   // RESET_CS*RATIO
  }
}

// ---------------------------------------------------------------------------
__global__ __launch_bounds__(256) void embed_out_kernel(
    const float* __restrict__ cn, const float* __restrict__ csm,
    const int* __restrict__ idxs, const float* __restrict__ xn,
    const float* __restrict__ embed_avg, const float* __restrict__ esum,
    float* __restrict__ out)
{
  const int c = blockIdx.x, t = threadIdx.x;
  float oe, oa;
  if (cn[c] < 0.1f) {
    float s = xn[(size_t)(idxs[c] & (NROWS - 1)) * EDIM + t];
    oe = s; oa = s * 0.12f;
  } else {
    float an = embed_avg[(size_t)c * EDIM + t] * 0.99f
             + esum[(size_t)c * EDIM + t] * 0.01f;
    oa = an; oe = an / csm[c];
  }
  out[OFF_EMB  + (size_t)c * EDIM + t] = oe;
  out[OFF_EAVG + (size_t)c * EDIM + t] = oa;
}

// ---------------------------------------------------------------------------
// GEMM-out via bf16x3 MFMA: out[M][768] = embed[ind[M]] @ W_out^T + b_out.
// ---------------------------------------------------------------------------
__global__ __launch_bounds__(256) void gemm_out_mfma_kernel(
    const bf16_t* __restrict__ eh, const bf16_t* __restrict__ el,
    const bf16_t* __restrict__ wh, const bf16_t* __restrict__ wl,
    const float* __restrict__ bias, const int* __restrict__ gather,
    float* __restrict__ C)
{
  __shared__ bf16_t Ab[PM * 64];
  __shared__ bf16_t Bb[PN * 64];
  const int tid  = threadIdx.x;
  const int lane = tid & 63;
  const int wave = tid >> 6;
  const int wm = wave >> 1, wn = wave & 1;
  const int bm   = blockIdx.x * PM;
  const int bcol = blockIdx.y * PN;

  const int srow8 = lane >> 3;
  const int chunk = (lane & 7) ^ srow8;
  const bf16_t* gpa = (chunk & 4) ? el : eh;
  const bf16_t* gpb = (chunk & 4) ? wl : wh;
  const int within = (chunk & 3) << 3;
  const int acall0 = wave << 5;

  const bf16_t* ga[4];
#pragma unroll
  for (int c = 0; c < 4; ++c) {
    const int gr = gather[bm + acall0 + (c << 3) + srow8] & (NE - 1);
    ga[c] = gpa + (size_t)gr * EDIM + within;
  }
  const bf16_t* gb0 = gpb + (size_t)(bcol + acall0 + srow8) * EDIM + within;

  f32x4 acc[4][4] = {};

  for (int k0 = 0; k0 < EDIM; k0 += PK) {
    __syncthreads();
#pragma unroll
    for (int c = 0; c < 4; ++c) {
      const int rr = acall0 + (c << 3);
      gload16(ga[c] + k0, &Ab[rr * 64]);
      gload16(gb0 + (size_t)(c << 3) * EDIM + k0, &Bb[rr * 64]);
    }
    __syncthreads();

    const int swz = lane & 7;
    const int sh  = (lane >> 4) ^ swz;
    const int sl  = sh ^ 4;
    const int ar0 = (wm << 6) + (lane & 15);
    const int br0 = (wn << 6) + (lane & 15);
    bf16x8 bhf[4], blf[4];
#pragma unroll
    for (int n = 0; n < 4; ++n) {
      const int r = br0 + (n << 4);
      bhf[n] = *(const bf16x8*)&Bb[r * 64 + (sh << 3)];
      blf[n] = *(const bf16x8*)&Bb[r * 64 + (sl << 3)];
    }
#pragma unroll
    for (int m = 0; m < 4; ++m) {
      const int r = ar0 + (m << 4);
      bf16x8 ahf = *(const bf16x8*)&Ab[r * 64 + (sh << 3)];
      bf16x8 alf = *(const bf16x8*)&Ab[r * 64 + (sl << 3)];
#pragma unroll
      for (int n = 0; n < 4; ++n) {
        acc[m][n] = __builtin_amdgcn_mfma_f32_16x16x32_bf16(ahf, bhf[n], acc[m][n], 0, 0, 0);
        acc[m][n] = __builtin_amdgcn_mfma_f32_16x16x32_bf16(ahf, blf[n], acc[m][n], 0, 0, 0);
        acc[m][n] = __builtin_amdgcn_mfma_f32_16x16x32_bf16(alf, bhf[n], acc[m][n], 0, 0, 0);
      }
    }
  }

  const int colb = bcol + (wn << 6) + (lane & 15);
  float bs[4];
#pragma unroll
  for (int n = 0; n < 4; ++n) bs[n] = bias[colb + (n << 4)];
  const int row0 = bm + (wm << 6) + ((lane >> 4) << 2);
#pragma unroll
  for (int m = 0; m < 4; ++m) {
#pragma unroll
    for (int q = 0; q < 4; ++q) {
      float* op = C + (size_t)(row0 + (m << 4) + q) * ODIM;
#pragma unroll
      for (int n = 0; n < 4; ++n)
        op[colb + (n << 4)] = acc[m][n][q] + bs[n];
    }
  }
}

// ---------------------------------------------------------------------------
extern "C" void kernel_launch(void* const* d_in, const int* in_sizes, int n_in,
                              void* d_out, int out_size, void* d_ws, size_t ws_size,
                              hipStream_t stream)
{
  const float* x         = (const float*)d_in[0];
  const float* W_in      = (const float*)d_in[1];
  const float* b_in      = (const float*)d_in[2];
  const float* W_out     = (const float*)d_in[3];
  const float* b_out     = (const float*)d_in[4];
  const float* embed     = (const float*)d_in[5];
  const float* embed_avg = (const float*)d_in[6];
  const float* cs_in     = (const float*)d_in[7];
  float* out = (float*)d_out;
  char* ws = (char*)d_ws;

  if (ws_size < (size_t)W_END) {   // guard (proven not to fire)
    zero_out_kernel<<<(out_size + 255) / 256, 256, 0, stream>>>(out, out_size);
    return;
  }

  bf16_t* xh = (bf16_t*)(ws + W_XN);
  bf16_t* xl = (bf16_t*)(ws + W_XN + 8388608u);
  bf16_t* eh = (bf16_t*)(ws + W_ESUM);
  bf16_t* el = (bf16_t*)(ws + W_ESUM + 4194304u);
  // after panels: esum in dead xh region; W_out planes in dead xl region
  float*  esum = (float*)(ws + W_XN);
  bf16_t* wh   = (bf16_t*)(ws + W_XN + 8388608u);
  bf16_t* wl   = (bf16_t*)(ws + W_XN + 8388608u + 393216u);
  u64*   rowmin= (u64*)  (ws + W_RMIN);
  int*   offs  = (int*)  (ws + W_RMIN);            // reuses rowmin AFTER repair
  int*   cursor= offs + NE;
  float* rowZ  = (float*)(ws + W_RZ);
  float* rowS1 = (float*)(ws + W_RS1);
  int*   binsI = (int*)  (ws + W_INVZ);
  int*   indw  = (int*)  (ws + W_INDW);
  float* bins  = (float*)(ws + W_BINS);
  float* cn    = (float*)(ws + W_CN);
  float* csm   = (float*)(ws + W_CSM);
  int*   idxs  = (int*)  (ws + W_IDXS);
  float* ap    = (float*)(ws + W_AP);
  float* scal  = (float*)(ws + W_SCAL);

  // d_out scratch:
  //   z_q region: [0,16MB) fp32 xn ; [16MB,48MB) bf16 P panel (ends at OFF_IND)
  //   emb region: ccnt[16384] + clist[16384*16] + sorted[16384] (pre-embed_out)
  float*  xnf    = out + OFF_ZQ;
  bf16_t* Pbuf   = (bf16_t*)(out + OFF_ZQ + 4194304);
  int*    ccnt   = (int*)(out + OFF_EMB);
  int*    clist  = ccnt + NROWS;
  int*    sorted = clist + NROWS * CANDCAP;

  hipMemsetAsync(ws + W_RMIN, 0xFF, W_RZ - W_RMIN, stream); // rowmin = ~0
  hipMemsetAsync(ws + W_RZ,   0,    W_END - W_RZ,  stream); // rowZ..scal = 0 (incl binsI)
  hipMemsetAsync(ccnt, 0, NROWS * sizeof(int), stream);     // candidate counts

  // 1. x_proj (fp32 into d_out scratch)
  gemm_in_kernel<<<dim3(NROWS / 64, EDIM / 64), 256, 0, stream>>>(
      x, W_in, b_in, xnf);
  // 2. l2norm + bf16 hi/lo planes
  l2norm_split_kernel<<<NROWS, 256, 0, stream>>>(xnf, xh, xl);
  // 3. embed bf16 hi/lo planes
  split_kernel<<<(NE * EDIM / 4) / 256, 256, 0, stream>>>(embed, eh, el);
  // 4. panel loop: MFMA similarity + permuted P store, then vector column-reduce
  for (int p = 0; p < NROWS / PROWS; ++p) {
    const int rowbase = p * PROWS;
    phase1_mfma_kernel<<<dim3(PROWS / PM, NE / PN), 256, 0, stream>>>(
        xh, xl, eh, el, rowbase, rowmin, rowZ, rowS1, Pbuf);
    colreduce_kernel<<<dim3(NE / 1024, PROWS / 64), 256, 0, stream>>>(
        Pbuf, rowZ, rowmin, rowbase, ap, ccnt, clist);
  }
  // 5. esum region zero (xh dead now; covers empty codes)
  hipMemsetAsync(ws + W_XN, 0, NE * EDIM * sizeof(float), stream);
  // 6. entropy_to_min partials
  rowent_kernel<<<NROWS / 256, 256, 0, stream>>>(rowZ, rowS1, scal);
  // 7. exact argmin repair (+ bins / binsI)
  repair_kernel<<<NROWS / 64, 256, 0, stream>>>(
      xnf, embed, rowmin, ccnt, clist, indw, bins, binsI, out);
  // 8. counting sort of rows by code (payload packs code)
  sortprep_kernel<<<1, 256, 0, stream>>>(binsI, offs, cursor);
  rowsort_kernel<<<NROWS / 256, 256, 0, stream>>>(indw, cursor, sorted);
  // 9. W_out bf16 planes (xl region dead after panels)
  split_kernel<<<(ODIM * EDIM / 4) / 256, 256, 0, stream>>>(W_out, wh, wl);
  // 10. esum + commit loss (entry-parallel segmented reduction)
  esum_commit_kernel<<<NROWS / 64, 256, 0, stream>>>(
      sorted, offs, binsI, xnf, embed, esum, scal);
  // 11. cluster_new + total
  cluster_kernel<<<NE / 256, 256, 0, stream>>>(cs_in, bins, cn, scal);
  // 12. expiry scan + cluster_final
  scan_kernel<<<1, 256, 0, stream>>>(cn, scal, idxs, csm, out);
  // 13. scalar outputs
  scalars_kernel<<<1, 256, 0, stream>>>(ap, scal, out);
  // 14. embed_final / embed_avg_final
  embed_out_kernel<<<NE, 256, 0, stream>>>(cn, csm, idxs, xnf, embed_avg, esum, out);
  // 15. z_q GEMM LAST via MFMA (overwrites z_q scratch incl. P)
  gemm_out_mfma_kernel<<<dim3(NROWS / PM, ODIM / PN), 256, 0, stream>>>(
      eh, el, wh, wl, b_out, indw, out + OFF_ZQ);
}

// Round 8
// 985.826 us; speedup vs baseline: 1.7148x; 1.0304x over previous
//
#include <hip/hip_runtime.h>
#include <hip/hip_bf16.h>

typedef unsigned long long u64;
typedef __bf16 bf16_t;
typedef __attribute__((ext_vector_type(8))) __bf16 bf16x8;
typedef __attribute__((ext_vector_type(4))) __bf16 bf16x4;
typedef __attribute__((ext_vector_type(4))) float f32x4;

#define NROWS 16384
#define KLAT  768
#define EDIM  256
#define NE    8192
#define ODIM  768

// output element offsets (FLOAT32 elements — d_out is fp32, 16,801,795 elems)
#define OFF_ZQ   0
#define OFF_IND  12582912
#define OFF_LOSS 12599296
#define OFF_EMB  12599297
#define OFF_EAVG 14696449
#define OFF_CSF  16793601
#define OFF_EMIN 16801793
#define OFF_CMT  16801794

// workspace layout (~25.76 MB proven)
// W_XN: W_in bf16 h/m/l planes (1.15MB) during gemm_in; then xh/xl planes
//       during panels; after panels: [0,8MB) f32 esum ; [8MB,+768KB) W_out planes
#define W_XN    0u
#define W_ESUM  16777216u    // bf16 eh (4MB) + el (4MB) — live until gemm_out (last)
#define W_RMIN  25165824u    // u64 rowmin [16384]; after repair: i32 offs+cursor
#define W_RZ    25296896u    // f32 rowZ
#define W_RS1   25362432u    // f32 rowS1
#define W_INVZ  25427968u    // i32 binsI [8192]
#define W_INDW  25493504u    // i32 ind
#define W_BINS  25559040u    // f32 bins [8192]
#define W_CN    25591808u    // f32 cluster_new
#define W_CSM   25624576u    // f32 cs smoothed
#define W_IDXS  25657344u    // i32 sampled idx
#define W_AP    25690112u    // f32 ap [8192] (PERMUTED col space — entropy invariant)
#define W_SCAL  25722880u    // f32 scal[4]
#define W_END   25722896u

#define CANDCAP 16
#define PROWS   2048         // panel rows
#define PM      128          // MFMA block rows
#define PN      128          // MFMA block cols
#define PK      32           // MFMA K chunk

// gemm_in MFMA geometry
#define GM 128
#define GN 64
#define GK 32
#define ASTR 40              // bf16 row stride (80B = 5x16B slots, conflict-free b128)

typedef __attribute__((address_space(3))) unsigned char lds_u8;
typedef __attribute__((address_space(1))) const unsigned char glb_u8;
static __device__ __forceinline__ void gload16(const void* g, void* l)
{
  __builtin_amdgcn_global_load_lds((glb_u8*)g, (lds_u8*)l, 16, 0, 0);
}

// ---------------------------------------------------------------------------
__global__ __launch_bounds__(256) void zero_out_kernel(float* __restrict__ out, int n)
{
  int i = blockIdx.x * 256 + threadIdx.x;
  if (i < n) out[i] = 0.0f;
}

// ---------------------------------------------------------------------------
// 3-way bf16 split: src -> h + m + l (covers >=24 mantissa bits)
// ---------------------------------------------------------------------------
__global__ __launch_bounds__(256) void split3_kernel(
    const float* __restrict__ src, bf16_t* __restrict__ h3,
    bf16_t* __restrict__ m3, bf16_t* __restrict__ l3)
{
  const int i = (blockIdx.x * 256 + threadIdx.x) << 2;
  float4 v = *(const float4*)(src + i);
  bf16_t hv[4], mv[4], lv[4];
  float c[4] = {v.x, v.y, v.z, v.w};
#pragma unroll
  for (int j = 0; j < 4; ++j) {
    bf16_t h = (bf16_t)c[j];
    float r1 = c[j] - (float)h;
    bf16_t m = (bf16_t)r1;
    bf16_t l = (bf16_t)(r1 - (float)m);
    hv[j] = h; mv[j] = m; lv[j] = l;
  }
  *(bf16x4*)(h3 + i) = *(bf16x4*)hv;
  *(bf16x4*)(m3 + i) = *(bf16x4*)mv;
  *(bf16x4*)(l3 + i) = *(bf16x4*)lv;
}

// ---------------------------------------------------------------------------
// GEMM-in via 3-way-split MFMA (6 products: hh,hm,mh,hl,lh,mm — fp32-grade,
// dot error ~8e-7 rel, same class as fp32 reorder noise vs jax).
// Tile 128x64, K-chunk 32, 4 waves (2x2), wave tile 64x32 (4m x 2n frags).
// A (x) split on the fly fp32->3 planes; B (W_in) planes precomputed.
// LDS 80B row stride: b128 reads 2-way (free), writes uniform/2-way.
// ---------------------------------------------------------------------------
__global__ __launch_bounds__(256) void gemm_in_mfma_kernel(
    const float* __restrict__ A,
    const bf16_t* __restrict__ wh, const bf16_t* __restrict__ wm,
    const bf16_t* __restrict__ wl,
    const float* __restrict__ bias, float* __restrict__ C)
{
  __shared__ bf16_t Ah[GM * ASTR], Am[GM * ASTR], Al[GM * ASTR];
  __shared__ bf16_t Bh[GN * ASTR], Bm[GN * ASTR], Bl[GN * ASTR];
  const int tid  = threadIdx.x;
  const int lane = tid & 63;
  const int wave = tid >> 6;
  const int wmr = wave >> 1, wnc = wave & 1;
  const int bm = blockIdx.x * GM;
  const int bn = blockIdx.y * GN;

  const int brow = tid >> 2, bkc = tid & 3;   // B staging: row, 8-bf16 chunk

  f32x4 acc[4][2] = {};

  for (int k0 = 0; k0 < KLAT; k0 += GK) {
    __syncthreads();
    // A: load fp32, 3-way split, write planes
#pragma unroll
    for (int c = 0; c < 4; ++c) {
      const int pos = (c << 8) + tid;
      const int r = pos >> 3, kq = pos & 7;
      float4 v = *(const float4*)(A + (size_t)(bm + r) * KLAT + k0 + (kq << 2));
      float cc[4] = {v.x, v.y, v.z, v.w};
      bf16_t hv[4], mv[4], lv[4];
#pragma unroll
      for (int j = 0; j < 4; ++j) {
        bf16_t h = (bf16_t)cc[j];
        float r1 = cc[j] - (float)h;
        bf16_t m = (bf16_t)r1;
        hv[j] = h; mv[j] = m; lv[j] = (bf16_t)(r1 - (float)m);
      }
      const int off = r * ASTR + (kq << 2);
      *(bf16x4*)&Ah[off] = *(bf16x4*)hv;
      *(bf16x4*)&Am[off] = *(bf16x4*)mv;
      *(bf16x4*)&Al[off] = *(bf16x4*)lv;
    }
    // B: register-stage precomputed planes
    {
      const size_t g = (size_t)(bn + brow) * KLAT + k0 + (bkc << 3);
      const int off = brow * ASTR + (bkc << 3);
      *(bf16x8*)&Bh[off] = *(const bf16x8*)(wh + g);
      *(bf16x8*)&Bm[off] = *(const bf16x8*)(wm + g);
      *(bf16x8*)&Bl[off] = *(const bf16x8*)(wl + g);
    }
    __syncthreads();

    const int koff = (lane >> 4) << 3;          // 0,8,16,24 bf16
    const int br0 = (wnc << 5) + (lane & 15);
    bf16x8 bh[2], bm2[2], bl2[2];
#pragma unroll
    for (int n = 0; n < 2; ++n) {
      const int r = br0 + (n << 4);
      bh[n]  = *(const bf16x8*)&Bh[r * ASTR + koff];
      bm2[n] = *(const bf16x8*)&Bm[r * ASTR + koff];
      bl2[n] = *(const bf16x8*)&Bl[r * ASTR + koff];
    }
    const int ar0 = (wmr << 6) + (lane & 15);
#pragma unroll
    for (int m = 0; m < 4; ++m) {
      const int r = ar0 + (m << 4);
      bf16x8 ah = *(const bf16x8*)&Ah[r * ASTR + koff];
      bf16x8 am = *(const bf16x8*)&Am[r * ASTR + koff];
      bf16x8 al = *(const bf16x8*)&Al[r * ASTR + koff];
#pragma unroll
      for (int n = 0; n < 2; ++n) {
        acc[m][n] = __builtin_amdgcn_mfma_f32_16x16x32_bf16(ah, bh[n],  acc[m][n], 0, 0, 0);
        acc[m][n] = __builtin_amdgcn_mfma_f32_16x16x32_bf16(ah, bm2[n], acc[m][n], 0, 0, 0);
        acc[m][n] = __builtin_amdgcn_mfma_f32_16x16x32_bf16(am, bh[n],  acc[m][n], 0, 0, 0);
        acc[m][n] = __builtin_amdgcn_mfma_f32_16x16x32_bf16(ah, bl2[n], acc[m][n], 0, 0, 0);
        acc[m][n] = __builtin_amdgcn_mfma_f32_16x16x32_bf16(al, bh[n],  acc[m][n], 0, 0, 0);
        acc[m][n] = __builtin_amdgcn_mfma_f32_16x16x32_bf16(am, bm2[n], acc[m][n], 0, 0, 0);
      }
    }
  }

  // epilogue: col = bn + wnc*32 + n*16 + (lane&15); row = bm + wmr*64 + m*16 + (lane>>4)*4 + q
  const int colb = bn + (wnc << 5) + (lane & 15);
  const float bs0 = bias[colb], bs1 = bias[colb + 16];
  const int row0 = bm + (wmr << 6) + ((lane >> 4) << 2);
#pragma unroll
  for (int m = 0; m < 4; ++m) {
#pragma unroll
    for (int q = 0; q < 4; ++q) {
      float* op = C + (size_t)(row0 + (m << 4) + q) * EDIM;
      op[colb]      = acc[m][0][q] + bs0;
      op[colb + 16] = acc[m][1][q] + bs1;
    }
  }
}

// ---------------------------------------------------------------------------
__global__ __launch_bounds__(256) void l2norm_split_kernel(
    float* __restrict__ xnf, bf16_t* __restrict__ xh, bf16_t* __restrict__ xl)
{
  __shared__ float sb[4];
  const int r = blockIdx.x, t = threadIdx.x;
  const size_t o = (size_t)r * EDIM + t;
  float v = xnf[o];
  float s = v * v;
#pragma unroll
  for (int off = 32; off >= 1; off >>= 1) s += __shfl_xor(s, off);
  if ((t & 63) == 0) sb[t >> 6] = s;
  __syncthreads();
  float tot = sb[0] + sb[1] + sb[2] + sb[3];
  float nv = v / sqrtf(tot);
  xnf[o] = nv;
  bf16_t h = (bf16_t)nv;
  xh[o] = h;
  xl[o] = (bf16_t)(nv - (float)h);
}

// ---------------------------------------------------------------------------
__global__ __launch_bounds__(256) void split_kernel(
    const float* __restrict__ src, bf16_t* __restrict__ hi, bf16_t* __restrict__ lo)
{
  const int i = (blockIdx.x * 256 + threadIdx.x) << 2;
  float4 v = *(const float4*)(src + i);
  bf16_t h0 = (bf16_t)v.x, h1 = (bf16_t)v.y, h2 = (bf16_t)v.z, h3 = (bf16_t)v.w;
  bf16x4 hv = {h0, h1, h2, h3};
  bf16x4 lv = {(bf16_t)(v.x - (float)h0), (bf16_t)(v.y - (float)h1),
               (bf16_t)(v.z - (float)h2), (bf16_t)(v.w - (float)h3)};
  *(bf16x4*)(hi + i) = hv;
  *(bf16x4*)(lo + i) = lv;
}

// ---------------------------------------------------------------------------
// Phase 1 (panel): d~ via bf16x3 MFMA. Block 128x128, 4 waves (2x2), wave
// tile 64x64. LDS rows 128B = [hi|lo], XOR-swizzled; staged via
// global_load_lds w=16 with pre-swizzled per-lane global source.
// ---------------------------------------------------------------------------
__global__ __launch_bounds__(256) void phase1_mfma_kernel(
    const bf16_t* __restrict__ xh, const bf16_t* __restrict__ xl,
    const bf16_t* __restrict__ eh, const bf16_t* __restrict__ el,
    const int rowbase,
    u64* __restrict__ rowmin, float* __restrict__ rowZ, float* __restrict__ rowS1,
    bf16_t* __restrict__ P)
{
  __shared__ bf16_t Ab[PM * 64];
  __shared__ bf16_t Bb[PN * 64];
  const int tid  = threadIdx.x;
  const int lane = tid & 63;
  const int wave = tid >> 6;
  const int wm = wave >> 1, wn = wave & 1;
  const int brow = blockIdx.x * PM;
  const int bcol = blockIdx.y * PN;

  const int srow8 = lane >> 3;
  const int chunk = (lane & 7) ^ srow8;
  const bf16_t* gpa = (chunk & 4) ? xl : xh;
  const bf16_t* gpb = (chunk & 4) ? el : eh;
  const int within = (chunk & 3) << 3;
  const int acall0 = wave << 5;

  const bf16_t* ga0 = gpa + (size_t)(rowbase + brow + acall0 + srow8) * EDIM + within;
  const bf16_t* gb0 = gpb + (size_t)(bcol + acall0 + srow8) * EDIM + within;

  f32x4 acc[4][4] = {};

  for (int k0 = 0; k0 < EDIM; k0 += PK) {
    __syncthreads();
#pragma unroll
    for (int c = 0; c < 4; ++c) {
      const int rr = acall0 + (c << 3);
      gload16(ga0 + (size_t)(c << 3) * EDIM + k0, &Ab[rr * 64]);
      gload16(gb0 + (size_t)(c << 3) * EDIM + k0, &Bb[rr * 64]);
    }
    __syncthreads();

    const int swz = lane & 7;
    const int sh  = (lane >> 4) ^ swz;
    const int sl  = sh ^ 4;
    const int ar0 = (wm << 6) + (lane & 15);
    const int br0 = (wn << 6) + (lane & 15);
    bf16x8 bhf[4], blf[4];
#pragma unroll
    for (int n = 0; n < 4; ++n) {
      const int r = br0 + (n << 4);
      bhf[n] = *(const bf16x8*)&Bb[r * 64 + (sh << 3)];
      blf[n] = *(const bf16x8*)&Bb[r * 64 + (sl << 3)];
    }
#pragma unroll
    for (int m = 0; m < 4; ++m) {
      const int r = ar0 + (m << 4);
      bf16x8 ahf = *(const bf16x8*)&Ab[r * 64 + (sh << 3)];
      bf16x8 alf = *(const bf16x8*)&Ab[r * 64 + (sl << 3)];
#pragma unroll
      for (int n = 0; n < 4; ++n) {
        acc[m][n] = __builtin_amdgcn_mfma_f32_16x16x32_bf16(ahf, bhf[n], acc[m][n], 0, 0, 0);
        acc[m][n] = __builtin_amdgcn_mfma_f32_16x16x32_bf16(ahf, blf[n], acc[m][n], 0, 0, 0);
        acc[m][n] = __builtin_amdgcn_mfma_f32_16x16x32_bf16(alf, bhf[n], acc[m][n], 0, 0, 0);
      }
    }
  }

  const int colg  = bcol + (wn << 6) + (lane & 15);
  const int pbase = bcol + (wn << 6) + ((lane & 15) << 2);
  const int rl0   = brow + (wm << 6) + ((lane >> 4) << 2);
#pragma unroll
  for (int m = 0; m < 4; ++m) {
#pragma unroll
    for (int q = 0; q < 4; ++q) {
      const int rl = rl0 + (m << 4) + q;
      float Z = 0.f, S1 = 0.f;
      float dloc = 1e30f;
      int nbest = 0;
      bf16_t evv[4];
#pragma unroll
      for (int n = 0; n < 4; ++n) {
        float d = acc[m][n][q];
        float l = 10.f * d;
        float e = __expf(l);
        Z += e; S1 += l * e;
        evv[n] = (bf16_t)e;
        if (d < dloc) { dloc = d; nbest = n; }
      }
      bf16x4 pv = {evv[0], evv[1], evv[2], evv[3]};
      *(bf16x4*)(P + (size_t)rl * NE + pbase) = pv;
      float dmin = dloc;
#pragma unroll
      for (int off = 1; off < 16; off <<= 1) {
        dmin = fminf(dmin, __shfl_xor(dmin, off));
        Z  += __shfl_xor(Z, off);
        S1 += __shfl_xor(S1, off);
      }
      const int rg = rowbase + rl;
      if (dloc == dmin) {
        u64 key = ((u64)__float_as_uint(dloc + 2.0f) << 32)
                | (unsigned)(colg + (nbest << 4));
        atomicMin(rowmin + rg, key);
      }
      if ((lane & 15) == 0) {
        atomicAdd(rowZ + rg, Z);
        atomicAdd(rowS1 + rg, S1);
      }
    }
  }
}

// ---------------------------------------------------------------------------
// Column reduce: vectorized bf16x4, 4 cols/thread over 64 rows.
// ---------------------------------------------------------------------------
__global__ __launch_bounds__(256) void colreduce_kernel(
    const bf16_t* __restrict__ P, const float* __restrict__ rowZ,
    const u64* __restrict__ rowmin, const int rowbase,
    float* __restrict__ ap, int* __restrict__ ccnt, int* __restrict__ clist)
{
  __shared__ float izs[64], ths[64];
  const int t = threadIdx.x;
  const int pc0 = blockIdx.x * 1024 + (t << 2);
  const int r0 = blockIdx.y * 64;
  if (t < 64) {
    const int rg = rowbase + r0 + t;
    izs[t] = 1.0f / rowZ[rg];
    float dmin = __uint_as_float((unsigned)(rowmin[rg] >> 32)) - 2.0f;
    ths[t] = __expf(10.f * (dmin + 3e-4f));
  }
  __syncthreads();
  const int Bbase = pc0 & ~63;
  const int sub   = (pc0 & 63) >> 2;
  float s0 = 0.f, s1 = 0.f, s2 = 0.f, s3 = 0.f;
  for (int r = 0; r < 64; ++r) {
    bf16x4 p4 = *(const bf16x4*)(P + (size_t)(r0 + r) * NE + pc0);
    float p0 = (float)p4[0], p1 = (float)p4[1], p2 = (float)p4[2], p3 = (float)p4[3];
    float iz = izs[r], th = ths[r];
    s0 = fmaf(p0, iz, s0); s1 = fmaf(p1, iz, s1);
    s2 = fmaf(p2, iz, s2); s3 = fmaf(p3, iz, s3);
    float pm = fminf(fminf(p0, p1), fminf(p2, p3));
    if (pm <= th) {
      const int rg = rowbase + r0 + r;
      float pvv[4] = {p0, p1, p2, p3};
      for (int n = 0; n < 4; ++n)
        if (pvv[n] <= th) {
          int pos = atomicAdd(ccnt + rg, 1);
          if (pos < CANDCAP) clist[(rg << 4) + pos] = Bbase + (n << 4) + sub;
        }
    }
  }
  atomicAdd(ap + pc0 + 0, s0); atomicAdd(ap + pc0 + 1, s1);
  atomicAdd(ap + pc0 + 2, s2); atomicAdd(ap + pc0 + 3, s3);
}

// ---------------------------------------------------------------------------
__global__ __launch_bounds__(256) void rowent_kernel(
    const float* __restrict__ rowZ, const float* __restrict__ rowS1,
    float* __restrict__ scal)
{
  __shared__ float sb[4];
  const int r = blockIdx.x * 256 + threadIdx.x;
  const int t = threadIdx.x;
  float Z = rowZ[r], S1 = rowS1[r];
  float ent = logf(Z) - S1 / Z;
#pragma unroll
  for (int off = 32; off >= 1; off >>= 1) ent += __shfl_xor(ent, off);
  if ((t & 63) == 0) sb[t >> 6] = ent;
  __syncthreads();
  if (t == 0) atomicAdd(scal + 1, sb[0] + sb[1] + sb[2] + sb[3]);
}

// ---------------------------------------------------------------------------
// Repair: exact fp32 argmin over candidate set; lexicographic (d, idx) min.
// ---------------------------------------------------------------------------
__global__ __launch_bounds__(256) void repair_kernel(
    const float* __restrict__ xnf, const float* __restrict__ embed,
    const u64* __restrict__ rowmin, const int* __restrict__ ccnt,
    const int* __restrict__ clist, int* __restrict__ indw,
    float* __restrict__ bins, int* __restrict__ binsI, float* __restrict__ out)
{
  const int t = threadIdx.x;
  const int row = blockIdx.x * 64 + (t >> 2);
  const int sub = t & 3;
  const int base = ((int)(unsigned)(rowmin[row] & 0xFFFFFFFFull)) & (NE - 1);
  int cnt = ccnt[row];
  if (cnt > CANDCAP) cnt = CANDCAP;
  float bestD = 1e30f;
  int bestI = NE;
  const float* xr = xnf + (size_t)row * EDIM + (sub << 6);
  for (int j = -1; j < cnt; ++j) {
    const int c = (j < 0) ? base : (clist[(row << 4) + j] & (NE - 1));
    const float* er = embed + (size_t)c * EDIM + (sub << 6);
    float s = 0.f;
#pragma unroll
    for (int k = 0; k < 64; k += 4) {
      float4 a = *(const float4*)(xr + k);
      float4 b = *(const float4*)(er + k);
      s = fmaf(a.x, b.x, s); s = fmaf(a.y, b.y, s);
      s = fmaf(a.z, b.z, s); s = fmaf(a.w, b.w, s);
    }
    s += __shfl_xor(s, 1);
    s += __shfl_xor(s, 2);
    if (s < bestD || (s == bestD && c < bestI)) { bestD = s; bestI = c; }
  }
  if (sub == 0) {
    indw[row] = bestI;
    out[OFF_IND + row] = (float)bestI;
    atomicAdd(bins + bestI, 1.0f);
    atomicAdd(binsI + bestI, 1);
  }
}

// ---------------------------------------------------------------------------
__global__ __launch_bounds__(256) void sortprep_kernel(
    const int* __restrict__ binsI, int* __restrict__ offs, int* __restrict__ cursor)
{
  __shared__ int ssum[256];
  const int t = threadIdx.x;
  const int base = t * 32;
  int loc[32];
  int cnt = 0;
#pragma unroll
  for (int j = 0; j < 32; ++j) { loc[j] = cnt; cnt += binsI[base + j]; }
  ssum[t] = cnt;
  __syncthreads();
  for (int off = 1; off < 256; off <<= 1) {
    int v = (t >= off) ? ssum[t - off] : 0;
    __syncthreads();
    ssum[t] += v;
    __syncthreads();
  }
  int run = (t > 0) ? ssum[t - 1] : 0;
#pragma unroll
  for (int j = 0; j < 32; ++j) {
    offs[base + j]   = run + loc[j];
    cursor[base + j] = run + loc[j];
  }
}

// ---------------------------------------------------------------------------
__global__ __launch_bounds__(256) void rowsort_kernel(
    const int* __restrict__ indw, int* __restrict__ cursor, int* __restrict__ sorted)
{
  const int r = blockIdx.x * 256 + threadIdx.x;
  const int ind = indw[r] & (NE - 1);
  int pos = atomicAdd(cursor + ind, 1);
  sorted[pos & (NROWS - 1)] = (ind << 14) | r;
}

// ---------------------------------------------------------------------------
// esum + commit: entry-parallel segmented reduction over the sorted list.
// ---------------------------------------------------------------------------
__global__ __launch_bounds__(256) void esum_commit_kernel(
    const int* __restrict__ sorted, const int* __restrict__ offs,
    const int* __restrict__ binsI, const float* __restrict__ xnf,
    const float* __restrict__ embed, float* __restrict__ esum,
    float* __restrict__ scal)
{
  __shared__ int ent[64];
  __shared__ float sb[4];
  const int t = threadIdx.x;
  const int base = blockIdx.x * 64;
  if (t < 64) ent[t] = sorted[base + t];
  __syncthreads();
  float cm = 0.f;
  float acc = 0.f;
  int ccur = ent[0] >> 14;
#pragma unroll
  for (int j = 0; j < 64; ++j) {
    const int e = ent[j];
    const int c = e >> 14;
    const int r = e & (NROWS - 1);
    if (c != ccur) {
      const int s0 = offs[ccur], cn = binsI[ccur];
      float* ep = esum + (size_t)ccur * EDIM + t;
      if (s0 >= base && s0 + cn <= base + 64) *ep = acc;
      else atomicAdd(ep, acc);
      acc = 0.f;
      ccur = c;
    }
    float xv = xnf[(size_t)r * EDIM + t];
    acc += xv;
    float df = embed[(size_t)c * EDIM + t] - xv;
    cm = fmaf(df, df, cm);
  }
  {
    const int s0 = offs[ccur], cn = binsI[ccur];
    float* ep = esum + (size_t)ccur * EDIM + t;
    if (s0 >= base && s0 + cn <= base + 64) *ep = acc;
    else atomicAdd(ep, acc);
  }
#pragma unroll
  for (int off = 32; off >= 1; off >>= 1) cm += __shfl_xor(cm, off);
  if ((t & 63) == 0) sb[t >> 6] = cm;
  __syncthreads();
  if (t == 0) atomicAdd(scal + 2, sb[0] + sb[1] + sb[2] + sb[3]);
}

// ---------------------------------------------------------------------------
__global__ __launch_bounds__(256) void scalars_kernel(
    const float* __restrict__ ap, const float* __restrict__ scal, float* __restrict__ out)
{
  __shared__ float sb[4];
  const int t = threadIdx.x;
  float h = 0.f;
  for (int c = t; c < NE; c += 256) {
    float apv = ap[c] * (1.0f / NROWS);
    h -= apv * logf(apv);
  }
#pragma unroll
  for (int off = 32; off >= 1; off >>= 1) h += __shfl_xor(h, off);
  if ((t & 63) == 0) sb[t >> 6] = h;
  __syncthreads();
  if (t == 0) {
    float Hmax = sb[0] + sb[1] + sb[2] + sb[3];
    float commit = scal[2] * (1.0f / ((float)NROWS * (float)EDIM));
    float emin = scal[1] * (1.0f / (float)NROWS);
    out[OFF_LOSS] = commit - Hmax;
    out[OFF_EMIN] = emin;
    out[OFF_CMT]  = commit;
  }
}

// ---------------------------------------------------------------------------
__global__ __launch_bounds__(256) void cluster_kernel(
    const float* __restrict__ cs_in, const float* __restrict__ bins,
    float* __restrict__ cn, float* __restrict__ scal)
{
  __shared__ float sb[4];
  const int c = blockIdx.x * 256 + threadIdx.x;
  const int t = threadIdx.x;
  float v = cs_in[c] * 0.99f + bins[c] * 0.01f;
  cn[c] = v;
  float s = v;
#pragma unroll
  for (int off = 32; off >= 1; off >>= 1) s += __shfl_xor(s, off);
  if ((t & 63) == 0) sb[t >> 6] = s;
  __syncthreads();
  if (t == 0) atomicAdd(scal + 0, sb[0] + sb[1] + sb[2] + sb[3]);
}

// ---------------------------------------------------------------------------
__global__ __launch_bounds__(256) void scan_kernel(
    const float* __restrict__ cn, const float* __restrict__ scal,
    int* __restrict__ idxs, float* __restrict__ csm, float* __restrict__ out)
{
  __shared__ int ssum[256];
  const int t = threadIdx.x;
  const int base = t * 32;
  int cnt = 0;
  for (int j = 0; j < 32; ++j) cnt += (cn[base + j] < 0.1f) ? 1 : 0;
  ssum[t] = cnt;
  __syncthreads();
  for (int off = 1; off < 256; off <<= 1) {
    int v = (t >= off) ? ssum[t - off] : 0;
    __syncthreads();
    ssum[t] += v;
    __syncthreads();
  }
  int run = (t > 0) ? ssum[t - 1] : 0;
  const float total = scal[0];
  const float dscale = total / (total + (float)NE * 1e-5f);
  for (int j = 0; j < 32; ++j) {
    float v = cn[base + j];
    bool ex = v < 0.1f;                 // DEAD_THRESH * RATIO
    run += ex ? 1 : 0;
    int idx = run - 1; if (idx < 0) idx = 0;
    idx &= (NROWS - 1);
    idxs[base + j] = idx;
    csm[base + j] = (v + 1e-5f) * dscale;
    out[OFF_CSF + base + j] = ex ? 0.12f : v;   // RESET_CS*RATIO
  }
}

// ---------------------------------------------------------------------------
__global__ __launch_bounds__(256) void embed_out_kernel(
    const float* __restrict__ cn, const float* __restrict__ csm,
    const int* __restrict__ idxs, const float* __restrict__ xn,
    const float* __restrict__ embed_avg, const float* __restrict__ esum,
    float* __restrict__ out)
{
  const int c = blockIdx.x, t = threadIdx.x;
  float oe, oa;
  if (cn[c] < 0.1f) {
    float s = xn[(size_t)(idxs[c] & (NROWS - 1)) * EDIM + t];
    oe = s; oa = s * 0.12f;
  } else {
    float an = embed_avg[(size_t)c * EDIM + t] * 0.99f
             + esum[(size_t)c * EDIM + t] * 0.01f;
    oa = an; oe = an / csm[c];
  }
  out[OFF_EMB  + (size_t)c * EDIM + t] = oe;
  out[OFF_EAVG + (size_t)c * EDIM + t] = oa;
}

// ---------------------------------------------------------------------------
// GEMM-out via bf16x3 MFMA: out[M][768] = embed[ind[M]] @ W_out^T + b_out.
// ---------------------------------------------------------------------------
__global__ __launch_bounds__(256) void gemm_out_mfma_kernel(
    const bf16_t* __restrict__ eh, const bf16_t* __restrict__ el,
    const bf16_t* __restrict__ wh, const bf16_t* __restrict__ wl,
    const float* __restrict__ bias, const int* __restrict__ gather,
    float* __restrict__ C)
{
  __shared__ bf16_t Ab[PM * 64];
  __shared__ bf16_t Bb[PN * 64];
  const int tid  = threadIdx.x;
  const int lane = tid & 63;
  const int wave = tid >> 6;
  const int wm = wave >> 1, wn = wave & 1;
  const int bm   = blockIdx.x * PM;
  const int bcol = blockIdx.y * PN;

  const int srow8 = lane >> 3;
  const int chunk = (lane & 7) ^ srow8;
  const bf16_t* gpa = (chunk & 4) ? el : eh;
  const bf16_t* gpb = (chunk & 4) ? wl : wh;
  const int within = (chunk & 3) << 3;
  const int acall0 = wave << 5;

  const bf16_t* ga[4];
#pragma unroll
  for (int c = 0; c < 4; ++c) {
    const int gr = gather[bm + acall0 + (c << 3) + srow8] & (NE - 1);
    ga[c] = gpa + (size_t)gr * EDIM + within;
  }
  const bf16_t* gb0 = gpb + (size_t)(bcol + acall0 + srow8) * EDIM + within;

  f32x4 acc[4][4] = {};

  for (int k0 = 0; k0 < EDIM; k0 += PK) {
    __syncthreads();
#pragma unroll
    for (int c = 0; c < 4; ++c) {
      const int rr = acall0 + (c << 3);
      gload16(ga[c] + k0, &Ab[rr * 64]);
      gload16(gb0 + (size_t)(c << 3) * EDIM + k0, &Bb[rr * 64]);
    }
    __syncthreads();

    const int swz = lane & 7;
    const int sh  = (lane >> 4) ^ swz;
    const int sl  = sh ^ 4;
    const int ar0 = (wm << 6) + (lane & 15);
    const int br0 = (wn << 6) + (lane & 15);
    bf16x8 bhf[4], blf[4];
#pragma unroll
    for (int n = 0; n < 4; ++n) {
      const int r = br0 + (n << 4);
      bhf[n] = *(const bf16x8*)&Bb[r * 64 + (sh << 3)];
      blf[n] = *(const bf16x8*)&Bb[r * 64 + (sl << 3)];
    }
#pragma unroll
    for (int m = 0; m < 4; ++m) {
      const int r = ar0 + (m << 4);
      bf16x8 ahf = *(const bf16x8*)&Ab[r * 64 + (sh << 3)];
      bf16x8 alf = *(const bf16x8*)&Ab[r * 64 + (sl << 3)];
#pragma unroll
      for (int n = 0; n < 4; ++n) {
        acc[m][n] = __builtin_amdgcn_mfma_f32_16x16x32_bf16(ahf, bhf[n], acc[m][n], 0, 0, 0);
        acc[m][n] = __builtin_amdgcn_mfma_f32_16x16x32_bf16(ahf, blf[n], acc[m][n], 0, 0, 0);
        acc[m][n] = __builtin_amdgcn_mfma_f32_16x16x32_bf16(alf, bhf[n], acc[m][n], 0, 0, 0);
      }
    }
  }

  const int colb = bcol + (wn << 6) + (lane & 15);
  float bs[4];
#pragma unroll
  for (int n = 0; n < 4; ++n) bs[n] = bias[colb + (n << 4)];
  const int row0 = bm + (wm << 6) + ((lane >> 4) << 2);
#pragma unroll
  for (int m = 0; m < 4; ++m) {
#pragma unroll
    for (int q = 0; q < 4; ++q) {
      float* op = C + (size_t)(row0 + (m << 4) + q) * ODIM;
#pragma unroll
      for (int n = 0; n < 4; ++n)
        op[colb + (n << 4)] = acc[m][n][q] + bs[n];
    }
  }
}

// ---------------------------------------------------------------------------
extern "C" void kernel_launch(void* const* d_in, const int* in_sizes, int n_in,
                              void* d_out, int out_size, void* d_ws, size_t ws_size,
                              hipStream_t stream)
{
  const float* x         = (const float*)d_in[0];
  const float* W_in      = (const float*)d_in[1];
  const float* b_in      = (const float*)d_in[2];
  const float* W_out     = (const float*)d_in[3];
  const float* b_out     = (const float*)d_in[4];
  const float* embed     = (const float*)d_in[5];
  const float* embed_avg = (const float*)d_in[6];
  const float* cs_in     = (const float*)d_in[7];
  float* out = (float*)d_out;
  char* ws = (char*)d_ws;

  if (ws_size < (size_t)W_END) {   // guard (proven not to fire)
    zero_out_kernel<<<(out_size + 255) / 256, 256, 0, stream>>>(out, out_size);
    return;
  }

  // W_in planes live in xh region until l2norm_split overwrites it
  bf16_t* wih = (bf16_t*)(ws + W_XN);
  bf16_t* wim = wih + (size_t)EDIM * KLAT;
  bf16_t* wil = wim + (size_t)EDIM * KLAT;
  bf16_t* xh = (bf16_t*)(ws + W_XN);
  bf16_t* xl = (bf16_t*)(ws + W_XN + 8388608u);
  bf16_t* eh = (bf16_t*)(ws + W_ESUM);
  bf16_t* el = (bf16_t*)(ws + W_ESUM + 4194304u);
  // after panels: esum in dead xh region; W_out planes in dead xl region
  float*  esum = (float*)(ws + W_XN);
  bf16_t* wh   = (bf16_t*)(ws + W_XN + 8388608u);
  bf16_t* wl   = (bf16_t*)(ws + W_XN + 8388608u + 393216u);
  u64*   rowmin= (u64*)  (ws + W_RMIN);
  int*   offs  = (int*)  (ws + W_RMIN);            // reuses rowmin AFTER repair
  int*   cursor= offs + NE;
  float* rowZ  = (float*)(ws + W_RZ);
  float* rowS1 = (float*)(ws + W_RS1);
  int*   binsI = (int*)  (ws + W_INVZ);
  int*   indw  = (int*)  (ws + W_INDW);
  float* bins  = (float*)(ws + W_BINS);
  float* cn    = (float*)(ws + W_CN);
  float* csm   = (float*)(ws + W_CSM);
  int*   idxs  = (int*)  (ws + W_IDXS);
  float* ap    = (float*)(ws + W_AP);
  float* scal  = (float*)(ws + W_SCAL);

  // d_out scratch:
  //   z_q region: [0,16MB) fp32 xn ; [16MB,48MB) bf16 P panel (ends at OFF_IND)
  //   emb region: ccnt[16384] + clist[16384*16] + sorted[16384] (pre-embed_out)
  float*  xnf    = out + OFF_ZQ;
  bf16_t* Pbuf   = (bf16_t*)(out + OFF_ZQ + 4194304);
  int*    ccnt   = (int*)(out + OFF_EMB);
  int*    clist  = ccnt + NROWS;
  int*    sorted = clist + NROWS * CANDCAP;

  hipMemsetAsync(ws + W_RMIN, 0xFF, W_RZ - W_RMIN, stream); // rowmin = ~0
  hipMemsetAsync(ws + W_RZ,   0,    W_END - W_RZ,  stream); // rowZ..scal = 0 (incl binsI)
  hipMemsetAsync(ccnt, 0, NROWS * sizeof(int), stream);     // candidate counts

  // 0. W_in 3-way bf16 planes (xh region, dead until l2norm)
  split3_kernel<<<(EDIM * KLAT / 4) / 256, 256, 0, stream>>>(W_in, wih, wim, wil);
  // 1. x_proj via 6-product split MFMA (fp32-grade, into d_out scratch)
  gemm_in_mfma_kernel<<<dim3(NROWS / GM, EDIM / GN), 256, 0, stream>>>(
      x, wih, wim, wil, b_in, xnf);
  // 2. l2norm + bf16 hi/lo planes (overwrites W_in planes)
  l2norm_split_kernel<<<NROWS, 256, 0, stream>>>(xnf, xh, xl);
  // 3. embed bf16 hi/lo planes
  split_kernel<<<(NE * EDIM / 4) / 256, 256, 0, stream>>>(embed, eh, el);
  // 4. panel loop: MFMA similarity + permuted P store, then vector column-reduce
  for (int p = 0; p < NROWS / PROWS; ++p) {
    const int rowbase = p * PROWS;
    phase1_mfma_kernel<<<dim3(PROWS / PM, NE / PN), 256, 0, stream>>>(
        xh, xl, eh, el, rowbase, rowmin, rowZ, rowS1, Pbuf);
    colreduce_kernel<<<dim3(NE / 1024, PROWS / 64), 256, 0, stream>>>(
        Pbuf, rowZ, rowmin, rowbase, ap, ccnt, clist);
  }
  // 5. esum region zero (xh dead now; covers empty codes)
  hipMemsetAsync(ws + W_XN, 0, NE * EDIM * sizeof(float), stream);
  // 6. entropy_to_min partials
  rowent_kernel<<<NROWS / 256, 256, 0, stream>>>(rowZ, rowS1, scal);
  // 7. exact argmin repair (+ bins / binsI)
  repair_kernel<<<NROWS / 64, 256, 0, stream>>>(
      xnf, embed, rowmin, ccnt, clist, indw, bins, binsI, out);
  // 8. counting sort of rows by code (payload packs code)
  sortprep_kernel<<<1, 256, 0, stream>>>(binsI, offs, cursor);
  rowsort_kernel<<<NROWS / 256, 256, 0, stream>>>(indw, cursor, sorted);
  // 9. W_out bf16 planes (xl region dead after panels)
  split_kernel<<<(ODIM * EDIM / 4) / 256, 256, 0, stream>>>(W_out, wh, wl);
  // 10. esum + commit loss (entry-parallel segmented reduction)
  esum_commit_kernel<<<NROWS / 64, 256, 0, stream>>>(
      sorted, offs, binsI, xnf, embed, esum, scal);
  // 11. cluster_new + total
  cluster_kernel<<<NE / 256, 256, 0, stream>>>(cs_in, bins, cn, scal);
  // 12. expiry scan + cluster_final
  scan_kernel<<<1, 256, 0, stream>>>(cn, scal, idxs, csm, out);
  // 13. scalar outputs
  scalars_kernel<<<1, 256, 0, stream>>>(ap, scal, out);
  // 14. embed_final / embed_avg_final
  embed_out_kernel<<<NE, 256, 0, stream>>>(cn, csm, idxs, xnf, embed_avg, esum, out);
  // 15. z_q GEMM LAST via MFMA (overwrites z_q scratch incl. P)
  gemm_out_mfma_kernel<<<dim3(NROWS / PM, ODIM / PN), 256, 0, stream>>>(
      eh, el, wh, wl, b_out, indw, out + OFF_ZQ);
}